// Round 3
// baseline (2398.515 us; speedup 1.0000x reference)
//
#include <hip/hip_runtime.h>

typedef unsigned short u16;
typedef __attribute__((ext_vector_type(4))) float floatx4;
typedef __attribute__((ext_vector_type(8))) short shortx8;
typedef __attribute__((ext_vector_type(4))) short shortx4;
typedef __attribute__((ext_vector_type(4))) unsigned short ushortx4;

#define NOPS 8192
#define NMS  512
#define FDIM 512
#define CQ   2560   // op qkv cols: q | k0 | v0 | k2 | v2
#define CM   1536   // machine qkv cols: q | k1 | v1
#define NE2  65536

__device__ __forceinline__ float bf2f(u16 u){ return __uint_as_float(((unsigned)u)<<16); }
__device__ __forceinline__ u16 f2bf(float f){
  unsigned u = __float_as_uint(f);
  u += 0x7FFFu + ((u>>16)&1u);
  return (u16)(u>>16);
}
__device__ __forceinline__ float wred(float v){
  #pragma unroll
  for (int o=32;o;o>>=1) v += __shfl_xor(v,o,64);
  return v;
}
__device__ __forceinline__ float geluf(float x){
  return 0.5f*x*(1.f+erff(x*0.70710678118654752f));
}

// ---------------- zero small ws regions ----------------
__global__ void zero_ws_k(float* acc, int* counts, float* scratch){
  int i = blockIdx.x*blockDim.x + threadIdx.x;
  if (i < 64)   acc[i] = 0.f;
  if (i < 512)  counts[i] = 0;
  if (i < 4096) scratch[i] = 0.f;
}

// ---------------- CSR build for compat edges (dst = machine) ----------------
__global__ void csr_count_k(const int* __restrict__ d2, int* counts){
  int e = blockIdx.x*blockDim.x + threadIdx.x;
  if (e < NE2) atomicAdd(&counts[d2[e]], 1);
}
__global__ __launch_bounds__(512) void csr_scan_k(const int* counts, int* row_start, int* cursor){
  __shared__ int sd[512];
  int t = threadIdx.x;
  sd[t] = counts[t];
  __syncthreads();
  for (int off=1; off<512; off<<=1){
    int v = (t >= off) ? sd[t-off] : 0;
    __syncthreads();
    sd[t] += v;
    __syncthreads();
  }
  row_start[t+1] = sd[t];
  if (t==0) row_start[0] = 0;
  cursor[t] = sd[t] - counts[t];
}
__global__ void csr_scatter_k(const int* __restrict__ d2, int* cursor, int* elist){
  int e = blockIdx.x*blockDim.x + threadIdx.x;
  if (e < NE2){
    int pos = atomicAdd(&cursor[d2[e]], 1);
    elist[pos] = e;
  }
}

// ---------------- f32 -> bf16 convert (for W_out) ----------------
__global__ __launch_bounds__(256) void cvt_bf16_k(const float* __restrict__ src, u16* __restrict__ dst, int total){
  for (int i = blockIdx.x*blockDim.x + threadIdx.x; i < total; i += gridDim.x*blockDim.x)
    dst[i] = f2bf(src[i]);
}

// ---------------- embedding GEMM (tiny K, f32 in) + LN stats ----------------
__global__ __launch_bounds__(256) void embed_k(const float* __restrict__ X, const float* __restrict__ W,
                                               const float* __restrict__ bias, float* __restrict__ Y,
                                               int total, int K, float* accp){
  float s = 0.f, s2 = 0.f;
  for (int idx = blockIdx.x*blockDim.x + threadIdx.x; idx < total; idx += gridDim.x*blockDim.x){
    int n = idx >> 9, f = idx & 511;
    float v = bias[f];
    for (int c=0;c<K;++c) v += X[n*K+c] * W[c*512+f];
    Y[idx] = v;
    s += v; s2 += v*v;
  }
  s = wred(s); s2 = wred(s2);
  if ((threadIdx.x & 63) == 0){ atomicAdd(&accp[0], s); atomicAdd(&accp[1], s2); }
}

// ---------------- graph-LN apply ----------------
__global__ __launch_bounds__(256) void ln_apply_k(const float* __restrict__ src, float* __restrict__ dst,
                                                  const float* __restrict__ w, const float* __restrict__ b,
                                                  const float* accp, float inv_n, int total){
  float mean = accp[0]*inv_n;
  float var  = fmaxf(accp[1]*inv_n - mean*mean, 0.f);
  float rinv = 1.f/(sqrtf(var) + 1e-5f);
  for (int i = blockIdx.x*blockDim.x + threadIdx.x; i < total; i += gridDim.x*blockDim.x){
    int f = i & 511;
    dst[i] = (src[i]-mean)*rinv*w[f] + b[f];
  }
}

// ---------------- gated residual + LN stats ----------------
__global__ __launch_bounds__(256) void gate_res_k(float* __restrict__ y, const float* __restrict__ x,
                                                  const float* __restrict__ bout, const float* __restrict__ skipel,
                                                  float* accp, int total){
  float g = 1.f/(1.f+expf(-(*skipel)));
  float s = 0.f, s2 = 0.f;
  for (int i = blockIdx.x*blockDim.x + threadIdx.x; i < total; i += gridDim.x*blockDim.x){
    float o = g*(y[i]+bout[i & 511]) + (2.f-g)*x[i];  // gated skip + wrapper residual
    y[i] = o;
    s += o; s2 += o*o;
  }
  s = wred(s); s2 = wred(s2);
  if ((threadIdx.x & 63) == 0){ atomicAdd(&accp[0], s); atomicAdd(&accp[1], s2); }
}

// ---------------- per-layer combined weights: W' = W @ blockdiag(Rel), b' = b @ Rel ----------------
__global__ __launch_bounds__(256) void combine_k(const float* Wk, const float* bk, const float* Wq, const float* bq,
                                                 const float* Wv, const float* bv, const float* Ar, const float* Mr,
                                                 int l, u16* Wc_op, float* bias_op, u16* Wc_m, float* bias_m){
  const int TOT_OP = 513*CQ;
  const int TOT = TOT_OP + 513*CM;
  for (int idx = blockIdx.x*blockDim.x + threadIdx.x; idx < TOT; idx += gridDim.x*blockDim.x){
    int side, c, f;
    if (idx < TOT_OP){ side = 0; c = idx/CQ; f = idx - c*CQ; }
    else { int j = idx - TOT_OP; side = 1; c = j/CM; f = j - c*CM; }
    int r = f >> 9, fc = f & 511;
    size_t woff = (size_t)(l*2+side)*262144;
    size_t boff = (size_t)(l*2+side)*512;
    float val;
    if (r == 0){
      val = (c < 512) ? Wq[woff + (size_t)c*512 + fc] : bq[boff + fc];
    } else {
      int useK = (side==0) ? (r==1 || r==3) : (r==1);
      const float* W  = useK ? (Wk + woff) : (Wv + woff);
      const float* bb = useK ? (bk + boff) : (bv + boff);
      int rel = (side==0) ? ((r<=2)?0:2) : 1;
      int h = fc >> 6, e2 = fc & 63;
      const float* Rb = (useK ? Ar : Mr) + ((size_t)(l*3+rel)*8 + h)*4096;
      int h64 = h*64;
      float sacc = 0.f;
      for (int dd=0; dd<64; ++dd){
        float wv = (c<512) ? W[(size_t)c*512 + h64 + dd] : bb[h64+dd];
        sacc += wv * Rb[dd*64 + e2];
      }
      val = sacc;
    }
    if (side==0){ if (c<512) Wc_op[(size_t)c*CQ + f] = f2bf(val); else bias_op[f] = val; }
    else        { if (c<512) Wc_m [(size_t)c*CM + f] = f2bf(val); else bias_m [f] = val; }
  }
}

// ---------------- bf16 MFMA GEMM: C[MxN] = (gelu?)A[MxK,f32] @ B[KxN,bf16] (+bias) ----------------
// out_bf16: C is u16 bf16, else f32.
__global__ __launch_bounds__(256) void gemm_bf16(const float* __restrict__ A, const u16* __restrict__ B,
                                                 const float* __restrict__ bias, void* __restrict__ Cp,
                                                 int M, int N, int K, int gelu_a, int out_bf16){
  __shared__ short As[128][40];  // 80B rows = 5x16B: b128 fragment reads stay 16B-aligned
  __shared__ short Bs[64][40];   // stored transposed: Bs[n][k]
  const int tid = threadIdx.x;
  const int bm = blockIdx.y * 128;
  const int bn = blockIdx.x * 64;
  const int lane = tid & 63, wave = tid >> 6;
  const int wm = wave & 1, wn = wave >> 1;
  const int mrow = lane & 15, quad = lane >> 4;
  floatx4 acc[4][2];
  #pragma unroll
  for (int a=0;a<4;++a)
    #pragma unroll
    for (int b=0;b<2;++b) acc[a][b] = (floatx4){0.f,0.f,0.f,0.f};
  for (int k0 = 0; k0 < K; k0 += 32){
    #pragma unroll
    for (int i=0;i<4;++i){            // stage A: 128x32 f32 -> bf16
      int f4 = tid + i*256;
      int r = f4 >> 3, c4 = f4 & 7;
      floatx4 av = *(const floatx4*)(A + (size_t)(bm+r)*K + k0 + c4*4);
      if (gelu_a){
        #pragma unroll
        for (int e=0;e<4;++e) av[e] = geluf(av[e]);
      }
      shortx4 sv;
      #pragma unroll
      for (int e=0;e<4;++e) sv[e] = (short)f2bf(av[e]);
      *(shortx4*)&As[r][c4*4] = sv;
    }
    #pragma unroll
    for (int i=0;i<2;++i){            // stage B: 32x64 bf16, transposed into LDS
      int q4 = tid + i*256;
      int r = q4 >> 4, c4 = q4 & 15;
      ushortx4 bv = *(const ushortx4*)(B + (size_t)(k0+r)*N + bn + c4*4);
      #pragma unroll
      for (int e=0;e<4;++e) Bs[c4*4+e][r] = (short)bv[e];
    }
    __syncthreads();
    shortx8 af[4], bfr[2];
    #pragma unroll
    for (int mt=0;mt<4;++mt) af[mt]  = *(const shortx8*)&As[wm*64 + mt*16 + mrow][quad*8];
    #pragma unroll
    for (int nt=0;nt<2;++nt) bfr[nt] = *(const shortx8*)&Bs[wn*32 + nt*16 + mrow][quad*8];
    #pragma unroll
    for (int mt=0;mt<4;++mt)
      #pragma unroll
      for (int nt=0;nt<2;++nt)
        acc[mt][nt] = __builtin_amdgcn_mfma_f32_16x16x32_bf16(af[mt], bfr[nt], acc[mt][nt], 0, 0, 0);
    __syncthreads();
  }
  #pragma unroll
  for (int mt=0;mt<4;++mt){
    #pragma unroll
    for (int nt=0;nt<2;++nt){
      int col = bn + wn*32 + nt*16 + mrow;
      float bval = bias ? bias[col] : 0.f;
      #pragma unroll
      for (int r=0;r<4;++r){
        int row = bm + wm*64 + mt*16 + quad*4 + r;
        float v = acc[mt][nt][r] + bval;
        if (out_bf16) ((u16*)Cp)[(size_t)row*N + col] = f2bf(v);
        else          ((float*)Cp)[(size_t)row*N + col] = v;
      }
    }
  }
}

// ---------------- attention into op nodes (8 canproc + optional 1 precedes) ----------------
__global__ __launch_bounds__(512) void attn_op_k(const u16* __restrict__ qkv_op, const u16* __restrict__ qkv_m,
                                                 const int* __restrict__ s0, const int* __restrict__ s1,
                                                 const float* __restrict__ prel, float* __restrict__ agg){
  int n = blockIdx.x;
  int h = threadIdx.x >> 6, d = threadIdx.x & 63;
  int hd = h*64 + d;
  float q = bf2f(qkv_op[(size_t)n*CQ + hd]);
  float p0 = prel[h]     * 0.125f;
  float p1 = prel[8 + h] * 0.125f;
  float a[9]; int src[9];
  int i = n & 1023;
  #pragma unroll
  for (int j=0;j<8;++j){
    int m = s1[n*8 + j];
    src[j] = m;
    float t = q * bf2f(qkv_m[(size_t)m*CM + 512 + hd]);
    a[j] = wred(t) * p1;
  }
  bool hasp = (i > 0);
  if (hasp){
    int e0 = (n >> 10)*1023 + i - 1;
    int s = s0[e0];
    src[8] = s;
    float t = q * bf2f(qkv_op[(size_t)s*CQ + 512 + hd]);
    a[8] = wred(t) * p0;
  }
  float mx = a[0];
  #pragma unroll
  for (int j=1;j<8;++j) mx = fmaxf(mx, a[j]);
  if (hasp) mx = fmaxf(mx, a[8]);
  float ssum = 0.f;
  #pragma unroll
  for (int j=0;j<8;++j){ a[j] = expf(a[j]-mx); ssum += a[j]; }
  float e8 = 0.f;
  if (hasp){ e8 = expf(a[8]-mx); ssum += e8; }
  float inv = 1.f/(ssum + 1e-16f);
  float o = 0.f;
  #pragma unroll
  for (int j=0;j<8;++j) o += a[j] * bf2f(qkv_m[(size_t)src[j]*CM + 1024 + hd]);
  if (hasp) o += e8 * bf2f(qkv_op[(size_t)src[8]*CQ + 1024 + hd]);
  agg[(size_t)n*512 + hd] = o * inv;
}

// ---------------- attention into machine nodes (CSR over compat edges) ----------------
__global__ __launch_bounds__(512) void attn_m_k(const u16* __restrict__ qkv_op, const u16* __restrict__ qkv_m,
                                                const int* __restrict__ s2, const int* __restrict__ row_start,
                                                const int* __restrict__ elist, const float* __restrict__ prel,
                                                float* __restrict__ agg){
  __shared__ float abuf[8][512];
  int m = blockIdx.x;
  int h = threadIdx.x >> 6, d = threadIdx.x & 63;
  int hd = h*64 + d;
  int beg = row_start[m];
  int deg = row_start[m+1] - beg;
  if (deg > 512) deg = 512;
  float q = bf2f(qkv_m[(size_t)m*CM + hd]);
  float p2 = prel[16 + h] * 0.125f;
  float mx = -1e30f;
  for (int idx=0; idx<deg; ++idx){
    int e = elist[beg+idx]; int s = s2[e];
    float t = q * bf2f(qkv_op[(size_t)s*CQ + 1536 + hd]);
    t = wred(t) * p2;
    if (d == 0) abuf[h][idx] = t;
    mx = fmaxf(mx, t);
  }
  __syncthreads();   // deg is block-uniform
  float ss = 0.f;
  for (int idx=d; idx<deg; idx+=64){
    float ex = expf(abuf[h][idx] - mx);
    abuf[h][idx] = ex;
    ss += ex;
  }
  ss = wred(ss);
  __syncthreads();
  float inv = 1.f/(ss + 1e-16f);
  float o = 0.f;
  for (int idx=0; idx<deg; ++idx){
    int e = elist[beg+idx]; int s = s2[e];
    o += abuf[h][idx] * bf2f(qkv_op[(size_t)s*CQ + 2048 + hd]);
  }
  agg[(size_t)m*512 + hd] = (deg > 0) ? o * inv : 0.f;
}

// ---------------- final emit (f32 out) + means ----------------
__global__ __launch_bounds__(256) void emit_k(const float* __restrict__ x_op, const float* __restrict__ x_m,
                                              float* __restrict__ out){
  const int T1 = NOPS*512, T2 = T1 + NMS*512;
  for (int i = blockIdx.x*blockDim.x + threadIdx.x; i < T2; i += gridDim.x*blockDim.x){
    out[i] = (i < T1) ? x_op[i] : x_m[i - T1];
  }
}
__global__ __launch_bounds__(512) void meanj_part_k(const float* __restrict__ x_op, float* scratch){
  int b = blockIdx.x, chunk = blockIdx.y, f = threadIdx.x;
  float s = 0.f;
  for (int r=0;r<128;++r){
    int row = b*1024 + chunk*128 + r;
    s += x_op[(size_t)row*512 + f];
  }
  atomicAdd(&scratch[b*512 + f], s);
}
__global__ void meanj_fin_k(const float* scratch, float* out){
  int i = blockIdx.x*blockDim.x + threadIdx.x;
  if (i < 4096) out[4456448 + i] = scratch[i] * (1.f/1024.f);
}
__global__ __launch_bounds__(512) void meanm_k(const float* __restrict__ x_m, float* out){
  int b = blockIdx.x, f = threadIdx.x;
  float s = 0.f;
  for (int r=0;r<64;++r) s += x_m[(size_t)(b*64+r)*512 + f];
  out[4460544 + b*512 + f] = s * (1.f/64.f);
}

extern "C" void kernel_launch(void* const* d_in, const int* in_sizes, int n_in,
                              void* d_out, int out_size, void* d_ws, size_t ws_size,
                              hipStream_t stream){
  const float* op_x      = (const float*)d_in[0];
  const float* machine_x = (const float*)d_in[1];
  const float* W_emb_op  = (const float*)d_in[2];
  const float* b_emb_op  = (const float*)d_in[3];
  const float* W_emb_m   = (const float*)d_in[4];
  const float* b_emb_m   = (const float*)d_in[5];
  const float* opn_w     = (const float*)d_in[6];
  const float* opn_b     = (const float*)d_in[7];
  const float* mn_w      = (const float*)d_in[8];
  const float* mn_b      = (const float*)d_in[9];
  const float* Wk        = (const float*)d_in[10];
  const float* bk        = (const float*)d_in[11];
  const float* Wq        = (const float*)d_in[12];
  const float* bq        = (const float*)d_in[13];
  const float* Wv        = (const float*)d_in[14];
  const float* bv        = (const float*)d_in[15];
  const float* A_rel     = (const float*)d_in[16];
  const float* M_rel     = (const float*)d_in[17];
  const float* p_rel     = (const float*)d_in[18];
  const float* W_out     = (const float*)d_in[19];
  const float* b_out     = (const float*)d_in[20];
  const float* skip      = (const float*)d_in[21];
  const float* ln_w      = (const float*)d_in[22];
  const float* ln_b      = (const float*)d_in[23];
  const int* s0          = (const int*)d_in[24];  // precedes src row
  const int* s1          = (const int*)d_in[25];  // canproc src row (machines)
  const int* s2          = (const int*)d_in[26];  // compat src row (ops)
  const int* d2          = s2 + NE2;              // compat dst row (machines)
  float* out = (float*)d_out;

  char* ws = (char*)d_ws;
  size_t off = 0;
  auto alloc = [&](size_t bytes)->void*{
    void* p = ws + off;
    off = (off + bytes + 255) & ~(size_t)255;
    return p;
  };
  float* accb      = (float*)alloc(64*4);
  int*   counts    = (int*)  alloc(512*4);
  int*   row_start = (int*)  alloc(513*4);
  int*   cursor    = (int*)  alloc(512*4);
  int*   elist     = (int*)  alloc((size_t)NE2*4);
  float* scratch   = (float*)alloc(4096*4);
  float* x_op      = (float*)alloc((size_t)NOPS*512*4);
  float* x_m       = (float*)alloc((size_t)NMS*512*4);
  u16*   qkv_op    = (u16*)  alloc((size_t)NOPS*CQ*2);   // 40MB; o_op (16MB f32) aliases it
  u16*   qkv_m     = (u16*)  alloc((size_t)NMS*CM*2);    // 1.5MB; o_m (1MB f32) aliases it
  float* agg_op    = (float*)alloc((size_t)NOPS*512*4);
  float* agg_m     = (float*)alloc((size_t)NMS*512*4);
  u16*   Wc_op     = (u16*)  alloc((size_t)512*CQ*2);
  float* bias_op   = (float*)alloc(CQ*4);
  u16*   Wc_m      = (u16*)  alloc((size_t)512*CM*2);
  float* bias_m    = (float*)alloc(CM*4);
  u16*   Wout_bf   = (u16*)  alloc((size_t)512*512*2);   // per-use converted W_out block
  float* o_op      = (float*)qkv_op;   // alias: qkv dead once attn done
  float* o_m       = (float*)qkv_m;

  const int TOP = NOPS*512;   // 4194304
  const int TM  = NMS*512;    // 262144

  // setup: zero accumulators, build machine CSR
  zero_ws_k<<<16,256,0,stream>>>(accb, counts, scratch);
  csr_count_k<<<256,256,0,stream>>>(d2, counts);
  csr_scan_k<<<1,512,0,stream>>>(counts, row_start, cursor);
  csr_scatter_k<<<256,256,0,stream>>>(d2, cursor, elist);

  // embeddings + graph LN
  embed_k<<<2048,256,0,stream>>>(op_x, W_emb_op, b_emb_op, x_op, TOP, 16, accb + 0);
  embed_k<<<256,256,0,stream>>>(machine_x, W_emb_m, b_emb_m, x_m, TM, 8, accb + 2);
  ln_apply_k<<<2048,256,0,stream>>>(x_op, x_op, opn_w, opn_b, accb + 0, 1.f/TOP, TOP);
  ln_apply_k<<<256,256,0,stream>>>(x_m, x_m, mn_w, mn_b, accb + 2, 1.f/TM, TM);

  for (int l=0; l<3; ++l){
    combine_k<<<1024,256,0,stream>>>(Wk,bk,Wq,bq,Wv,bv,A_rel,M_rel,l,Wc_op,bias_op,Wc_m,bias_m);
    dim3 g1(CQ/64, NOPS/128);
    gemm_bf16<<<g1,256,0,stream>>>(x_op, Wc_op, bias_op, qkv_op, NOPS, CQ, 512, 0, 1);
    dim3 g2(CM/64, NMS/128);
    gemm_bf16<<<g2,256,0,stream>>>(x_m, Wc_m, bias_m, qkv_m, NMS, CM, 512, 0, 1);
    attn_op_k<<<NOPS,512,0,stream>>>(qkv_op, qkv_m, s0, s1, p_rel + l*24, agg_op);
    attn_m_k<<<NMS,512,0,stream>>>(qkv_op, qkv_m, s2, row_start, elist, p_rel + l*24, agg_m);
    // op-side output projection
    cvt_bf16_k<<<512,256,0,stream>>>(W_out + (size_t)(l*2+0)*262144, Wout_bf, 262144);
    dim3 g3(512/64, NOPS/128);
    gemm_bf16<<<g3,256,0,stream>>>(agg_op, Wout_bf, nullptr, o_op, NOPS, 512, 512, 1, 0);
    gate_res_k<<<2048,256,0,stream>>>(o_op, x_op, b_out + (size_t)(l*2+0)*512, skip + l*2+0, accb + 2*(2+2*l), TOP);
    // machine-side output projection
    cvt_bf16_k<<<512,256,0,stream>>>(W_out + (size_t)(l*2+1)*262144, Wout_bf, 262144);
    dim3 g4(512/64, NMS/128);
    gemm_bf16<<<g4,256,0,stream>>>(agg_m, Wout_bf, nullptr, o_m, NMS, 512, 512, 1, 0);
    gate_res_k<<<256,256,0,stream>>>(o_m, x_m, b_out + (size_t)(l*2+1)*512, skip + l*2+1, accb + 2*(3+2*l), TM);
    ln_apply_k<<<2048,256,0,stream>>>(o_op, x_op, ln_w + l*512, ln_b + l*512, accb + 2*(2+2*l), 1.f/TOP, TOP);
    ln_apply_k<<<256,256,0,stream>>>(o_m, x_m, ln_w + l*512, ln_b + l*512, accb + 2*(3+2*l), 1.f/TM, TM);
  }

  emit_k<<<2048,256,0,stream>>>(x_op, x_m, out);
  meanj_part_k<<<dim3(8,8),512,0,stream>>>(x_op, scratch);
  meanj_fin_k<<<16,256,0,stream>>>(scratch, out);
  meanm_k<<<8,512,0,stream>>>(x_m, out);
}

// Round 4
// 1488.175 us; speedup vs baseline: 1.6117x; 1.6117x over previous
//
#include <hip/hip_runtime.h>

typedef unsigned short u16;
typedef __attribute__((ext_vector_type(4))) float floatx4;
typedef __attribute__((ext_vector_type(8))) short shortx8;
typedef __attribute__((ext_vector_type(4))) short shortx4;
typedef __attribute__((ext_vector_type(4))) unsigned short ushortx4;

#define NOPS 8192
#define NMS  512
#define FDIM 512
#define CQ   2560   // op qkv cols: q | k0 | v0 | k2 | v2
#define CM   1536   // machine qkv cols: q | k1 | v1
#define NE2  65536

__device__ __forceinline__ float bf2f(u16 u){ return __uint_as_float(((unsigned)u)<<16); }
__device__ __forceinline__ u16 f2bf(float f){
  unsigned u = __float_as_uint(f);
  u += 0x7FFFu + ((u>>16)&1u);
  return (u16)(u>>16);
}
__device__ __forceinline__ float wred(float v){
  #pragma unroll
  for (int o=32;o;o>>=1) v += __shfl_xor(v,o,64);
  return v;
}
__device__ __forceinline__ float geluf(float x){
  return 0.5f*x*(1.f+erff(x*0.70710678118654752f));
}
// block-level (s,s2) reduction -> one pair per block (no global same-address atomics)
__device__ __forceinline__ void block_stat_out(float s, float s2, float* pstat){
  __shared__ float sb[8];
  s = wred(s); s2 = wred(s2);
  int wv = threadIdx.x >> 6;
  if ((threadIdx.x & 63) == 0){ sb[wv*2] = s; sb[wv*2+1] = s2; }
  __syncthreads();
  if (threadIdx.x == 0){
    float a = 0.f, b = 0.f;
    int nw = blockDim.x >> 6;
    for (int i=0;i<nw;++i){ a += sb[i*2]; b += sb[i*2+1]; }
    pstat[blockIdx.x*2]   = a;
    pstat[blockIdx.x*2+1] = b;
  }
}

// ---------------- zero small ws regions ----------------
__global__ void zero_ws_k(float* acc, int* counts, float* scratch){
  int i = blockIdx.x*blockDim.x + threadIdx.x;
  if (i < 64)   acc[i] = 0.f;
  if (i < 512)  counts[i] = 0;
  if (i < 4096) scratch[i] = 0.f;
}

// ---------------- CSR build for compat edges (dst = machine) ----------------
__global__ void csr_count_k(const int* __restrict__ d2, int* counts){
  int e = blockIdx.x*blockDim.x + threadIdx.x;
  if (e < NE2) atomicAdd(&counts[d2[e]], 1);
}
__global__ __launch_bounds__(512) void csr_scan_k(const int* counts, int* row_start, int* cursor){
  __shared__ int sd[512];
  int t = threadIdx.x;
  sd[t] = counts[t];
  __syncthreads();
  for (int off=1; off<512; off<<=1){
    int v = (t >= off) ? sd[t-off] : 0;
    __syncthreads();
    sd[t] += v;
    __syncthreads();
  }
  row_start[t+1] = sd[t];
  if (t==0) row_start[0] = 0;
  cursor[t] = sd[t] - counts[t];
}
__global__ void csr_scatter_k(const int* __restrict__ d2, int* cursor, int* elist){
  int e = blockIdx.x*blockDim.x + threadIdx.x;
  if (e < NE2){
    int pos = atomicAdd(&cursor[d2[e]], 1);
    elist[pos] = e;
  }
}

// ---------------- f32 -> bf16 convert (for W_out) ----------------
__global__ __launch_bounds__(256) void cvt_bf16_k(const float* __restrict__ src, u16* __restrict__ dst, int total){
  for (int i = blockIdx.x*blockDim.x + threadIdx.x; i < total; i += gridDim.x*blockDim.x)
    dst[i] = f2bf(src[i]);
}

// ---------------- embedding GEMM (tiny K, f32 in) + per-block LN partials ----------------
__global__ __launch_bounds__(256) void embed_k(const float* __restrict__ X, const float* __restrict__ W,
                                               const float* __restrict__ bias, float* __restrict__ Y,
                                               int total, int K, float* pstat){
  float s = 0.f, s2 = 0.f;
  for (int idx = blockIdx.x*blockDim.x + threadIdx.x; idx < total; idx += gridDim.x*blockDim.x){
    int n = idx >> 9, f = idx & 511;
    float v = bias[f];
    for (int c=0;c<K;++c) v += X[n*K+c] * W[c*512+f];
    Y[idx] = v;
    s += v; s2 += v*v;
  }
  block_stat_out(s, s2, pstat);
}

// ---------------- stats finalize: (Σ,Σ²) partials -> mean, 1/(std+eps) ----------------
__global__ __launch_bounds__(256) void reduce_stats_k(const float* __restrict__ pstat, int nblk,
                                                      float inv_n, float* acc){
  float s = 0.f, s2 = 0.f;
  for (int i = threadIdx.x; i < nblk; i += 256){ s += pstat[2*i]; s2 += pstat[2*i+1]; }
  __shared__ float sb[8];
  s = wred(s); s2 = wred(s2);
  int wv = threadIdx.x >> 6;
  if ((threadIdx.x & 63) == 0){ sb[wv*2] = s; sb[wv*2+1] = s2; }
  __syncthreads();
  if (threadIdx.x == 0){
    float a = 0.f, b = 0.f;
    for (int i=0;i<4;++i){ a += sb[i*2]; b += sb[i*2+1]; }
    float mean = a * inv_n;
    float var  = fmaxf(b * inv_n - mean*mean, 0.f);
    acc[0] = mean;
    acc[1] = 1.f/(sqrtf(var) + 1e-5f);
  }
}

// ---------------- graph-LN apply (vectorized, mean/rinv precomputed) ----------------
__global__ __launch_bounds__(256) void ln_apply_k(const float* __restrict__ src, float* __restrict__ dst,
                                                  const float* __restrict__ w, const float* __restrict__ b,
                                                  const float* acc, int total4){
  float mean = acc[0], rinv = acc[1];
  const floatx4* s4 = (const floatx4*)src;
  floatx4* d4 = (floatx4*)dst;
  const floatx4* w4 = (const floatx4*)w;
  const floatx4* b4 = (const floatx4*)b;
  for (int i = blockIdx.x*blockDim.x + threadIdx.x; i < total4; i += gridDim.x*blockDim.x){
    int f = i & 127;
    floatx4 v = s4[i], wv = w4[f], bv = b4[f];
    #pragma unroll
    for (int e=0;e<4;++e) v[e] = (v[e]-mean)*rinv*wv[e] + bv[e];
    d4[i] = v;
  }
}

// ---------------- gated residual (vectorized) + per-block LN partials ----------------
__global__ __launch_bounds__(256) void gate_res_k(float* __restrict__ y, const float* __restrict__ x,
                                                  const float* __restrict__ bout, const float* __restrict__ skipel,
                                                  float* pstat, int total4){
  float g = 1.f/(1.f+expf(-(*skipel)));
  floatx4* y4 = (floatx4*)y;
  const floatx4* x4 = (const floatx4*)x;
  const floatx4* b4 = (const floatx4*)bout;
  float s = 0.f, s2 = 0.f;
  for (int i = blockIdx.x*blockDim.x + threadIdx.x; i < total4; i += gridDim.x*blockDim.x){
    floatx4 yv = y4[i], xv = x4[i], bv = b4[i & 127];
    #pragma unroll
    for (int e=0;e<4;++e){
      float o = g*(yv[e]+bv[e]) + (2.f-g)*xv[e];  // gated skip + wrapper residual
      yv[e] = o;
      s += o; s2 += o*o;
    }
    y4[i] = yv;
  }
  block_stat_out(s, s2, pstat);
}

// ---------------- per-layer combined weights: W' = W @ blockdiag(Rel), b' = b @ Rel ----------------
__global__ __launch_bounds__(256) void combine_k(const float* Wk, const float* bk, const float* Wq, const float* bq,
                                                 const float* Wv, const float* bv, const float* Ar, const float* Mr,
                                                 int l, u16* Wc_op, float* bias_op, u16* Wc_m, float* bias_m){
  const int TOT_OP = 513*CQ;
  const int TOT = TOT_OP + 513*CM;
  for (int idx = blockIdx.x*blockDim.x + threadIdx.x; idx < TOT; idx += gridDim.x*blockDim.x){
    int side, c, f;
    if (idx < TOT_OP){ side = 0; c = idx/CQ; f = idx - c*CQ; }
    else { int j = idx - TOT_OP; side = 1; c = j/CM; f = j - c*CM; }
    int r = f >> 9, fc = f & 511;
    size_t woff = (size_t)(l*2+side)*262144;
    size_t boff = (size_t)(l*2+side)*512;
    float val;
    if (r == 0){
      val = (c < 512) ? Wq[woff + (size_t)c*512 + fc] : bq[boff + fc];
    } else {
      int useK = (side==0) ? (r==1 || r==3) : (r==1);
      const float* W  = useK ? (Wk + woff) : (Wv + woff);
      const float* bb = useK ? (bk + boff) : (bv + boff);
      int rel = (side==0) ? ((r<=2)?0:2) : 1;
      int h = fc >> 6, e2 = fc & 63;
      const float* Rb = (useK ? Ar : Mr) + ((size_t)(l*3+rel)*8 + h)*4096;
      int h64 = h*64;
      float sacc = 0.f;
      for (int dd=0; dd<64; ++dd){
        float wv = (c<512) ? W[(size_t)c*512 + h64 + dd] : bb[h64+dd];
        sacc += wv * Rb[dd*64 + e2];
      }
      val = sacc;
    }
    if (side==0){ if (c<512) Wc_op[(size_t)c*CQ + f] = f2bf(val); else bias_op[f] = val; }
    else        { if (c<512) Wc_m [(size_t)c*CM + f] = f2bf(val); else bias_m [f] = val; }
  }
}

// ---------------- bf16 MFMA GEMM: C[MxN] = (gelu?)A[MxK,f32] @ B[KxN,bf16] (+bias) ----------------
// out_bf16: C is u16 bf16, else f32.
__global__ __launch_bounds__(256) void gemm_bf16(const float* __restrict__ A, const u16* __restrict__ B,
                                                 const float* __restrict__ bias, void* __restrict__ Cp,
                                                 int M, int N, int K, int gelu_a, int out_bf16){
  __shared__ short As[128][40];  // 80B rows = 5x16B: b128 fragment reads stay 16B-aligned
  __shared__ short Bs[64][40];   // stored transposed: Bs[n][k]
  const int tid = threadIdx.x;
  const int bm = blockIdx.y * 128;
  const int bn = blockIdx.x * 64;
  const int lane = tid & 63, wave = tid >> 6;
  const int wm = wave & 1, wn = wave >> 1;
  const int mrow = lane & 15, quad = lane >> 4;
  floatx4 acc[4][2];
  #pragma unroll
  for (int a=0;a<4;++a)
    #pragma unroll
    for (int b=0;b<2;++b) acc[a][b] = (floatx4){0.f,0.f,0.f,0.f};
  for (int k0 = 0; k0 < K; k0 += 32){
    #pragma unroll
    for (int i=0;i<4;++i){            // stage A: 128x32 f32 -> bf16
      int f4 = tid + i*256;
      int r = f4 >> 3, c4 = f4 & 7;
      floatx4 av = *(const floatx4*)(A + (size_t)(bm+r)*K + k0 + c4*4);
      if (gelu_a){
        #pragma unroll
        for (int e=0;e<4;++e) av[e] = geluf(av[e]);
      }
      shortx4 sv;
      #pragma unroll
      for (int e=0;e<4;++e) sv[e] = (short)f2bf(av[e]);
      *(shortx4*)&As[r][c4*4] = sv;
    }
    #pragma unroll
    for (int i=0;i<2;++i){            // stage B: 32x64 bf16, transposed into LDS
      int q4 = tid + i*256;
      int r = q4 >> 4, c4 = q4 & 15;
      ushortx4 bv = *(const ushortx4*)(B + (size_t)(k0+r)*N + bn + c4*4);
      #pragma unroll
      for (int e=0;e<4;++e) Bs[c4*4+e][r] = (short)bv[e];
    }
    __syncthreads();
    shortx8 af[4], bfr[2];
    #pragma unroll
    for (int mt=0;mt<4;++mt) af[mt]  = *(const shortx8*)&As[wm*64 + mt*16 + mrow][quad*8];
    #pragma unroll
    for (int nt=0;nt<2;++nt) bfr[nt] = *(const shortx8*)&Bs[wn*32 + nt*16 + mrow][quad*8];
    #pragma unroll
    for (int mt=0;mt<4;++mt)
      #pragma unroll
      for (int nt=0;nt<2;++nt)
        acc[mt][nt] = __builtin_amdgcn_mfma_f32_16x16x32_bf16(af[mt], bfr[nt], acc[mt][nt], 0, 0, 0);
    __syncthreads();
  }
  #pragma unroll
  for (int mt=0;mt<4;++mt){
    #pragma unroll
    for (int nt=0;nt<2;++nt){
      int col = bn + wn*32 + nt*16 + mrow;
      float bval = bias ? bias[col] : 0.f;
      #pragma unroll
      for (int r=0;r<4;++r){
        int row = bm + wm*64 + mt*16 + quad*4 + r;
        float v = acc[mt][nt][r] + bval;
        if (out_bf16) ((u16*)Cp)[(size_t)row*N + col] = f2bf(v);
        else          ((float*)Cp)[(size_t)row*N + col] = v;
      }
    }
  }
}

// ---------------- attention into op nodes (8 canproc + optional 1 precedes) ----------------
__global__ __launch_bounds__(512) void attn_op_k(const u16* __restrict__ qkv_op, const u16* __restrict__ qkv_m,
                                                 const int* __restrict__ s0, const int* __restrict__ s1,
                                                 const float* __restrict__ prel, float* __restrict__ agg){
  int n = blockIdx.x;
  int h = threadIdx.x >> 6, d = threadIdx.x & 63;
  int hd = h*64 + d;
  float q = bf2f(qkv_op[(size_t)n*CQ + hd]);
  float p0 = prel[h]     * 0.125f;
  float p1 = prel[8 + h] * 0.125f;
  float a[9]; int src[9];
  int i = n & 1023;
  #pragma unroll
  for (int j=0;j<8;++j){
    int m = s1[n*8 + j];
    src[j] = m;
    float t = q * bf2f(qkv_m[(size_t)m*CM + 512 + hd]);
    a[j] = wred(t) * p1;
  }
  bool hasp = (i > 0);
  if (hasp){
    int e0 = (n >> 10)*1023 + i - 1;
    int s = s0[e0];
    src[8] = s;
    float t = q * bf2f(qkv_op[(size_t)s*CQ + 512 + hd]);
    a[8] = wred(t) * p0;
  }
  float mx = a[0];
  #pragma unroll
  for (int j=1;j<8;++j) mx = fmaxf(mx, a[j]);
  if (hasp) mx = fmaxf(mx, a[8]);
  float ssum = 0.f;
  #pragma unroll
  for (int j=0;j<8;++j){ a[j] = expf(a[j]-mx); ssum += a[j]; }
  float e8 = 0.f;
  if (hasp){ e8 = expf(a[8]-mx); ssum += e8; }
  float inv = 1.f/(ssum + 1e-16f);
  float o = 0.f;
  #pragma unroll
  for (int j=0;j<8;++j) o += a[j] * bf2f(qkv_m[(size_t)src[j]*CM + 1024 + hd]);
  if (hasp) o += e8 * bf2f(qkv_op[(size_t)src[8]*CQ + 1024 + hd]);
  agg[(size_t)n*512 + hd] = o * inv;
}

// ---------------- attention into machine nodes (CSR over compat edges) ----------------
__global__ __launch_bounds__(512) void attn_m_k(const u16* __restrict__ qkv_op, const u16* __restrict__ qkv_m,
                                                const int* __restrict__ s2, const int* __restrict__ row_start,
                                                const int* __restrict__ elist, const float* __restrict__ prel,
                                                float* __restrict__ agg){
  __shared__ float abuf[8][512];
  int m = blockIdx.x;
  int h = threadIdx.x >> 6, d = threadIdx.x & 63;
  int hd = h*64 + d;
  int beg = row_start[m];
  int deg = row_start[m+1] - beg;
  if (deg > 512) deg = 512;
  float q = bf2f(qkv_m[(size_t)m*CM + hd]);
  float p2 = prel[16 + h] * 0.125f;
  float mx = -1e30f;
  for (int idx=0; idx<deg; ++idx){
    int e = elist[beg+idx]; int s = s2[e];
    float t = q * bf2f(qkv_op[(size_t)s*CQ + 1536 + hd]);
    t = wred(t) * p2;
    if (d == 0) abuf[h][idx] = t;
    mx = fmaxf(mx, t);
  }
  __syncthreads();   // deg is block-uniform
  float ss = 0.f;
  for (int idx=d; idx<deg; idx+=64){
    float ex = expf(abuf[h][idx] - mx);
    abuf[h][idx] = ex;
    ss += ex;
  }
  ss = wred(ss);
  __syncthreads();
  float inv = 1.f/(ss + 1e-16f);
  float o = 0.f;
  for (int idx=0; idx<deg; ++idx){
    int e = elist[beg+idx]; int s = s2[e];
    o += abuf[h][idx] * bf2f(qkv_op[(size_t)s*CQ + 2048 + hd]);
  }
  agg[(size_t)m*512 + hd] = (deg > 0) ? o * inv : 0.f;
}

// ---------------- final emit (f32 out, vectorized) + means ----------------
__global__ __launch_bounds__(256) void emit_k(const float* __restrict__ x_op, const float* __restrict__ x_m,
                                              float* __restrict__ out){
  const int T1 = NOPS*128, T2 = T1 + NMS*128;   // in float4 units
  const floatx4* a4 = (const floatx4*)x_op;
  const floatx4* b4 = (const floatx4*)x_m;
  floatx4* o4 = (floatx4*)out;
  for (int i = blockIdx.x*blockDim.x + threadIdx.x; i < T2; i += gridDim.x*blockDim.x){
    o4[i] = (i < T1) ? a4[i] : b4[i - T1];
  }
}
__global__ __launch_bounds__(512) void meanj_part_k(const float* __restrict__ x_op, float* scratch){
  int b = blockIdx.x, chunk = blockIdx.y, f = threadIdx.x;
  float s = 0.f;
  for (int r=0;r<128;++r){
    int row = b*1024 + chunk*128 + r;
    s += x_op[(size_t)row*512 + f];
  }
  atomicAdd(&scratch[b*512 + f], s);
}
__global__ void meanj_fin_k(const float* scratch, float* out){
  int i = blockIdx.x*blockDim.x + threadIdx.x;
  if (i < 4096) out[4456448 + i] = scratch[i] * (1.f/1024.f);
}
__global__ __launch_bounds__(512) void meanm_k(const float* __restrict__ x_m, float* out){
  int b = blockIdx.x, f = threadIdx.x;
  float s = 0.f;
  for (int r=0;r<64;++r) s += x_m[(size_t)(b*64+r)*512 + f];
  out[4460544 + b*512 + f] = s * (1.f/64.f);
}

extern "C" void kernel_launch(void* const* d_in, const int* in_sizes, int n_in,
                              void* d_out, int out_size, void* d_ws, size_t ws_size,
                              hipStream_t stream){
  const float* op_x      = (const float*)d_in[0];
  const float* machine_x = (const float*)d_in[1];
  const float* W_emb_op  = (const float*)d_in[2];
  const float* b_emb_op  = (const float*)d_in[3];
  const float* W_emb_m   = (const float*)d_in[4];
  const float* b_emb_m   = (const float*)d_in[5];
  const float* opn_w     = (const float*)d_in[6];
  const float* opn_b     = (const float*)d_in[7];
  const float* mn_w      = (const float*)d_in[8];
  const float* mn_b      = (const float*)d_in[9];
  const float* Wk        = (const float*)d_in[10];
  const float* bk        = (const float*)d_in[11];
  const float* Wq        = (const float*)d_in[12];
  const float* bq        = (const float*)d_in[13];
  const float* Wv        = (const float*)d_in[14];
  const float* bv        = (const float*)d_in[15];
  const float* A_rel     = (const float*)d_in[16];
  const float* M_rel     = (const float*)d_in[17];
  const float* p_rel     = (const float*)d_in[18];
  const float* W_out     = (const float*)d_in[19];
  const float* b_out     = (const float*)d_in[20];
  const float* skip      = (const float*)d_in[21];
  const float* ln_w      = (const float*)d_in[22];
  const float* ln_b      = (const float*)d_in[23];
  const int* s0          = (const int*)d_in[24];  // precedes src row
  const int* s1          = (const int*)d_in[25];  // canproc src row (machines)
  const int* s2          = (const int*)d_in[26];  // compat src row (ops)
  const int* d2          = s2 + NE2;              // compat dst row (machines)
  float* out = (float*)d_out;

  char* ws = (char*)d_ws;
  size_t off = 0;
  auto alloc = [&](size_t bytes)->void*{
    void* p = ws + off;
    off = (off + bytes + 255) & ~(size_t)255;
    return p;
  };
  float* accb      = (float*)alloc(64*4);
  int*   counts    = (int*)  alloc(512*4);
  int*   row_start = (int*)  alloc(513*4);
  int*   cursor    = (int*)  alloc(512*4);
  int*   elist     = (int*)  alloc((size_t)NE2*4);
  float* scratch   = (float*)alloc(4096*4);
  float* pstat     = (float*)alloc(4096*4);      // per-block (s,s2) partials
  float* x_op      = (float*)alloc((size_t)NOPS*512*4);
  float* x_m       = (float*)alloc((size_t)NMS*512*4);
  u16*   qkv_op    = (u16*)  alloc((size_t)NOPS*CQ*2);   // 40MB; o_op (16MB f32) aliases it
  u16*   qkv_m     = (u16*)  alloc((size_t)NMS*CM*2);    // 1.5MB; o_m (1MB f32) aliases it
  float* agg_op    = (float*)alloc((size_t)NOPS*512*4);
  float* agg_m     = (float*)alloc((size_t)NMS*512*4);
  u16*   Wc_op     = (u16*)  alloc((size_t)512*CQ*2);
  float* bias_op   = (float*)alloc(CQ*4);
  u16*   Wc_m      = (u16*)  alloc((size_t)512*CM*2);
  float* bias_m    = (float*)alloc(CM*4);
  u16*   Wout_bf   = (u16*)  alloc((size_t)512*512*2);   // per-use converted W_out block
  float* o_op      = (float*)qkv_op;   // alias: qkv dead once attn done
  float* o_m       = (float*)qkv_m;
  float* pstat_m   = pstat + 2048;     // machine-side partial region

  const int TOP = NOPS*512;   // 4194304
  const int TM  = NMS*512;    // 262144
  const int T4OP = TOP/4, T4M = TM/4;
  const int GB_OP = 1024, GB_M = 128; // stat-kernel grids (pstat slots)

  // setup: zero accumulators, build machine CSR
  zero_ws_k<<<16,256,0,stream>>>(accb, counts, scratch);
  csr_count_k<<<256,256,0,stream>>>(d2, counts);
  csr_scan_k<<<1,512,0,stream>>>(counts, row_start, cursor);
  csr_scatter_k<<<256,256,0,stream>>>(d2, cursor, elist);

  // embeddings + graph LN
  embed_k<<<GB_OP,256,0,stream>>>(op_x, W_emb_op, b_emb_op, x_op, TOP, 16, pstat);
  embed_k<<<GB_M,256,0,stream>>>(machine_x, W_emb_m, b_emb_m, x_m, TM, 8, pstat_m);
  reduce_stats_k<<<1,256,0,stream>>>(pstat,   GB_OP, 1.f/TOP, accb + 0);
  reduce_stats_k<<<1,256,0,stream>>>(pstat_m, GB_M,  1.f/TM,  accb + 2);
  ln_apply_k<<<1024,256,0,stream>>>(x_op, x_op, opn_w, opn_b, accb + 0, T4OP);
  ln_apply_k<<<128,256,0,stream>>>(x_m, x_m, mn_w, mn_b, accb + 2, T4M);

  for (int l=0; l<3; ++l){
    combine_k<<<1024,256,0,stream>>>(Wk,bk,Wq,bq,Wv,bv,A_rel,M_rel,l,Wc_op,bias_op,Wc_m,bias_m);
    dim3 g1(CQ/64, NOPS/128);
    gemm_bf16<<<g1,256,0,stream>>>(x_op, Wc_op, bias_op, qkv_op, NOPS, CQ, 512, 0, 1);
    dim3 g2(CM/64, NMS/128);
    gemm_bf16<<<g2,256,0,stream>>>(x_m, Wc_m, bias_m, qkv_m, NMS, CM, 512, 0, 1);
    attn_op_k<<<NOPS,512,0,stream>>>(qkv_op, qkv_m, s0, s1, p_rel + l*24, agg_op);
    attn_m_k<<<NMS,512,0,stream>>>(qkv_op, qkv_m, s2, row_start, elist, p_rel + l*24, agg_m);
    // op-side output projection
    cvt_bf16_k<<<512,256,0,stream>>>(W_out + (size_t)(l*2+0)*262144, Wout_bf, 262144);
    dim3 g3(512/64, NOPS/128);
    gemm_bf16<<<g3,256,0,stream>>>(agg_op, Wout_bf, nullptr, o_op, NOPS, 512, 512, 1, 0);
    gate_res_k<<<GB_OP,256,0,stream>>>(o_op, x_op, b_out + (size_t)(l*2+0)*512, skip + l*2+0, pstat, T4OP);
    // machine-side output projection
    cvt_bf16_k<<<512,256,0,stream>>>(W_out + (size_t)(l*2+1)*262144, Wout_bf, 262144);
    dim3 g4(512/64, NMS/128);
    gemm_bf16<<<g4,256,0,stream>>>(agg_m, Wout_bf, nullptr, o_m, NMS, 512, 512, 1, 0);
    gate_res_k<<<GB_M,256,0,stream>>>(o_m, x_m, b_out + (size_t)(l*2+1)*512, skip + l*2+1, pstat_m, T4M);
    reduce_stats_k<<<1,256,0,stream>>>(pstat,   GB_OP, 1.f/TOP, accb + 2*(2+2*l));
    reduce_stats_k<<<1,256,0,stream>>>(pstat_m, GB_M,  1.f/TM,  accb + 2*(3+2*l));
    ln_apply_k<<<1024,256,0,stream>>>(o_op, x_op, ln_w + l*512, ln_b + l*512, accb + 2*(2+2*l), T4OP);
    ln_apply_k<<<128,256,0,stream>>>(o_m, x_m, ln_w + l*512, ln_b + l*512, accb + 2*(3+2*l), T4M);
  }

  emit_k<<<2048,256,0,stream>>>(x_op, x_m, out);
  meanj_part_k<<<dim3(8,8),512,0,stream>>>(x_op, scratch);
  meanj_fin_k<<<16,256,0,stream>>>(scratch, out);
  meanm_k<<<8,512,0,stream>>>(x_m, out);
}

// Round 5
// 1292.509 us; speedup vs baseline: 1.8557x; 1.1514x over previous
//
#include <hip/hip_runtime.h>

typedef unsigned short u16;
typedef __attribute__((ext_vector_type(4))) float floatx4;
typedef __attribute__((ext_vector_type(8))) short shortx8;
typedef __attribute__((ext_vector_type(4))) short shortx4;
typedef __attribute__((ext_vector_type(4))) unsigned short ushortx4;

#define NOPS 8192
#define NMS  512
#define FDIM 512
#define CQ   2560   // op qkv cols: q | k0 | v0 | k2 | v2
#define CM   1536   // machine qkv cols: q | k1 | v1
#define NE2  65536
#define MSPLIT 8

__device__ __forceinline__ float bf2f(u16 u){ return __uint_as_float(((unsigned)u)<<16); }
__device__ __forceinline__ u16 f2bf(float f){
  unsigned u = __float_as_uint(f);
  u += 0x7FFFu + ((u>>16)&1u);
  return (u16)(u>>16);
}
__device__ __forceinline__ float wred(float v){
  #pragma unroll
  for (int o=32;o;o>>=1) v += __shfl_xor(v,o,64);
  return v;
}
__device__ __forceinline__ float geluf(float x){
  return 0.5f*x*(1.f+erff(x*0.70710678118654752f));
}
// block-level (s,s2) reduction -> one pair per block (no global same-address atomics)
__device__ __forceinline__ void block_stat_out(float s, float s2, float* pstat){
  __shared__ float sb[8];
  s = wred(s); s2 = wred(s2);
  int wv = threadIdx.x >> 6;
  if ((threadIdx.x & 63) == 0){ sb[wv*2] = s; sb[wv*2+1] = s2; }
  __syncthreads();
  if (threadIdx.x == 0){
    float a = 0.f, b = 0.f;
    int nw = blockDim.x >> 6;
    for (int i=0;i<nw;++i){ a += sb[i*2]; b += sb[i*2+1]; }
    pstat[blockIdx.x*2]   = a;
    pstat[blockIdx.x*2+1] = b;
  }
}

// ---------------- zero small ws regions ----------------
__global__ void zero_ws_k(float* acc, int* counts, float* scratch){
  int i = blockIdx.x*blockDim.x + threadIdx.x;
  if (i < 64)   acc[i] = 0.f;
  if (i < 512)  counts[i] = 0;
  if (i < 4096) scratch[i] = 0.f;
}

// ---------------- CSR build for compat edges (dst = machine) ----------------
__global__ void csr_count_k(const int* __restrict__ d2, int* counts){
  int e = blockIdx.x*blockDim.x + threadIdx.x;
  if (e < NE2) atomicAdd(&counts[d2[e]], 1);
}
__global__ __launch_bounds__(512) void csr_scan_k(const int* counts, int* row_start, int* cursor){
  __shared__ int sd[512];
  int t = threadIdx.x;
  sd[t] = counts[t];
  __syncthreads();
  for (int off=1; off<512; off<<=1){
    int v = (t >= off) ? sd[t-off] : 0;
    __syncthreads();
    sd[t] += v;
    __syncthreads();
  }
  row_start[t+1] = sd[t];
  if (t==0) row_start[0] = 0;
  cursor[t] = sd[t] - counts[t];
}
__global__ void csr_scatter_k(const int* __restrict__ d2, int* cursor, int* elist){
  int e = blockIdx.x*blockDim.x + threadIdx.x;
  if (e < NE2){
    int pos = atomicAdd(&cursor[d2[e]], 1);
    elist[pos] = e;
  }
}

// ---------------- f32 -> bf16 convert (for W_out, all 6 blocks at once) ----------------
__global__ __launch_bounds__(256) void cvt_bf16_k(const float* __restrict__ src, u16* __restrict__ dst, int total){
  for (int i = blockIdx.x*blockDim.x + threadIdx.x; i < total; i += gridDim.x*blockDim.x)
    dst[i] = f2bf(src[i]);
}

// ---------------- embedding GEMM (tiny K, f32 in) + per-block LN partials ----------------
__global__ __launch_bounds__(256) void embed_k(const float* __restrict__ X, const float* __restrict__ W,
                                               const float* __restrict__ bias, float* __restrict__ Y,
                                               int total, int K, float* pstat){
  float s = 0.f, s2 = 0.f;
  for (int idx = blockIdx.x*blockDim.x + threadIdx.x; idx < total; idx += gridDim.x*blockDim.x){
    int n = idx >> 9, f = idx & 511;
    float v = bias[f];
    for (int c=0;c<K;++c) v += X[n*K+c] * W[c*512+f];
    Y[idx] = v;
    s += v; s2 += v*v;
  }
  block_stat_out(s, s2, pstat);
}

// ---------------- stats finalize: (Σ,Σ²) partials -> mean, 1/(std+eps) ----------------
__global__ __launch_bounds__(256) void reduce_stats_k(const float* __restrict__ pstat, int nblk,
                                                      float inv_n, float* acc){
  float s = 0.f, s2 = 0.f;
  for (int i = threadIdx.x; i < nblk; i += 256){ s += pstat[2*i]; s2 += pstat[2*i+1]; }
  __shared__ float sb[8];
  s = wred(s); s2 = wred(s2);
  int wv = threadIdx.x >> 6;
  if ((threadIdx.x & 63) == 0){ sb[wv*2] = s; sb[wv*2+1] = s2; }
  __syncthreads();
  if (threadIdx.x == 0){
    float a = 0.f, b = 0.f;
    for (int i=0;i<4;++i){ a += sb[i*2]; b += sb[i*2+1]; }
    float mean = a * inv_n;
    float var  = fmaxf(b * inv_n - mean*mean, 0.f);
    acc[0] = mean;
    acc[1] = 1.f/(sqrtf(var) + 1e-5f);
  }
}

// ---------------- graph-LN apply (vectorized, mean/rinv precomputed) ----------------
__global__ __launch_bounds__(256) void ln_apply_k(const float* __restrict__ src, float* __restrict__ dst,
                                                  const float* __restrict__ w, const float* __restrict__ b,
                                                  const float* acc, int total4){
  float mean = acc[0], rinv = acc[1];
  const floatx4* s4 = (const floatx4*)src;
  floatx4* d4 = (floatx4*)dst;
  const floatx4* w4 = (const floatx4*)w;
  const floatx4* b4 = (const floatx4*)b;
  for (int i = blockIdx.x*blockDim.x + threadIdx.x; i < total4; i += gridDim.x*blockDim.x){
    int f = i & 127;
    floatx4 v = s4[i], wv = w4[f], bv = b4[f];
    #pragma unroll
    for (int e=0;e<4;++e) v[e] = (v[e]-mean)*rinv*wv[e] + bv[e];
    d4[i] = v;
  }
}

// ---------------- gated residual (vectorized) + per-block LN partials ----------------
__global__ __launch_bounds__(256) void gate_res_k(float* __restrict__ y, const float* __restrict__ x,
                                                  const float* __restrict__ bout, const float* __restrict__ skipel,
                                                  float* pstat, int total4){
  float g = 1.f/(1.f+expf(-(*skipel)));
  floatx4* y4 = (floatx4*)y;
  const floatx4* x4 = (const floatx4*)x;
  const floatx4* b4 = (const floatx4*)bout;
  float s = 0.f, s2 = 0.f;
  for (int i = blockIdx.x*blockDim.x + threadIdx.x; i < total4; i += gridDim.x*blockDim.x){
    floatx4 yv = y4[i], xv = x4[i], bv = b4[i & 127];
    #pragma unroll
    for (int e=0;e<4;++e){
      float o = g*(yv[e]+bv[e]) + (2.f-g)*xv[e];  // gated skip + wrapper residual
      yv[e] = o;
      s += o; s2 += o*o;
    }
    y4[i] = yv;
  }
  block_stat_out(s, s2, pstat);
}

// ---------------- per-layer combined weights: W' = W @ blockdiag(Rel), b' = b @ Rel ----------------
__global__ __launch_bounds__(256) void combine_k(const float* Wk, const float* bk, const float* Wq, const float* bq,
                                                 const float* Wv, const float* bv, const float* Ar, const float* Mr,
                                                 int l, u16* Wc_op, float* bias_op, u16* Wc_m, float* bias_m){
  const int TOT_OP = 513*CQ;
  const int TOT = TOT_OP + 513*CM;
  for (int idx = blockIdx.x*blockDim.x + threadIdx.x; idx < TOT; idx += gridDim.x*blockDim.x){
    int side, c, f;
    if (idx < TOT_OP){ side = 0; c = idx/CQ; f = idx - c*CQ; }
    else { int j = idx - TOT_OP; side = 1; c = j/CM; f = j - c*CM; }
    int r = f >> 9, fc = f & 511;
    size_t woff = (size_t)(l*2+side)*262144;
    size_t boff = (size_t)(l*2+side)*512;
    float val;
    if (r == 0){
      val = (c < 512) ? Wq[woff + (size_t)c*512 + fc] : bq[boff + fc];
    } else {
      int useK = (side==0) ? (r==1 || r==3) : (r==1);
      const float* W  = useK ? (Wk + woff) : (Wv + woff);
      const float* bb = useK ? (bk + boff) : (bv + boff);
      int rel = (side==0) ? ((r<=2)?0:2) : 1;
      int h = fc >> 6, e2 = fc & 63;
      const float* Rb = (useK ? Ar : Mr) + ((size_t)(l*3+rel)*8 + h)*4096;
      int h64 = h*64;
      float sacc = 0.f;
      for (int dd=0; dd<64; ++dd){
        float wv = (c<512) ? W[(size_t)c*512 + h64 + dd] : bb[h64+dd];
        sacc += wv * Rb[dd*64 + e2];
      }
      val = sacc;
    }
    if (side==0){ if (c<512) Wc_op[(size_t)c*CQ + f] = f2bf(val); else bias_op[f] = val; }
    else        { if (c<512) Wc_m [(size_t)c*CM + f] = f2bf(val); else bias_m [f] = val; }
  }
}

// ---------------- bf16 MFMA GEMM: C[MxN] = (gelu?)A[MxK,f32] @ B[KxN,bf16] (+bias) ----------------
// out_bf16: C is u16 bf16, else f32.
__global__ __launch_bounds__(256) void gemm_bf16(const float* __restrict__ A, const u16* __restrict__ B,
                                                 const float* __restrict__ bias, void* __restrict__ Cp,
                                                 int M, int N, int K, int gelu_a, int out_bf16){
  __shared__ short As[128][40];  // 80B rows = 5x16B: b128 fragment reads stay 16B-aligned
  __shared__ short Bs[64][40];   // stored transposed: Bs[n][k]
  const int tid = threadIdx.x;
  const int bm = blockIdx.y * 128;
  const int bn = blockIdx.x * 64;
  const int lane = tid & 63, wave = tid >> 6;
  const int wm = wave & 1, wn = wave >> 1;
  const int mrow = lane & 15, quad = lane >> 4;
  floatx4 acc[4][2];
  #pragma unroll
  for (int a=0;a<4;++a)
    #pragma unroll
    for (int b=0;b<2;++b) acc[a][b] = (floatx4){0.f,0.f,0.f,0.f};
  for (int k0 = 0; k0 < K; k0 += 32){
    #pragma unroll
    for (int i=0;i<4;++i){            // stage A: 128x32 f32 -> bf16
      int f4 = tid + i*256;
      int r = f4 >> 3, c4 = f4 & 7;
      floatx4 av = *(const floatx4*)(A + (size_t)(bm+r)*K + k0 + c4*4);
      if (gelu_a){
        #pragma unroll
        for (int e=0;e<4;++e) av[e] = geluf(av[e]);
      }
      shortx4 sv;
      #pragma unroll
      for (int e=0;e<4;++e) sv[e] = (short)f2bf(av[e]);
      *(shortx4*)&As[r][c4*4] = sv;
    }
    #pragma unroll
    for (int i=0;i<2;++i){            // stage B: 32x64 bf16, transposed into LDS
      int q4 = tid + i*256;
      int r = q4 >> 4, c4 = q4 & 15;
      ushortx4 bv = *(const ushortx4*)(B + (size_t)(k0+r)*N + bn + c4*4);
      #pragma unroll
      for (int e=0;e<4;++e) Bs[c4*4+e][r] = (short)bv[e];
    }
    __syncthreads();
    shortx8 af[4], bfr[2];
    #pragma unroll
    for (int mt=0;mt<4;++mt) af[mt]  = *(const shortx8*)&As[wm*64 + mt*16 + mrow][quad*8];
    #pragma unroll
    for (int nt=0;nt<2;++nt) bfr[nt] = *(const shortx8*)&Bs[wn*32 + nt*16 + mrow][quad*8];
    #pragma unroll
    for (int mt=0;mt<4;++mt)
      #pragma unroll
      for (int nt=0;nt<2;++nt)
        acc[mt][nt] = __builtin_amdgcn_mfma_f32_16x16x32_bf16(af[mt], bfr[nt], acc[mt][nt], 0, 0, 0);
    __syncthreads();
  }
  #pragma unroll
  for (int mt=0;mt<4;++mt){
    #pragma unroll
    for (int nt=0;nt<2;++nt){
      int col = bn + wn*32 + nt*16 + mrow;
      float bval = bias ? bias[col] : 0.f;
      #pragma unroll
      for (int r=0;r<4;++r){
        int row = bm + wm*64 + mt*16 + quad*4 + r;
        float v = acc[mt][nt][r] + bval;
        if (out_bf16) ((u16*)Cp)[(size_t)row*N + col] = f2bf(v);
        else          ((float*)Cp)[(size_t)row*N + col] = v;
      }
    }
  }
}

// ---------------- attention into op nodes (8 canproc + optional 1 precedes) ----------------
__global__ __launch_bounds__(512) void attn_op_k(const u16* __restrict__ qkv_op, const u16* __restrict__ qkv_m,
                                                 const int* __restrict__ s0, const int* __restrict__ s1,
                                                 const float* __restrict__ prel, float* __restrict__ agg){
  int n = blockIdx.x;
  int h = threadIdx.x >> 6, d = threadIdx.x & 63;
  int hd = h*64 + d;
  float q = bf2f(qkv_op[(size_t)n*CQ + hd]);
  float p0 = prel[h]     * 0.125f;
  float p1 = prel[8 + h] * 0.125f;
  float a[9]; int src[9];
  int i = n & 1023;
  #pragma unroll
  for (int j=0;j<8;++j){
    int m = s1[n*8 + j];
    src[j] = m;
    float t = q * bf2f(qkv_m[(size_t)m*CM + 512 + hd]);
    a[j] = wred(t) * p1;
  }
  bool hasp = (i > 0);
  if (hasp){
    int e0 = (n >> 10)*1023 + i - 1;
    int s = s0[e0];
    src[8] = s;
    float t = q * bf2f(qkv_op[(size_t)s*CQ + 512 + hd]);
    a[8] = wred(t) * p0;
  }
  float mx = a[0];
  #pragma unroll
  for (int j=1;j<8;++j) mx = fmaxf(mx, a[j]);
  if (hasp) mx = fmaxf(mx, a[8]);
  float ssum = 0.f;
  #pragma unroll
  for (int j=0;j<8;++j){ a[j] = expf(a[j]-mx); ssum += a[j]; }
  float e8 = 0.f;
  if (hasp){ e8 = expf(a[8]-mx); ssum += e8; }
  float inv = 1.f/(ssum + 1e-16f);
  float o = 0.f;
  #pragma unroll
  for (int j=0;j<8;++j) o += a[j] * bf2f(qkv_m[(size_t)src[j]*CM + 1024 + hd]);
  if (hasp) o += e8 * bf2f(qkv_op[(size_t)src[8]*CQ + 1024 + hd]);
  agg[(size_t)n*512 + hd] = o * inv;
}

// ---------------- machine attention, split-edge online softmax partials ----------------
// grid (NMS, MSPLIT), block 512 = 8 waves (wave = head). Each block does ~deg/8 edges.
__global__ __launch_bounds__(512) void attn_m_part_k(const u16* __restrict__ qkv_op, const u16* __restrict__ qkv_m,
                                                     const int* __restrict__ s2, const int* __restrict__ row_start,
                                                     const int* __restrict__ elist, const float* __restrict__ prel,
                                                     float* __restrict__ pml, float* __restrict__ pacc){
  int m = blockIdx.x, sp = blockIdx.y;
  int h = threadIdx.x >> 6, d = threadIdx.x & 63;
  int hd = h*64 + d;
  int beg = row_start[m];
  int deg = row_start[m+1] - beg;
  int cs = (deg + MSPLIT - 1) / MSPLIT;
  int start = sp * cs;
  int end = min(start + cs, deg);
  float q = bf2f(qkv_m[(size_t)m*CM + hd]);
  float p2 = prel[16 + h] * 0.125f;
  float mi = -1e30f, l = 0.f, acc = 0.f;
  for (int idx = start; idx < end; ++idx){
    int e = elist[beg + idx]; int so = s2[e];
    float t = q * bf2f(qkv_op[(size_t)so*CQ + 1536 + hd]);
    t = wred(t) * p2;
    float v = bf2f(qkv_op[(size_t)so*CQ + 2048 + hd]);
    float mn = fmaxf(mi, t);
    float sc = expf(mi - mn);   // first iter: exp(-inf)=0
    float e1 = expf(t - mn);
    l = l*sc + e1;
    acc = acc*sc + e1*v;
    mi = mn;
  }
  int pidx = (m*MSPLIT + sp)*8 + h;
  if (d == 0){ pml[pidx*2] = mi; pml[pidx*2+1] = l; }
  pacc[(size_t)pidx*64 + d] = acc;
}
// combine partials: 512 blocks x 512 threads (h,d)
__global__ __launch_bounds__(512) void attn_m_comb_k(const float* __restrict__ pml, const float* __restrict__ pacc,
                                                     float* __restrict__ agg){
  int m = blockIdx.x;
  int h = threadIdx.x >> 6, d = threadIdx.x & 63;
  float M = -1e30f;
  #pragma unroll
  for (int sp=0; sp<MSPLIT; ++sp) M = fmaxf(M, pml[((m*MSPLIT+sp)*8+h)*2]);
  float l = 0.f, acc = 0.f;
  #pragma unroll
  for (int sp=0; sp<MSPLIT; ++sp){
    int pidx = (m*MSPLIT+sp)*8+h;
    float sc = expf(pml[pidx*2] - M);  // empty chunk: mi=-1e30 -> sc=0 (l,acc already 0)
    l   += sc * pml[pidx*2+1];
    acc += sc * pacc[(size_t)pidx*64 + d];
  }
  agg[(size_t)m*512 + h*64 + d] = acc / (l + 1e-16f);
}

// ---------------- final emit (f32 out, vectorized) + means ----------------
__global__ __launch_bounds__(256) void emit_k(const float* __restrict__ x_op, const float* __restrict__ x_m,
                                              float* __restrict__ out){
  const int T1 = NOPS*128, T2 = T1 + NMS*128;   // in float4 units
  const floatx4* a4 = (const floatx4*)x_op;
  const floatx4* b4 = (const floatx4*)x_m;
  floatx4* o4 = (floatx4*)out;
  for (int i = blockIdx.x*blockDim.x + threadIdx.x; i < T2; i += gridDim.x*blockDim.x){
    o4[i] = (i < T1) ? a4[i] : b4[i - T1];
  }
}
__global__ __launch_bounds__(512) void meanj_part_k(const float* __restrict__ x_op, float* scratch){
  int b = blockIdx.x, chunk = blockIdx.y, f = threadIdx.x;
  float s = 0.f;
  for (int r=0;r<128;++r){
    int row = b*1024 + chunk*128 + r;
    s += x_op[(size_t)row*512 + f];
  }
  atomicAdd(&scratch[b*512 + f], s);
}
__global__ void meanj_fin_k(const float* scratch, float* out){
  int i = blockIdx.x*blockDim.x + threadIdx.x;
  if (i < 4096) out[4456448 + i] = scratch[i] * (1.f/1024.f);
}
__global__ __launch_bounds__(512) void meanm_k(const float* __restrict__ x_m, float* out){
  int b = blockIdx.x, f = threadIdx.x;
  float s = 0.f;
  for (int r=0;r<64;++r) s += x_m[(size_t)(b*64+r)*512 + f];
  out[4460544 + b*512 + f] = s * (1.f/64.f);
}

extern "C" void kernel_launch(void* const* d_in, const int* in_sizes, int n_in,
                              void* d_out, int out_size, void* d_ws, size_t ws_size,
                              hipStream_t stream){
  const float* op_x      = (const float*)d_in[0];
  const float* machine_x = (const float*)d_in[1];
  const float* W_emb_op  = (const float*)d_in[2];
  const float* b_emb_op  = (const float*)d_in[3];
  const float* W_emb_m   = (const float*)d_in[4];
  const float* b_emb_m   = (const float*)d_in[5];
  const float* opn_w     = (const float*)d_in[6];
  const float* opn_b     = (const float*)d_in[7];
  const float* mn_w      = (const float*)d_in[8];
  const float* mn_b      = (const float*)d_in[9];
  const float* Wk        = (const float*)d_in[10];
  const float* bk        = (const float*)d_in[11];
  const float* Wq        = (const float*)d_in[12];
  const float* bq        = (const float*)d_in[13];
  const float* Wv        = (const float*)d_in[14];
  const float* bv        = (const float*)d_in[15];
  const float* A_rel     = (const float*)d_in[16];
  const float* M_rel     = (const float*)d_in[17];
  const float* p_rel     = (const float*)d_in[18];
  const float* W_out     = (const float*)d_in[19];
  const float* b_out     = (const float*)d_in[20];
  const float* skip      = (const float*)d_in[21];
  const float* ln_w      = (const float*)d_in[22];
  const float* ln_b      = (const float*)d_in[23];
  const int* s0          = (const int*)d_in[24];  // precedes src row
  const int* s1          = (const int*)d_in[25];  // canproc src row (machines)
  const int* s2          = (const int*)d_in[26];  // compat src row (ops)
  const int* d2          = s2 + NE2;              // compat dst row (machines)
  float* out = (float*)d_out;

  char* ws = (char*)d_ws;
  size_t off = 0;
  auto alloc = [&](size_t bytes)->void*{
    void* p = ws + off;
    off = (off + bytes + 255) & ~(size_t)255;
    return p;
  };
  float* accb      = (float*)alloc(64*4);
  int*   counts    = (int*)  alloc(512*4);
  int*   row_start = (int*)  alloc(513*4);
  int*   cursor    = (int*)  alloc(512*4);
  int*   elist     = (int*)  alloc((size_t)NE2*4);
  float* scratch   = (float*)alloc(4096*4);
  float* pstat     = (float*)alloc(4096*4);      // per-block (s,s2) partials
  float* x_op      = (float*)alloc((size_t)NOPS*512*4);
  float* x_m       = (float*)alloc((size_t)NMS*512*4);
  u16*   qkv_op    = (u16*)  alloc((size_t)NOPS*CQ*2);   // 40MB; o_op (16MB f32) aliases it
  u16*   qkv_m     = (u16*)  alloc((size_t)NMS*CM*2);    // 1.5MB; o_m (1MB f32) aliases it
  float* agg_op    = (float*)alloc((size_t)NOPS*512*4);
  float* agg_m     = (float*)alloc((size_t)NMS*512*4);
  u16*   Wc_op     = (u16*)  alloc((size_t)512*CQ*2);
  float* bias_op   = (float*)alloc(CQ*4);
  u16*   Wc_m      = (u16*)  alloc((size_t)512*CM*2);
  float* bias_m    = (float*)alloc(CM*4);
  u16*   Wout_bf   = (u16*)  alloc((size_t)6*262144*2);  // all 6 W_out blocks, bf16
  float* pml       = (float*)alloc((size_t)NMS*MSPLIT*8*2*4);   // (m,split,head) -> (max,l)
  float* pacc      = (float*)alloc((size_t)NMS*MSPLIT*8*64*4);  // partial weighted V
  float* o_op      = (float*)qkv_op;   // alias: qkv dead once attn done
  float* o_m       = (float*)qkv_m;
  float* pstat_m   = pstat + 2048;     // machine-side partial region

  const int TOP = NOPS*512;   // 4194304
  const int TM  = NMS*512;    // 262144
  const int T4OP = TOP/4, T4M = TM/4;
  const int GB_OP = 1024, GB_M = 128; // stat-kernel grids (pstat slots)

  // setup: zero accumulators, build machine CSR, convert W_out once
  zero_ws_k<<<16,256,0,stream>>>(accb, counts, scratch);
  csr_count_k<<<256,256,0,stream>>>(d2, counts);
  csr_scan_k<<<1,512,0,stream>>>(counts, row_start, cursor);
  csr_scatter_k<<<256,256,0,stream>>>(d2, cursor, elist);
  cvt_bf16_k<<<1536,256,0,stream>>>(W_out, Wout_bf, 6*262144);

  // embeddings + graph LN
  embed_k<<<GB_OP,256,0,stream>>>(op_x, W_emb_op, b_emb_op, x_op, TOP, 16, pstat);
  embed_k<<<GB_M,256,0,stream>>>(machine_x, W_emb_m, b_emb_m, x_m, TM, 8, pstat_m);
  reduce_stats_k<<<1,256,0,stream>>>(pstat,   GB_OP, 1.f/TOP, accb + 0);
  reduce_stats_k<<<1,256,0,stream>>>(pstat_m, GB_M,  1.f/TM,  accb + 2);
  ln_apply_k<<<1024,256,0,stream>>>(x_op, x_op, opn_w, opn_b, accb + 0, T4OP);
  ln_apply_k<<<128,256,0,stream>>>(x_m, x_m, mn_w, mn_b, accb + 2, T4M);

  for (int l=0; l<3; ++l){
    combine_k<<<1024,256,0,stream>>>(Wk,bk,Wq,bq,Wv,bv,A_rel,M_rel,l,Wc_op,bias_op,Wc_m,bias_m);
    dim3 g1(CQ/64, NOPS/128);
    gemm_bf16<<<g1,256,0,stream>>>(x_op, Wc_op, bias_op, qkv_op, NOPS, CQ, 512, 0, 1);
    dim3 g2(CM/64, NMS/128);
    gemm_bf16<<<g2,256,0,stream>>>(x_m, Wc_m, bias_m, qkv_m, NMS, CM, 512, 0, 1);
    attn_op_k<<<NOPS,512,0,stream>>>(qkv_op, qkv_m, s0, s1, p_rel + l*24, agg_op);
    attn_m_part_k<<<dim3(NMS,MSPLIT),512,0,stream>>>(qkv_op, qkv_m, s2, row_start, elist, p_rel + l*24, pml, pacc);
    attn_m_comb_k<<<NMS,512,0,stream>>>(pml, pacc, agg_m);
    // op-side output projection
    dim3 g3(512/64, NOPS/128);
    gemm_bf16<<<g3,256,0,stream>>>(agg_op, Wout_bf + (size_t)(l*2+0)*262144, nullptr, o_op, NOPS, 512, 512, 1, 0);
    gate_res_k<<<GB_OP,256,0,stream>>>(o_op, x_op, b_out + (size_t)(l*2+0)*512, skip + l*2+0, pstat, T4OP);
    // machine-side output projection
    dim3 g4(512/64, NMS/128);
    gemm_bf16<<<g4,256,0,stream>>>(agg_m, Wout_bf + (size_t)(l*2+1)*262144, nullptr, o_m, NMS, 512, 512, 1, 0);
    gate_res_k<<<GB_M,256,0,stream>>>(o_m, x_m, b_out + (size_t)(l*2+1)*512, skip + l*2+1, pstat_m, T4M);
    reduce_stats_k<<<1,256,0,stream>>>(pstat,   GB_OP, 1.f/TOP, accb + 2*(2+2*l));
    reduce_stats_k<<<1,256,0,stream>>>(pstat_m, GB_M,  1.f/TM,  accb + 2*(3+2*l));
    ln_apply_k<<<1024,256,0,stream>>>(o_op, x_op, ln_w + l*512, ln_b + l*512, accb + 2*(2+2*l), T4OP);
    ln_apply_k<<<128,256,0,stream>>>(o_m, x_m, ln_w + l*512, ln_b + l*512, accb + 2*(3+2*l), T4M);
  }

  emit_k<<<2048,256,0,stream>>>(x_op, x_m, out);
  meanj_part_k<<<dim3(8,8),512,0,stream>>>(x_op, scratch);
  meanj_fin_k<<<16,256,0,stream>>>(scratch, out);
  meanm_k<<<8,512,0,stream>>>(x_m, out);
}

// Round 6
// 1096.285 us; speedup vs baseline: 2.1879x; 1.1790x over previous
//
#include <hip/hip_runtime.h>

typedef unsigned short u16;
typedef __attribute__((ext_vector_type(4))) float floatx4;
typedef __attribute__((ext_vector_type(8))) short shortx8;
typedef __attribute__((ext_vector_type(4))) short shortx4;

#define NOPS 8192
#define NMS  512
#define CQ   2560   // op qkv cols: q | k0 | v0 | k2 | v2
#define CM   1536   // machine qkv cols: q | k1 | v1
#define NE2  65536
#define MSPLIT 8

__device__ __forceinline__ float bf2f(u16 u){ return __uint_as_float(((unsigned)u)<<16); }
__device__ __forceinline__ u16 f2bf(float f){
  unsigned u = __float_as_uint(f);
  u += 0x7FFFu + ((u>>16)&1u);
  return (u16)(u>>16);
}
__device__ __forceinline__ float wred(float v){
  #pragma unroll
  for (int o=32;o;o>>=1) v += __shfl_xor(v,o,64);
  return v;
}
__device__ __forceinline__ float geluf(float x){
  return 0.5f*x*(1.f+erff(x*0.70710678118654752f));
}
// block-level (s,s2) reduction -> one pair per block (no global same-address atomics)
__device__ __forceinline__ void block_stat_out(float s, float s2, float* pstat){
  __shared__ float sb[8];
  s = wred(s); s2 = wred(s2);
  int wv = threadIdx.x >> 6;
  if ((threadIdx.x & 63) == 0){ sb[wv*2] = s; sb[wv*2+1] = s2; }
  __syncthreads();
  if (threadIdx.x == 0){
    float a = 0.f, b = 0.f;
    int nw = blockDim.x >> 6;
    for (int i=0;i<nw;++i){ a += sb[i*2]; b += sb[i*2+1]; }
    pstat[blockIdx.x*2]   = a;
    pstat[blockIdx.x*2+1] = b;
  }
}

// ---------------- zero small ws regions ----------------
__global__ void zero_ws_k(float* acc, int* counts, float* scratch){
  int i = blockIdx.x*blockDim.x + threadIdx.x;
  if (i < 64)   acc[i] = 0.f;
  if (i < 512)  counts[i] = 0;
  if (i < 4096) scratch[i] = 0.f;
}

// ---------------- CSR build for compat edges (dst = machine) ----------------
__global__ void csr_count_k(const int* __restrict__ d2, int* counts){
  int e = blockIdx.x*blockDim.x + threadIdx.x;
  if (e < NE2) atomicAdd(&counts[d2[e]], 1);
}
__global__ __launch_bounds__(512) void csr_scan_k(const int* counts, int* row_start, int* cursor){
  __shared__ int sd[512];
  int t = threadIdx.x;
  sd[t] = counts[t];
  __syncthreads();
  for (int off=1; off<512; off<<=1){
    int v = (t >= off) ? sd[t-off] : 0;
    __syncthreads();
    sd[t] += v;
    __syncthreads();
  }
  row_start[t+1] = sd[t];
  if (t==0) row_start[0] = 0;
  cursor[t] = sd[t] - counts[t];
}
__global__ void csr_scatter_k(const int* __restrict__ d2, int* cursor, int* elist){
  int e = blockIdx.x*blockDim.x + threadIdx.x;
  if (e < NE2){
    int pos = atomicAdd(&cursor[d2[e]], 1);
    elist[pos] = e;
  }
}

// ---------------- W_out: f32 [6][K][N] -> bf16 transposed [6][N][K] (LDS tiled) ----------------
__global__ __launch_bounds__(256) void twout_k(const float* __restrict__ src, u16* __restrict__ dst){
  __shared__ u16 t[64][65];
  int l = blockIdx.x, kb = blockIdx.y*64, nb = blockIdx.z*64;
  const float* s = src + (size_t)l*262144;
  u16* d = dst + (size_t)l*262144;
  int tx = threadIdx.x & 63, ty4 = threadIdx.x >> 6;
  #pragma unroll 4
  for (int p=0;p<16;++p){
    int k = ty4 + p*4;
    t[k][tx] = f2bf(s[(size_t)(kb+k)*512 + nb + tx]);
  }
  __syncthreads();
  #pragma unroll 4
  for (int p=0;p<16;++p){
    int n = ty4 + p*4;
    d[(size_t)(nb+n)*512 + kb + tx] = t[tx][n];
  }
}

// ---------------- embedding GEMM (tiny K, f32 in) + per-block LN partials ----------------
__global__ __launch_bounds__(256) void embed_k(const float* __restrict__ X, const float* __restrict__ W,
                                               const float* __restrict__ bias, float* __restrict__ Y,
                                               int total, int K, float* pstat){
  float s = 0.f, s2 = 0.f;
  for (int idx = blockIdx.x*blockDim.x + threadIdx.x; idx < total; idx += gridDim.x*blockDim.x){
    int n = idx >> 9, f = idx & 511;
    float v = bias[f];
    for (int c=0;c<K;++c) v += X[n*K+c] * W[c*512+f];
    Y[idx] = v;
    s += v; s2 += v*v;
  }
  block_stat_out(s, s2, pstat);
}

// ---------------- stats finalize: (Σ,Σ²) partials -> mean, 1/(std+eps) ----------------
__global__ __launch_bounds__(256) void reduce_stats_k(const float* __restrict__ pstat, int nblk,
                                                      float inv_n, float* acc){
  float s = 0.f, s2 = 0.f;
  for (int i = threadIdx.x; i < nblk; i += 256){ s += pstat[2*i]; s2 += pstat[2*i+1]; }
  __shared__ float sb[8];
  s = wred(s); s2 = wred(s2);
  int wv = threadIdx.x >> 6;
  if ((threadIdx.x & 63) == 0){ sb[wv*2] = s; sb[wv*2+1] = s2; }
  __syncthreads();
  if (threadIdx.x == 0){
    float a = 0.f, b = 0.f;
    for (int i=0;i<4;++i){ a += sb[i*2]; b += sb[i*2+1]; }
    float mean = a * inv_n;
    float var  = fmaxf(b * inv_n - mean*mean, 0.f);
    acc[0] = mean;
    acc[1] = 1.f/(sqrtf(var) + 1e-5f);
  }
}

// ---------------- graph-LN apply: dual write f32 + bf16 ----------------
__global__ __launch_bounds__(256) void ln_apply_k(const float* __restrict__ src, float* __restrict__ dst,
                                                  u16* __restrict__ dst_bf,
                                                  const float* __restrict__ w, const float* __restrict__ b,
                                                  const float* acc, int total4){
  float mean = acc[0], rinv = acc[1];
  const floatx4* s4 = (const floatx4*)src;
  floatx4* d4 = (floatx4*)dst;
  shortx4* db4 = (shortx4*)dst_bf;
  const floatx4* w4 = (const floatx4*)w;
  const floatx4* b4 = (const floatx4*)b;
  for (int i = blockIdx.x*blockDim.x + threadIdx.x; i < total4; i += gridDim.x*blockDim.x){
    int f = i & 127;
    floatx4 v = s4[i], wv = w4[f], bv = b4[f];
    shortx4 sv;
    #pragma unroll
    for (int e=0;e<4;++e){ v[e] = (v[e]-mean)*rinv*wv[e] + bv[e]; sv[e] = (short)f2bf(v[e]); }
    d4[i] = v;
    db4[i] = sv;
  }
}

// ---------------- gated residual (vectorized) + per-block LN partials ----------------
__global__ __launch_bounds__(256) void gate_res_k(float* __restrict__ y, const float* __restrict__ x,
                                                  const float* __restrict__ bout, const float* __restrict__ skipel,
                                                  float* pstat, int total4){
  float g = 1.f/(1.f+expf(-(*skipel)));
  floatx4* y4 = (floatx4*)y;
  const floatx4* x4 = (const floatx4*)x;
  const floatx4* b4 = (const floatx4*)bout;
  float s = 0.f, s2 = 0.f;
  for (int i = blockIdx.x*blockDim.x + threadIdx.x; i < total4; i += gridDim.x*blockDim.x){
    floatx4 yv = y4[i], xv = x4[i], bv = b4[i & 127];
    #pragma unroll
    for (int e=0;e<4;++e){
      float o = g*(yv[e]+bv[e]) + (2.f-g)*xv[e];  // gated skip + wrapper residual
      yv[e] = o;
      s += o; s2 += o*o;
    }
    y4[i] = yv;
  }
  block_stat_out(s, s2, pstat);
}

// ---------------- per-layer combined weights, TRANSPOSED out: Wc_t[f][c] ----------------
__global__ __launch_bounds__(256) void combine_k(const float* Wk, const float* bk, const float* Wq, const float* bq,
                                                 const float* Wv, const float* bv, const float* Ar, const float* Mr,
                                                 int l, u16* Wc_op_t, float* bias_op, u16* Wc_m_t, float* bias_m){
  const int TOT_OP = CQ*513;
  const int TOT = TOT_OP + CM*513;
  for (int idx = blockIdx.x*blockDim.x + threadIdx.x; idx < TOT; idx += gridDim.x*blockDim.x){
    int side, f, cc;
    if (idx < TOT_OP){ side = 0; f = idx/513; cc = idx - f*513; }
    else { int j = idx - TOT_OP; side = 1; f = j/513; cc = j - f*513; }
    int r = f >> 9, fc = f & 511;
    size_t woff = (size_t)(l*2+side)*262144;
    size_t boff = (size_t)(l*2+side)*512;
    float val;
    if (r == 0){
      val = (cc < 512) ? Wq[woff + (size_t)cc*512 + fc] : bq[boff + fc];
    } else {
      int useK = (side==0) ? (r==1 || r==3) : (r==1);
      const float* W  = useK ? (Wk + woff) : (Wv + woff);
      const float* bb = useK ? (bk + boff) : (bv + boff);
      int rel = (side==0) ? ((r<=2)?0:2) : 1;
      int h = fc >> 6, e2 = fc & 63;
      const float* Rb = (useK ? Ar : Mr) + ((size_t)(l*3+rel)*8 + h)*4096 + e2;
      const float* wrow = (cc<512) ? (W + (size_t)cc*512 + h*64) : (bb + h*64);
      float sacc = 0.f;
      #pragma unroll 8
      for (int dd=0; dd<64; ++dd) sacc += wrow[dd] * Rb[dd*64];
      val = sacc;
    }
    if (side==0){ if (cc<512) Wc_op_t[(size_t)f*512 + cc] = f2bf(val); else bias_op[f] = val; }
    else        { if (cc<512) Wc_m_t [(size_t)f*512 + cc] = f2bf(val); else bias_m [f] = val; }
  }
}

// ---------------- m97-style bf16 MFMA GEMM: C[MxN] = A[MxK] @ Bt[NxK]^T (+bias) ----------------
// 128x128 tile, BK=32, 4 waves (2x2), 4x4 mfma_16x16x32 per wave, global_load_lds staging.
__global__ __launch_bounds__(256) void gemm_bt(const u16* __restrict__ A, const u16* __restrict__ Bt,
                                               const float* __restrict__ bias, void* __restrict__ Cp,
                                               int M, int N, int K, int out_bf16){
  __shared__ u16 As[128*32];
  __shared__ u16 Bs[128*32];
  const int tid = threadIdx.x;
  const int lane = tid & 63, wave = tid >> 6;
  const int bm = blockIdx.y * 128, bn = blockIdx.x * 128;
  const int wm = wave & 1, wn = wave >> 1;
  const int mrow = lane & 15, quad = lane >> 4;
  const u16* Ab = A + (size_t)bm*K;
  const u16* Bb = Bt + (size_t)bn*K;
  floatx4 acc[4][4];
  #pragma unroll
  for (int a=0;a<4;++a)
    #pragma unroll
    for (int b=0;b<4;++b) acc[a][b] = (floatx4){0.f,0.f,0.f,0.f};
  const int r0 = tid >> 2, c0 = (tid & 3) * 8;          // issue 0 chunk
  const int r1 = (tid+256) >> 2, c1 = ((tid+256) & 3) * 8; // issue 1 chunk
  const int lds0 = wave*512;            // (wave*64)*8 elems
  const int lds1 = wave*512 + 2048;     // + 256*8 elems
  for (int k0 = 0; k0 < K; k0 += 32){
    __builtin_amdgcn_global_load_lds((const __attribute__((address_space(1))) void*)(Ab + (size_t)r0*K + k0 + c0),
                                     (__attribute__((address_space(3))) void*)(As + lds0), 16, 0, 0);
    __builtin_amdgcn_global_load_lds((const __attribute__((address_space(1))) void*)(Ab + (size_t)r1*K + k0 + c1),
                                     (__attribute__((address_space(3))) void*)(As + lds1), 16, 0, 0);
    __builtin_amdgcn_global_load_lds((const __attribute__((address_space(1))) void*)(Bb + (size_t)r0*K + k0 + c0),
                                     (__attribute__((address_space(3))) void*)(Bs + lds0), 16, 0, 0);
    __builtin_amdgcn_global_load_lds((const __attribute__((address_space(1))) void*)(Bb + (size_t)r1*K + k0 + c1),
                                     (__attribute__((address_space(3))) void*)(Bs + lds1), 16, 0, 0);
    __syncthreads();   // compiler emits vmcnt(0) drain before barrier
    shortx8 af[4], bf[4];
    #pragma unroll
    for (int mt=0;mt<4;++mt) af[mt] = *(const shortx8*)(As + (wm*64 + mt*16 + mrow)*32 + quad*8);
    #pragma unroll
    for (int nt=0;nt<4;++nt) bf[nt] = *(const shortx8*)(Bs + (wn*64 + nt*16 + mrow)*32 + quad*8);
    #pragma unroll
    for (int mt=0;mt<4;++mt)
      #pragma unroll
      for (int nt=0;nt<4;++nt)
        acc[mt][nt] = __builtin_amdgcn_mfma_f32_16x16x32_bf16(af[mt], bf[nt], acc[mt][nt], 0, 0, 0);
    __syncthreads();
  }
  #pragma unroll
  for (int mt=0;mt<4;++mt){
    #pragma unroll
    for (int nt=0;nt<4;++nt){
      int col = bn + wn*64 + nt*16 + mrow;
      float bval = bias ? bias[col] : 0.f;
      #pragma unroll
      for (int r2=0;r2<4;++r2){
        int row = bm + wm*64 + mt*16 + quad*4 + r2;
        float v = acc[mt][nt][r2] + bval;
        if (out_bf16) ((u16*)Cp)[(size_t)row*N + col] = f2bf(v);
        else          ((float*)Cp)[(size_t)row*N + col] = v;
      }
    }
  }
}

// ---------------- attention into op nodes -> gelu'd bf16 agg ----------------
__global__ __launch_bounds__(512) void attn_op_k(const u16* __restrict__ qkv_op, const u16* __restrict__ qkv_m,
                                                 const int* __restrict__ s0, const int* __restrict__ s1,
                                                 const float* __restrict__ prel, u16* __restrict__ agg){
  int n = blockIdx.x;
  int h = threadIdx.x >> 6, d = threadIdx.x & 63;
  int hd = h*64 + d;
  float q = bf2f(qkv_op[(size_t)n*CQ + hd]);
  float p0 = prel[h]     * 0.125f;
  float p1 = prel[8 + h] * 0.125f;
  float a[9]; int src[9];
  int i = n & 1023;
  #pragma unroll
  for (int j=0;j<8;++j){
    int m = s1[n*8 + j];
    src[j] = m;
    float t = q * bf2f(qkv_m[(size_t)m*CM + 512 + hd]);
    a[j] = wred(t) * p1;
  }
  bool hasp = (i > 0);
  if (hasp){
    int e0 = (n >> 10)*1023 + i - 1;
    int s = s0[e0];
    src[8] = s;
    float t = q * bf2f(qkv_op[(size_t)s*CQ + 512 + hd]);
    a[8] = wred(t) * p0;
  }
  float mx = a[0];
  #pragma unroll
  for (int j=1;j<8;++j) mx = fmaxf(mx, a[j]);
  if (hasp) mx = fmaxf(mx, a[8]);
  float ssum = 0.f;
  #pragma unroll
  for (int j=0;j<8;++j){ a[j] = expf(a[j]-mx); ssum += a[j]; }
  float e8 = 0.f;
  if (hasp){ e8 = expf(a[8]-mx); ssum += e8; }
  float inv = 1.f/(ssum + 1e-16f);
  float o = 0.f;
  #pragma unroll
  for (int j=0;j<8;++j) o += a[j] * bf2f(qkv_m[(size_t)src[j]*CM + 1024 + hd]);
  if (hasp) o += e8 * bf2f(qkv_op[(size_t)src[8]*CQ + 1024 + hd]);
  agg[(size_t)n*512 + hd] = f2bf(geluf(o * inv));
}

// ---------------- machine attention, split-edge online softmax partials ----------------
__global__ __launch_bounds__(512) void attn_m_part_k(const u16* __restrict__ qkv_op, const u16* __restrict__ qkv_m,
                                                     const int* __restrict__ s2, const int* __restrict__ row_start,
                                                     const int* __restrict__ elist, const float* __restrict__ prel,
                                                     float* __restrict__ pml, float* __restrict__ pacc){
  int m = blockIdx.x, sp = blockIdx.y;
  int h = threadIdx.x >> 6, d = threadIdx.x & 63;
  int hd = h*64 + d;
  int beg = row_start[m];
  int deg = row_start[m+1] - beg;
  int cs = (deg + MSPLIT - 1) / MSPLIT;
  int start = sp * cs;
  int end = min(start + cs, deg);
  float q = bf2f(qkv_m[(size_t)m*CM + hd]);
  float p2 = prel[16 + h] * 0.125f;
  float mi = -1e30f, l = 0.f, acc = 0.f;
  for (int idx = start; idx < end; ++idx){
    int e = elist[beg + idx]; int so = s2[e];
    float t = q * bf2f(qkv_op[(size_t)so*CQ + 1536 + hd]);
    t = wred(t) * p2;
    float v = bf2f(qkv_op[(size_t)so*CQ + 2048 + hd]);
    float mn = fmaxf(mi, t);
    float sc = expf(mi - mn);
    float e1 = expf(t - mn);
    l = l*sc + e1;
    acc = acc*sc + e1*v;
    mi = mn;
  }
  int pidx = (m*MSPLIT + sp)*8 + h;
  if (d == 0){ pml[pidx*2] = mi; pml[pidx*2+1] = l; }
  pacc[(size_t)pidx*64 + d] = acc;
}
// combine partials -> gelu'd bf16 agg
__global__ __launch_bounds__(512) void attn_m_comb_k(const float* __restrict__ pml, const float* __restrict__ pacc,
                                                     u16* __restrict__ agg){
  int m = blockIdx.x;
  int h = threadIdx.x >> 6, d = threadIdx.x & 63;
  float M = -1e30f;
  #pragma unroll
  for (int sp=0; sp<MSPLIT; ++sp) M = fmaxf(M, pml[((m*MSPLIT+sp)*8+h)*2]);
  float l = 0.f, acc = 0.f;
  #pragma unroll
  for (int sp=0; sp<MSPLIT; ++sp){
    int pidx = (m*MSPLIT+sp)*8+h;
    float sc = expf(pml[pidx*2] - M);
    l   += sc * pml[pidx*2+1];
    acc += sc * pacc[(size_t)pidx*64 + d];
  }
  agg[(size_t)m*512 + h*64 + d] = f2bf(geluf(acc / (l + 1e-16f)));
}

// ---------------- final emit (f32 out, vectorized) + means ----------------
__global__ __launch_bounds__(256) void emit_k(const float* __restrict__ x_op, const float* __restrict__ x_m,
                                              float* __restrict__ out){
  const int T1 = NOPS*128, T2 = T1 + NMS*128;   // in float4 units
  const floatx4* a4 = (const floatx4*)x_op;
  const floatx4* b4 = (const floatx4*)x_m;
  floatx4* o4 = (floatx4*)out;
  for (int i = blockIdx.x*blockDim.x + threadIdx.x; i < T2; i += gridDim.x*blockDim.x){
    o4[i] = (i < T1) ? a4[i] : b4[i - T1];
  }
}
__global__ __launch_bounds__(512) void meanj_part_k(const float* __restrict__ x_op, float* scratch){
  int b = blockIdx.x, chunk = blockIdx.y, f = threadIdx.x;
  float s = 0.f;
  for (int r=0;r<128;++r){
    int row = b*1024 + chunk*128 + r;
    s += x_op[(size_t)row*512 + f];
  }
  atomicAdd(&scratch[b*512 + f], s);
}
__global__ void meanj_fin_k(const float* scratch, float* out){
  int i = blockIdx.x*blockDim.x + threadIdx.x;
  if (i < 4096) out[4456448 + i] = scratch[i] * (1.f/1024.f);
}
__global__ __launch_bounds__(512) void meanm_k(const float* __restrict__ x_m, float* out){
  int b = blockIdx.x, f = threadIdx.x;
  float s = 0.f;
  for (int r=0;r<64;++r) s += x_m[(size_t)(b*64+r)*512 + f];
  out[4460544 + b*512 + f] = s * (1.f/64.f);
}

extern "C" void kernel_launch(void* const* d_in, const int* in_sizes, int n_in,
                              void* d_out, int out_size, void* d_ws, size_t ws_size,
                              hipStream_t stream){
  const float* op_x      = (const float*)d_in[0];
  const float* machine_x = (const float*)d_in[1];
  const float* W_emb_op  = (const float*)d_in[2];
  const float* b_emb_op  = (const float*)d_in[3];
  const float* W_emb_m   = (const float*)d_in[4];
  const float* b_emb_m   = (const float*)d_in[5];
  const float* opn_w     = (const float*)d_in[6];
  const float* opn_b     = (const float*)d_in[7];
  const float* mn_w      = (const float*)d_in[8];
  const float* mn_b      = (const float*)d_in[9];
  const float* Wk        = (const float*)d_in[10];
  const float* bk        = (const float*)d_in[11];
  const float* Wq        = (const float*)d_in[12];
  const float* bq        = (const float*)d_in[13];
  const float* Wv        = (const float*)d_in[14];
  const float* bv        = (const float*)d_in[15];
  const float* A_rel     = (const float*)d_in[16];
  const float* M_rel     = (const float*)d_in[17];
  const float* p_rel     = (const float*)d_in[18];
  const float* W_out     = (const float*)d_in[19];
  const float* b_out     = (const float*)d_in[20];
  const float* skip      = (const float*)d_in[21];
  const float* ln_w      = (const float*)d_in[22];
  const float* ln_b      = (const float*)d_in[23];
  const int* s0          = (const int*)d_in[24];  // precedes src row
  const int* s1          = (const int*)d_in[25];  // canproc src row (machines)
  const int* s2          = (const int*)d_in[26];  // compat src row (ops)
  const int* d2          = s2 + NE2;              // compat dst row (machines)
  float* out = (float*)d_out;

  char* ws = (char*)d_ws;
  size_t off = 0;
  auto alloc = [&](size_t bytes)->void*{
    void* p = ws + off;
    off = (off + bytes + 255) & ~(size_t)255;
    return p;
  };
  float* accb      = (float*)alloc(64*4);
  int*   counts    = (int*)  alloc(512*4);
  int*   row_start = (int*)  alloc(513*4);
  int*   cursor    = (int*)  alloc(512*4);
  int*   elist     = (int*)  alloc((size_t)NE2*4);
  float* scratch   = (float*)alloc(4096*4);
  float* pstat     = (float*)alloc(4096*4);
  float* x_op      = (float*)alloc((size_t)NOPS*512*4);
  u16*   x_op_bf   = (u16*)  alloc((size_t)NOPS*512*2);
  float* x_m       = (float*)alloc((size_t)NMS*512*4);
  u16*   x_m_bf    = (u16*)  alloc((size_t)NMS*512*2);
  u16*   qkv_op    = (u16*)  alloc((size_t)NOPS*CQ*2);   // 40MB; o_op (16MB f32) aliases it
  u16*   qkv_m     = (u16*)  alloc((size_t)NMS*CM*2);    // 1.5MB; o_m (1MB f32) aliases it
  u16*   agg_op    = (u16*)  alloc((size_t)NOPS*512*2);  // gelu'd bf16
  u16*   agg_m     = (u16*)  alloc((size_t)NMS*512*2);
  u16*   Wc_op_t   = (u16*)  alloc((size_t)CQ*512*2);    // transposed [N][K]
  float* bias_op   = (float*)alloc(CQ*4);
  u16*   Wc_m_t    = (u16*)  alloc((size_t)CM*512*2);
  float* bias_m    = (float*)alloc(CM*4);
  u16*   Wout_t    = (u16*)  alloc((size_t)6*262144*2);  // transposed bf16 W_out
  float* pml       = (float*)alloc((size_t)NMS*MSPLIT*8*2*4);
  float* pacc      = (float*)alloc((size_t)NMS*MSPLIT*8*64*4);
  float* o_op      = (float*)qkv_op;   // alias: qkv dead once attn done
  float* o_m       = (float*)qkv_m;
  float* pstat_m   = pstat + 2048;

  const int TOP = NOPS*512;   // 4194304
  const int TM  = NMS*512;    // 262144
  const int T4OP = TOP/4, T4M = TM/4;
  const int GB_OP = 1024, GB_M = 128;

  // setup: zero accumulators, build machine CSR, transpose W_out once
  zero_ws_k<<<16,256,0,stream>>>(accb, counts, scratch);
  csr_count_k<<<256,256,0,stream>>>(d2, counts);
  csr_scan_k<<<1,512,0,stream>>>(counts, row_start, cursor);
  csr_scatter_k<<<256,256,0,stream>>>(d2, cursor, elist);
  twout_k<<<dim3(6,8,8),256,0,stream>>>(W_out, Wout_t);

  // embeddings + graph LN
  embed_k<<<GB_OP,256,0,stream>>>(op_x, W_emb_op, b_emb_op, x_op, TOP, 16, pstat);
  embed_k<<<GB_M,256,0,stream>>>(machine_x, W_emb_m, b_emb_m, x_m, TM, 8, pstat_m);
  reduce_stats_k<<<1,256,0,stream>>>(pstat,   GB_OP, 1.f/TOP, accb + 0);
  reduce_stats_k<<<1,256,0,stream>>>(pstat_m, GB_M,  1.f/TM,  accb + 2);
  ln_apply_k<<<1024,256,0,stream>>>(x_op, x_op, x_op_bf, opn_w, opn_b, accb + 0, T4OP);
  ln_apply_k<<<128,256,0,stream>>>(x_m, x_m, x_m_bf, mn_w, mn_b, accb + 2, T4M);

  for (int l=0; l<3; ++l){
    combine_k<<<1024,256,0,stream>>>(Wk,bk,Wq,bq,Wv,bv,A_rel,M_rel,l,Wc_op_t,bias_op,Wc_m_t,bias_m);
    gemm_bt<<<dim3(CQ/128, NOPS/128),256,0,stream>>>(x_op_bf, Wc_op_t, bias_op, qkv_op, NOPS, CQ, 512, 1);
    gemm_bt<<<dim3(CM/128, NMS/128),256,0,stream>>>(x_m_bf, Wc_m_t, bias_m, qkv_m, NMS, CM, 512, 1);
    attn_op_k<<<NOPS,512,0,stream>>>(qkv_op, qkv_m, s0, s1, p_rel + l*24, agg_op);
    attn_m_part_k<<<dim3(NMS,MSPLIT),512,0,stream>>>(qkv_op, qkv_m, s2, row_start, elist, p_rel + l*24, pml, pacc);
    attn_m_comb_k<<<NMS,512,0,stream>>>(pml, pacc, agg_m);
    // output projections (A = gelu'd bf16 agg)
    gemm_bt<<<dim3(512/128, NOPS/128),256,0,stream>>>(agg_op, Wout_t + (size_t)(l*2+0)*262144, nullptr, o_op, NOPS, 512, 512, 0);
    gate_res_k<<<GB_OP,256,0,stream>>>(o_op, x_op, b_out + (size_t)(l*2+0)*512, skip + l*2+0, pstat, T4OP);
    gemm_bt<<<dim3(512/128, NMS/128),256,0,stream>>>(agg_m, Wout_t + (size_t)(l*2+1)*262144, nullptr, o_m, NMS, 512, 512, 0);
    gate_res_k<<<GB_M,256,0,stream>>>(o_m, x_m, b_out + (size_t)(l*2+1)*512, skip + l*2+1, pstat_m, T4M);
    reduce_stats_k<<<1,256,0,stream>>>(pstat,   GB_OP, 1.f/TOP, accb + 2*(2+2*l));
    reduce_stats_k<<<1,256,0,stream>>>(pstat_m, GB_M,  1.f/TM,  accb + 2*(3+2*l));
    ln_apply_k<<<1024,256,0,stream>>>(o_op, x_op, x_op_bf, ln_w + l*512, ln_b + l*512, accb + 2*(2+2*l), T4OP);
    ln_apply_k<<<128,256,0,stream>>>(o_m, x_m, x_m_bf, ln_w + l*512, ln_b + l*512, accb + 2*(3+2*l), T4M);
  }

  emit_k<<<2048,256,0,stream>>>(x_op, x_m, out);
  meanj_part_k<<<dim3(8,8),512,0,stream>>>(x_op, scratch);
  meanj_fin_k<<<16,256,0,stream>>>(scratch, out);
  meanm_k<<<8,512,0,stream>>>(x_m, out);
}

// Round 7
// 950.279 us; speedup vs baseline: 2.5240x; 1.1536x over previous
//
#include <hip/hip_runtime.h>

typedef unsigned short u16;
typedef __attribute__((ext_vector_type(4))) float floatx4;
typedef __attribute__((ext_vector_type(8))) short shortx8;
typedef __attribute__((ext_vector_type(4))) short shortx4;

#define NOPS 8192
#define NMS  512
#define CQ   2560   // op qkv cols: q | k0 | v0 | k2 | v2
#define CM   1536   // machine qkv cols: q | k1 | v1
#define NE2  65536
#define MSPLIT 8

__device__ __forceinline__ float bf2f(u16 u){ return __uint_as_float(((unsigned)u)<<16); }
__device__ __forceinline__ u16 f2bf(float f){
  unsigned u = __float_as_uint(f);
  u += 0x7FFFu + ((u>>16)&1u);
  return (u16)(u>>16);
}
__device__ __forceinline__ float wred(float v){
  #pragma unroll
  for (int o=32;o;o>>=1) v += __shfl_xor(v,o,64);
  return v;
}
__device__ __forceinline__ float geluf(float x){
  return 0.5f*x*(1.f+erff(x*0.70710678118654752f));
}
// block-level (s,s2) reduction -> one pair per block (no global same-address atomics)
__device__ __forceinline__ void block_stat_out(float s, float s2, float* pstat){
  __shared__ float sb[8];
  s = wred(s); s2 = wred(s2);
  int wv = threadIdx.x >> 6;
  if ((threadIdx.x & 63) == 0){ sb[wv*2] = s; sb[wv*2+1] = s2; }
  __syncthreads();
  if (threadIdx.x == 0){
    float a = 0.f, b = 0.f;
    int nw = blockDim.x >> 6;
    for (int i=0;i<nw;++i){ a += sb[i*2]; b += sb[i*2+1]; }
    pstat[blockIdx.x*2]   = a;
    pstat[blockIdx.x*2+1] = b;
  }
}

// ---------------- zero small ws regions ----------------
__global__ void zero_ws_k(float* acc, int* counts, float* scratch){
  int i = blockIdx.x*blockDim.x + threadIdx.x;
  if (i < 64)   acc[i] = 0.f;
  if (i < 512)  counts[i] = 0;
  if (i < 4096) scratch[i] = 0.f;
}

// ---------------- CSR build for compat edges (dst = machine) ----------------
__global__ void csr_count_k(const int* __restrict__ d2, int* counts){
  int e = blockIdx.x*blockDim.x + threadIdx.x;
  if (e < NE2) atomicAdd(&counts[d2[e]], 1);
}
__global__ __launch_bounds__(512) void csr_scan_k(const int* counts, int* row_start, int* cursor){
  __shared__ int sd[512];
  int t = threadIdx.x;
  sd[t] = counts[t];
  __syncthreads();
  for (int off=1; off<512; off<<=1){
    int v = (t >= off) ? sd[t-off] : 0;
    __syncthreads();
    sd[t] += v;
    __syncthreads();
  }
  row_start[t+1] = sd[t];
  if (t==0) row_start[0] = 0;
  cursor[t] = sd[t] - counts[t];
}
__global__ void csr_scatter_k(const int* __restrict__ d2, int* cursor, int* elist){
  int e = blockIdx.x*blockDim.x + threadIdx.x;
  if (e < NE2){
    int pos = atomicAdd(&cursor[d2[e]], 1);
    elist[pos] = e;
  }
}

// ---------------- W_out: f32 [6][K][N] -> bf16 transposed [6][N][K] (LDS tiled) ----------------
__global__ __launch_bounds__(256) void twout_k(const float* __restrict__ src, u16* __restrict__ dst){
  __shared__ u16 t[64][65];
  int l = blockIdx.x, kb = blockIdx.y*64, nb = blockIdx.z*64;
  const float* s = src + (size_t)l*262144;
  u16* d = dst + (size_t)l*262144;
  int tx = threadIdx.x & 63, ty4 = threadIdx.x >> 6;
  #pragma unroll 4
  for (int p=0;p<16;++p){
    int k = ty4 + p*4;
    t[k][tx] = f2bf(s[(size_t)(kb+k)*512 + nb + tx]);
  }
  __syncthreads();
  #pragma unroll 4
  for (int p=0;p<16;++p){
    int n = ty4 + p*4;
    d[(size_t)(nb+n)*512 + kb + tx] = t[tx][n];
  }
}

// ---------------- Wq transpose into Wc rows 0..511 (q block, identity relation) ----------------
__global__ __launch_bounds__(256) void tq_k(const float* __restrict__ Wq,
                                            u16* __restrict__ Wc_op_t, u16* __restrict__ Wc_m_t){
  __shared__ u16 tl[64][65];
  int blk = blockIdx.x;        // l*2+side
  int l = blk >> 1, side = blk & 1;
  const float* s = Wq + (size_t)blk*262144;
  u16* d = side ? (Wc_m_t + (size_t)l*CM*512) : (Wc_op_t + (size_t)l*CQ*512);
  int kb = blockIdx.y*64, nb = blockIdx.z*64;   // kb: cc (src row), nb: fc
  int tx = threadIdx.x & 63, ty4 = threadIdx.x >> 6;
  #pragma unroll 4
  for (int p=0;p<16;++p){
    int k = ty4 + p*4;
    tl[k][tx] = f2bf(s[(size_t)(kb+k)*512 + nb + tx]);
  }
  __syncthreads();
  #pragma unroll 4
  for (int p=0;p<16;++p){
    int n = ty4 + p*4;
    d[(size_t)(nb+n)*512 + kb + tx] = tl[tx][n];
  }
}

// ---------------- q biases: bias[l][f<512] = bq ----------------
__global__ void qb_k(const float* __restrict__ bq, float* bias_op, float* bias_m){
  int i = blockIdx.x*blockDim.x + threadIdx.x;  // 3072
  if (i >= 3072) return;
  int l = i >> 10, side = (i >> 9) & 1, f = i & 511;
  float v = bq[(l*2+side)*512 + f];
  if (side==0) bias_op[l*CQ + f] = v; else bias_m[l*CM + f] = v;
}

// ---------------- relation-combined weights: 144 small GEMMs [513x64]x[64x64], LDS-staged ----------------
// grid.x = l*48 + s*8 + h (144), grid.y = cc chunk of 128 (4). block 256.
__global__ __launch_bounds__(256) void combine2_k(const float* __restrict__ Wk, const float* __restrict__ bk,
                                                  const float* __restrict__ Wv, const float* __restrict__ bv,
                                                  const float* __restrict__ Ar, const float* __restrict__ Mr,
                                                  u16* __restrict__ Wc_op_t, float* __restrict__ bias_op,
                                                  u16* __restrict__ Wc_m_t, float* __restrict__ bias_m){
  __shared__ float RelS[4096];
  __shared__ u16 tile[64*34];   // pad 34: stride 68B breaks the 64B-stride bank pattern
  int gx = blockIdx.x;
  int l = gx/48; int rem = gx - l*48; int s = rem >> 3; int h = rem & 7;
  int side = (s < 4) ? 0 : 1;
  int r = (s < 4) ? (s+1) : (s-3);
  int useK = side==0 ? (s==0 || s==2) : (s==4);
  int rel  = side==0 ? ((s<2)?0:2) : 1;
  size_t woff = (size_t)(l*2+side)*262144;
  size_t boff = (size_t)(l*2+side)*512;
  const float* W   = (useK ? Wk : Wv) + woff;
  const float* bb  = (useK ? bk : bv) + boff;
  const float* Rel = (useK ? Ar : Mr) + ((size_t)(l*3+rel)*8 + h)*4096;
  int h64 = h*64;
  u16* Wt; float* bias;
  if (side==0){ Wt = Wc_op_t + (size_t)l*CQ*512; bias = bias_op + l*CQ; }
  else        { Wt = Wc_m_t  + (size_t)l*CM*512; bias = bias_m  + l*CM; }
  int rbase = r*512 + h64;
  int t = threadIdx.x, lane = t & 63, wave = t >> 6;
  #pragma unroll
  for (int i=0;i<4;++i) ((floatx4*)RelS)[t + i*256] = ((const floatx4*)Rel)[t + i*256];
  __syncthreads();
  int ystart = blockIdx.y * 128;
  for (int cc0 = ystart; cc0 < ystart+128; cc0 += 32){
    #pragma unroll
    for (int p=0;p<4;++p){
      int ca = cc0 + wave*8 + p*2;
      const float* wa = W + (size_t)ca*512 + h64;
      const float* wb = wa + 512;
      float acc_a = 0.f, acc_b = 0.f;
      #pragma unroll
      for (int dd=0; dd<64; dd+=4){
        floatx4 va = *(const floatx4*)(wa+dd);
        floatx4 vb = *(const floatx4*)(wb+dd);
        #pragma unroll
        for (int e=0;e<4;++e){
          float rv = RelS[(dd+e)*64 + lane];
          acc_a += va[e]*rv;
          acc_b += vb[e]*rv;
        }
      }
      tile[lane*34 + wave*8 + p*2]     = f2bf(acc_a);
      tile[lane*34 + wave*8 + p*2 + 1] = f2bf(acc_b);
    }
    __syncthreads();
    #pragma unroll
    for (int j=0;j<8;++j){
      int e2 = (t>>5) + j*8;
      Wt[(size_t)(rbase+e2)*512 + cc0 + (t&31)] = tile[e2*34 + (t&31)];
    }
    __syncthreads();
  }
  if (blockIdx.y == 0 && wave == 0){   // bias row (cc==512)
    float acc = 0.f;
    #pragma unroll
    for (int dd=0; dd<64; dd+=4){
      floatx4 vb = *(const floatx4*)(bb + h64 + dd);
      #pragma unroll
      for (int e=0;e<4;++e) acc += vb[e]*RelS[(dd+e)*64 + lane];
    }
    bias[rbase + lane] = acc;
  }
}

// ---------------- embedding GEMM (tiny K, f32 in) + per-block LN partials ----------------
__global__ __launch_bounds__(256) void embed_k(const float* __restrict__ X, const float* __restrict__ W,
                                               const float* __restrict__ bias, float* __restrict__ Y,
                                               int total, int K, float* pstat){
  float s = 0.f, s2 = 0.f;
  for (int idx = blockIdx.x*blockDim.x + threadIdx.x; idx < total; idx += gridDim.x*blockDim.x){
    int n = idx >> 9, f = idx & 511;
    float v = bias[f];
    for (int c=0;c<K;++c) v += X[n*K+c] * W[c*512+f];
    Y[idx] = v;
    s += v; s2 += v*v;
  }
  block_stat_out(s, s2, pstat);
}

// ---------------- stats finalize: (Σ,Σ²) partials -> mean, 1/(std+eps) ----------------
__global__ __launch_bounds__(256) void reduce_stats_k(const float* __restrict__ pstat, int nblk,
                                                      float inv_n, float* acc){
  float s = 0.f, s2 = 0.f;
  for (int i = threadIdx.x; i < nblk; i += 256){ s += pstat[2*i]; s2 += pstat[2*i+1]; }
  __shared__ float sb[8];
  s = wred(s); s2 = wred(s2);
  int wv = threadIdx.x >> 6;
  if ((threadIdx.x & 63) == 0){ sb[wv*2] = s; sb[wv*2+1] = s2; }
  __syncthreads();
  if (threadIdx.x == 0){
    float a = 0.f, b = 0.f;
    for (int i=0;i<4;++i){ a += sb[i*2]; b += sb[i*2+1]; }
    float mean = a * inv_n;
    float var  = fmaxf(b * inv_n - mean*mean, 0.f);
    acc[0] = mean;
    acc[1] = 1.f/(sqrtf(var) + 1e-5f);
  }
}

// ---------------- graph-LN apply: dual write f32 + bf16 ----------------
__global__ __launch_bounds__(256) void ln_apply_k(const float* __restrict__ src, float* __restrict__ dst,
                                                  u16* __restrict__ dst_bf,
                                                  const float* __restrict__ w, const float* __restrict__ b,
                                                  const float* acc, int total4){
  float mean = acc[0], rinv = acc[1];
  const floatx4* s4 = (const floatx4*)src;
  floatx4* d4 = (floatx4*)dst;
  shortx4* db4 = (shortx4*)dst_bf;
  const floatx4* w4 = (const floatx4*)w;
  const floatx4* b4 = (const floatx4*)b;
  for (int i = blockIdx.x*blockDim.x + threadIdx.x; i < total4; i += gridDim.x*blockDim.x){
    int f = i & 127;
    floatx4 v = s4[i], wv = w4[f], bv = b4[f];
    shortx4 sv;
    #pragma unroll
    for (int e=0;e<4;++e){ v[e] = (v[e]-mean)*rinv*wv[e] + bv[e]; sv[e] = (short)f2bf(v[e]); }
    d4[i] = v;
    db4[i] = sv;
  }
}

// ---------------- gated residual (vectorized) + per-block LN partials ----------------
__global__ __launch_bounds__(256) void gate_res_k(float* __restrict__ y, const float* __restrict__ x,
                                                  const float* __restrict__ bout, const float* __restrict__ skipel,
                                                  float* pstat, int total4){
  float g = 1.f/(1.f+expf(-(*skipel)));
  floatx4* y4 = (floatx4*)y;
  const floatx4* x4 = (const floatx4*)x;
  const floatx4* b4 = (const floatx4*)bout;
  float s = 0.f, s2 = 0.f;
  for (int i = blockIdx.x*blockDim.x + threadIdx.x; i < total4; i += gridDim.x*blockDim.x){
    floatx4 yv = y4[i], xv = x4[i], bv = b4[i & 127];
    #pragma unroll
    for (int e=0;e<4;++e){
      float o = g*(yv[e]+bv[e]) + (2.f-g)*xv[e];  // gated skip + wrapper residual
      yv[e] = o;
      s += o; s2 += o*o;
    }
    y4[i] = yv;
  }
  block_stat_out(s, s2, pstat);
}

// ---------------- m97-style bf16 MFMA GEMM: C[MxN] = A[MxK] @ Bt[NxK]^T (+bias) ----------------
__global__ __launch_bounds__(256) void gemm_bt(const u16* __restrict__ A, const u16* __restrict__ Bt,
                                               const float* __restrict__ bias, void* __restrict__ Cp,
                                               int M, int N, int K, int out_bf16){
  __shared__ u16 As[128*32];
  __shared__ u16 Bs[128*32];
  const int tid = threadIdx.x;
  const int lane = tid & 63, wave = tid >> 6;
  const int bm = blockIdx.y * 128, bn = blockIdx.x * 128;
  const int wm = wave & 1, wn = wave >> 1;
  const int mrow = lane & 15, quad = lane >> 4;
  const u16* Ab = A + (size_t)bm*K;
  const u16* Bb = Bt + (size_t)bn*K;
  floatx4 acc[4][4];
  #pragma unroll
  for (int a=0;a<4;++a)
    #pragma unroll
    for (int b=0;b<4;++b) acc[a][b] = (floatx4){0.f,0.f,0.f,0.f};
  const int r0 = tid >> 2, c0 = (tid & 3) * 8;
  const int r1 = (tid+256) >> 2, c1 = ((tid+256) & 3) * 8;
  const int lds0 = wave*512;
  const int lds1 = wave*512 + 2048;
  for (int k0 = 0; k0 < K; k0 += 32){
    __builtin_amdgcn_global_load_lds((const __attribute__((address_space(1))) void*)(Ab + (size_t)r0*K + k0 + c0),
                                     (__attribute__((address_space(3))) void*)(As + lds0), 16, 0, 0);
    __builtin_amdgcn_global_load_lds((const __attribute__((address_space(1))) void*)(Ab + (size_t)r1*K + k0 + c1),
                                     (__attribute__((address_space(3))) void*)(As + lds1), 16, 0, 0);
    __builtin_amdgcn_global_load_lds((const __attribute__((address_space(1))) void*)(Bb + (size_t)r0*K + k0 + c0),
                                     (__attribute__((address_space(3))) void*)(Bs + lds0), 16, 0, 0);
    __builtin_amdgcn_global_load_lds((const __attribute__((address_space(1))) void*)(Bb + (size_t)r1*K + k0 + c1),
                                     (__attribute__((address_space(3))) void*)(Bs + lds1), 16, 0, 0);
    __syncthreads();
    shortx8 af[4], bf[4];
    #pragma unroll
    for (int mt=0;mt<4;++mt) af[mt] = *(const shortx8*)(As + (wm*64 + mt*16 + mrow)*32 + quad*8);
    #pragma unroll
    for (int nt=0;nt<4;++nt) bf[nt] = *(const shortx8*)(Bs + (wn*64 + nt*16 + mrow)*32 + quad*8);
    #pragma unroll
    for (int mt=0;mt<4;++mt)
      #pragma unroll
      for (int nt=0;nt<4;++nt)
        acc[mt][nt] = __builtin_amdgcn_mfma_f32_16x16x32_bf16(af[mt], bf[nt], acc[mt][nt], 0, 0, 0);
    __syncthreads();
  }
  #pragma unroll
  for (int mt=0;mt<4;++mt){
    #pragma unroll
    for (int nt=0;nt<4;++nt){
      int col = bn + wn*64 + nt*16 + mrow;
      float bval = bias ? bias[col] : 0.f;
      #pragma unroll
      for (int r2=0;r2<4;++r2){
        int row = bm + wm*64 + mt*16 + quad*4 + r2;
        float v = acc[mt][nt][r2] + bval;
        if (out_bf16) ((u16*)Cp)[(size_t)row*N + col] = f2bf(v);
        else          ((float*)Cp)[(size_t)row*N + col] = v;
      }
    }
  }
}

// ---------------- attention into op nodes -> gelu'd bf16 agg ----------------
__global__ __launch_bounds__(512) void attn_op_k(const u16* __restrict__ qkv_op, const u16* __restrict__ qkv_m,
                                                 const int* __restrict__ s0, const int* __restrict__ s1,
                                                 const float* __restrict__ prel, u16* __restrict__ agg){
  int n = blockIdx.x;
  int h = threadIdx.x >> 6, d = threadIdx.x & 63;
  int hd = h*64 + d;
  float q = bf2f(qkv_op[(size_t)n*CQ + hd]);
  float p0 = prel[h]     * 0.125f;
  float p1 = prel[8 + h] * 0.125f;
  float a[9]; int src[9];
  int i = n & 1023;
  #pragma unroll
  for (int j=0;j<8;++j){
    int m = s1[n*8 + j];
    src[j] = m;
    float t = q * bf2f(qkv_m[(size_t)m*CM + 512 + hd]);
    a[j] = wred(t) * p1;
  }
  bool hasp = (i > 0);
  if (hasp){
    int e0 = (n >> 10)*1023 + i - 1;
    int s = s0[e0];
    src[8] = s;
    float t = q * bf2f(qkv_op[(size_t)s*CQ + 512 + hd]);
    a[8] = wred(t) * p0;
  }
  float mx = a[0];
  #pragma unroll
  for (int j=1;j<8;++j) mx = fmaxf(mx, a[j]);
  if (hasp) mx = fmaxf(mx, a[8]);
  float ssum = 0.f;
  #pragma unroll
  for (int j=0;j<8;++j){ a[j] = expf(a[j]-mx); ssum += a[j]; }
  float e8 = 0.f;
  if (hasp){ e8 = expf(a[8]-mx); ssum += e8; }
  float inv = 1.f/(ssum + 1e-16f);
  float o = 0.f;
  #pragma unroll
  for (int j=0;j<8;++j) o += a[j] * bf2f(qkv_m[(size_t)src[j]*CM + 1024 + hd]);
  if (hasp) o += e8 * bf2f(qkv_op[(size_t)src[8]*CQ + 1024 + hd]);
  agg[(size_t)n*512 + hd] = f2bf(geluf(o * inv));
}

// ---------------- machine attention, split-edge online softmax partials ----------------
__global__ __launch_bounds__(512) void attn_m_part_k(const u16* __restrict__ qkv_op, const u16* __restrict__ qkv_m,
                                                     const int* __restrict__ s2, const int* __restrict__ row_start,
                                                     const int* __restrict__ elist, const float* __restrict__ prel,
                                                     float* __restrict__ pml, float* __restrict__ pacc){
  int m = blockIdx.x, sp = blockIdx.y;
  int h = threadIdx.x >> 6, d = threadIdx.x & 63;
  int hd = h*64 + d;
  int beg = row_start[m];
  int deg = row_start[m+1] - beg;
  int cs = (deg + MSPLIT - 1) / MSPLIT;
  int start = sp * cs;
  int end = min(start + cs, deg);
  float q = bf2f(qkv_m[(size_t)m*CM + hd]);
  float p2 = prel[16 + h] * 0.125f;
  float mi = -1e30f, l = 0.f, acc = 0.f;
  for (int idx = start; idx < end; ++idx){
    int e = elist[beg + idx]; int so = s2[e];
    float t = q * bf2f(qkv_op[(size_t)so*CQ + 1536 + hd]);
    t = wred(t) * p2;
    float v = bf2f(qkv_op[(size_t)so*CQ + 2048 + hd]);
    float mn = fmaxf(mi, t);
    float sc = expf(mi - mn);
    float e1 = expf(t - mn);
    l = l*sc + e1;
    acc = acc*sc + e1*v;
    mi = mn;
  }
  int pidx = (m*MSPLIT + sp)*8 + h;
  if (d == 0){ pml[pidx*2] = mi; pml[pidx*2+1] = l; }
  pacc[(size_t)pidx*64 + d] = acc;
}
// combine partials -> gelu'd bf16 agg
__global__ __launch_bounds__(512) void attn_m_comb_k(const float* __restrict__ pml, const float* __restrict__ pacc,
                                                     u16* __restrict__ agg){
  int m = blockIdx.x;
  int h = threadIdx.x >> 6, d = threadIdx.x & 63;
  float M = -1e30f;
  #pragma unroll
  for (int sp=0; sp<MSPLIT; ++sp) M = fmaxf(M, pml[((m*MSPLIT+sp)*8+h)*2]);
  float l = 0.f, acc = 0.f;
  #pragma unroll
  for (int sp=0; sp<MSPLIT; ++sp){
    int pidx = (m*MSPLIT+sp)*8+h;
    float sc = expf(pml[pidx*2] - M);
    l   += sc * pml[pidx*2+1];
    acc += sc * pacc[(size_t)pidx*64 + d];
  }
  agg[(size_t)m*512 + h*64 + d] = f2bf(geluf(acc / (l + 1e-16f)));
}

// ---------------- final emit (f32 out, vectorized) + means ----------------
__global__ __launch_bounds__(256) void emit_k(const float* __restrict__ x_op, const float* __restrict__ x_m,
                                              float* __restrict__ out){
  const int T1 = NOPS*128, T2 = T1 + NMS*128;
  const floatx4* a4 = (const floatx4*)x_op;
  const floatx4* b4 = (const floatx4*)x_m;
  floatx4* o4 = (floatx4*)out;
  for (int i = blockIdx.x*blockDim.x + threadIdx.x; i < T2; i += gridDim.x*blockDim.x){
    o4[i] = (i < T1) ? a4[i] : b4[i - T1];
  }
}
__global__ __launch_bounds__(512) void meanj_part_k(const float* __restrict__ x_op, float* scratch){
  int b = blockIdx.x, chunk = blockIdx.y, f = threadIdx.x;
  float s = 0.f;
  for (int r=0;r<128;++r){
    int row = b*1024 + chunk*128 + r;
    s += x_op[(size_t)row*512 + f];
  }
  atomicAdd(&scratch[b*512 + f], s);
}
__global__ void meanj_fin_k(const float* scratch, float* out){
  int i = blockIdx.x*blockDim.x + threadIdx.x;
  if (i < 4096) out[4456448 + i] = scratch[i] * (1.f/1024.f);
}
__global__ __launch_bounds__(512) void meanm_k(const float* __restrict__ x_m, float* out){
  int b = blockIdx.x, f = threadIdx.x;
  float s = 0.f;
  for (int r=0;r<64;++r) s += x_m[(size_t)(b*64+r)*512 + f];
  out[4460544 + b*512 + f] = s * (1.f/64.f);
}

extern "C" void kernel_launch(void* const* d_in, const int* in_sizes, int n_in,
                              void* d_out, int out_size, void* d_ws, size_t ws_size,
                              hipStream_t stream){
  const float* op_x      = (const float*)d_in[0];
  const float* machine_x = (const float*)d_in[1];
  const float* W_emb_op  = (const float*)d_in[2];
  const float* b_emb_op  = (const float*)d_in[3];
  const float* W_emb_m   = (const float*)d_in[4];
  const float* b_emb_m   = (const float*)d_in[5];
  const float* opn_w     = (const float*)d_in[6];
  const float* opn_b     = (const float*)d_in[7];
  const float* mn_w      = (const float*)d_in[8];
  const float* mn_b      = (const float*)d_in[9];
  const float* Wk        = (const float*)d_in[10];
  const float* bk        = (const float*)d_in[11];
  const float* Wq        = (const float*)d_in[12];
  const float* bq        = (const float*)d_in[13];
  const float* Wv        = (const float*)d_in[14];
  const float* bv        = (const float*)d_in[15];
  const float* A_rel     = (const float*)d_in[16];
  const float* M_rel     = (const float*)d_in[17];
  const float* p_rel     = (const float*)d_in[18];
  const float* W_out     = (const float*)d_in[19];
  const float* b_out     = (const float*)d_in[20];
  const float* skip      = (const float*)d_in[21];
  const float* ln_w      = (const float*)d_in[22];
  const float* ln_b      = (const float*)d_in[23];
  const int* s0          = (const int*)d_in[24];
  const int* s1          = (const int*)d_in[25];
  const int* s2          = (const int*)d_in[26];
  const int* d2          = s2 + NE2;
  float* out = (float*)d_out;

  char* ws = (char*)d_ws;
  size_t off = 0;
  auto alloc = [&](size_t bytes)->void*{
    void* p = ws + off;
    off = (off + bytes + 255) & ~(size_t)255;
    return p;
  };
  float* accb      = (float*)alloc(64*4);
  int*   counts    = (int*)  alloc(512*4);
  int*   row_start = (int*)  alloc(513*4);
  int*   cursor    = (int*)  alloc(512*4);
  int*   elist     = (int*)  alloc((size_t)NE2*4);
  float* scratch   = (float*)alloc(4096*4);
  float* pstat     = (float*)alloc(4096*4);
  float* x_op      = (float*)alloc((size_t)NOPS*512*4);
  u16*   x_op_bf   = (u16*)  alloc((size_t)NOPS*512*2);
  float* x_m       = (float*)alloc((size_t)NMS*512*4);
  u16*   x_m_bf    = (u16*)  alloc((size_t)NMS*512*2);
  u16*   qkv_op    = (u16*)  alloc((size_t)NOPS*CQ*2);   // 40MB; o_op (16MB f32) aliases it
  u16*   qkv_m     = (u16*)  alloc((size_t)NMS*CM*2);
  u16*   agg_op    = (u16*)  alloc((size_t)NOPS*512*2);
  u16*   agg_m     = (u16*)  alloc((size_t)NMS*512*2);
  u16*   Wc_op_t   = (u16*)  alloc((size_t)3*CQ*512*2);  // per-layer transposed [N][K]
  float* bias_op   = (float*)alloc((size_t)3*CQ*4);
  u16*   Wc_m_t    = (u16*)  alloc((size_t)3*CM*512*2);
  float* bias_m    = (float*)alloc((size_t)3*CM*4);
  u16*   Wout_t    = (u16*)  alloc((size_t)6*262144*2);
  float* pml       = (float*)alloc((size_t)NMS*MSPLIT*8*2*4);
  float* pacc      = (float*)alloc((size_t)NMS*MSPLIT*8*64*4);
  float* o_op      = (float*)qkv_op;
  float* o_m       = (float*)qkv_m;
  float* pstat_m   = pstat + 2048;

  const int TOP = NOPS*512;
  const int TM  = NMS*512;
  const int T4OP = TOP/4, T4M = TM/4;
  const int GB_OP = 1024, GB_M = 128;

  // setup: CSR, weight prep (all 3 layers), zero accumulators
  zero_ws_k<<<16,256,0,stream>>>(accb, counts, scratch);
  csr_count_k<<<256,256,0,stream>>>(d2, counts);
  csr_scan_k<<<1,512,0,stream>>>(counts, row_start, cursor);
  csr_scatter_k<<<256,256,0,stream>>>(d2, cursor, elist);
  twout_k<<<dim3(6,8,8),256,0,stream>>>(W_out, Wout_t);
  tq_k<<<dim3(6,8,8),256,0,stream>>>(Wq, Wc_op_t, Wc_m_t);
  qb_k<<<12,256,0,stream>>>(bq, bias_op, bias_m);
  combine2_k<<<dim3(144,4),256,0,stream>>>(Wk, bk, Wv, bv, A_rel, M_rel, Wc_op_t, bias_op, Wc_m_t, bias_m);

  // embeddings + graph LN
  embed_k<<<GB_OP,256,0,stream>>>(op_x, W_emb_op, b_emb_op, x_op, TOP, 16, pstat);
  embed_k<<<GB_M,256,0,stream>>>(machine_x, W_emb_m, b_emb_m, x_m, TM, 8, pstat_m);
  reduce_stats_k<<<1,256,0,stream>>>(pstat,   GB_OP, 1.f/TOP, accb + 0);
  reduce_stats_k<<<1,256,0,stream>>>(pstat_m, GB_M,  1.f/TM,  accb + 2);
  ln_apply_k<<<1024,256,0,stream>>>(x_op, x_op, x_op_bf, opn_w, opn_b, accb + 0, T4OP);
  ln_apply_k<<<128,256,0,stream>>>(x_m, x_m, x_m_bf, mn_w, mn_b, accb + 2, T4M);

  for (int l=0; l<3; ++l){
    gemm_bt<<<dim3(CQ/128, NOPS/128),256,0,stream>>>(x_op_bf, Wc_op_t + (size_t)l*CQ*512, bias_op + l*CQ, qkv_op, NOPS, CQ, 512, 1);
    gemm_bt<<<dim3(CM/128, NMS/128),256,0,stream>>>(x_m_bf, Wc_m_t + (size_t)l*CM*512, bias_m + l*CM, qkv_m, NMS, CM, 512, 1);
    attn_op_k<<<NOPS,512,0,stream>>>(qkv_op, qkv_m, s0, s1, p_rel + l*24, agg_op);
    attn_m_part_k<<<dim3(NMS,MSPLIT),512,0,stream>>>(qkv_op, qkv_m, s2, row_start, elist, p_rel + l*24, pml, pacc);
    attn_m_comb_k<<<NMS,512,0,stream>>>(pml, pacc, agg_m);
    gemm_bt<<<dim3(512/128, NOPS/128),256,0,stream>>>(agg_op, Wout_t + (size_t)(l*2+0)*262144, nullptr, o_op, NOPS, 512, 512, 0);
    gate_res_k<<<GB_OP,256,0,stream>>>(o_op, x_op, b_out + (size_t)(l*2+0)*512, skip + l*2+0, pstat, T4OP);
    gemm_bt<<<dim3(512/128, NMS/128),256,0,stream>>>(agg_m, Wout_t + (size_t)(l*2+1)*262144, nullptr, o_m, NMS, 512, 512, 0);
    gate_res_k<<<GB_M,256,0,stream>>>(o_m, x_m, b_out + (size_t)(l*2+1)*512, skip + l*2+1, pstat_m, T4M);
    reduce_stats_k<<<1,256,0,stream>>>(pstat,   GB_OP, 1.f/TOP, accb + 2*(2+2*l));
    reduce_stats_k<<<1,256,0,stream>>>(pstat_m, GB_M,  1.f/TM,  accb + 2*(3+2*l));
    ln_apply_k<<<1024,256,0,stream>>>(o_op, x_op, x_op_bf, ln_w + l*512, ln_b + l*512, accb + 2*(2+2*l), T4OP);
    ln_apply_k<<<128,256,0,stream>>>(o_m, x_m, x_m_bf, ln_w + l*512, ln_b + l*512, accb + 2*(3+2*l), T4M);
  }

  emit_k<<<2048,256,0,stream>>>(x_op, x_m, out);
  meanj_part_k<<<dim3(8,8),512,0,stream>>>(x_op, scratch);
  meanj_fin_k<<<16,256,0,stream>>>(scratch, out);
  meanm_k<<<8,512,0,stream>>>(x_m, out);
}

// Round 8
// 855.806 us; speedup vs baseline: 2.8026x; 1.1104x over previous
//
#include <hip/hip_runtime.h>

typedef unsigned short u16;
typedef __attribute__((ext_vector_type(4))) float floatx4;
typedef __attribute__((ext_vector_type(8))) short shortx8;
typedef __attribute__((ext_vector_type(4))) short shortx4;

#define NOPS 8192
#define NMS  512
#define CQ   2560   // op qkv cols: q | k0 | v0 | k2 | v2
#define CM   1536   // machine qkv cols: q | k1 | v1
#define NE2  65536

__device__ __forceinline__ float bf2f(u16 u){ return __uint_as_float(((unsigned)u)<<16); }
__device__ __forceinline__ u16 f2bf(float f){
  unsigned u = __float_as_uint(f);
  u += 0x7FFFu + ((u>>16)&1u);
  return (u16)(u>>16);
}
__device__ __forceinline__ float wred(float v){
  #pragma unroll
  for (int o=32;o;o>>=1) v += __shfl_xor(v,o,64);
  return v;
}
__device__ __forceinline__ float wredmax(float v){
  #pragma unroll
  for (int o=32;o;o>>=1) v = fmaxf(v, __shfl_xor(v,o,64));
  return v;
}
__device__ __forceinline__ float geluf(float x){
  return 0.5f*x*(1.f+erff(x*0.70710678118654752f));
}
// block-level (s,s2) reduction -> one pair per block (no global same-address atomics)
__device__ __forceinline__ void block_stat_out(float s, float s2, float* pstat){
  __shared__ float sb[8];
  s = wred(s); s2 = wred(s2);
  int wv = threadIdx.x >> 6;
  if ((threadIdx.x & 63) == 0){ sb[wv*2] = s; sb[wv*2+1] = s2; }
  __syncthreads();
  if (threadIdx.x == 0){
    float a = 0.f, b = 0.f;
    int nw = blockDim.x >> 6;
    for (int i=0;i<nw;++i){ a += sb[i*2]; b += sb[i*2+1]; }
    pstat[blockIdx.x*2]   = a;
    pstat[blockIdx.x*2+1] = b;
  }
}

// ---------------- zero ws regions: Ct (512K floats) + accb + scratch ----------------
__global__ __launch_bounds__(256) void zero_ws_k(float* Ct, float* acc, float* scratch){
  for (int i = blockIdx.x*blockDim.x + threadIdx.x; i < 524288 + 4096 + 64; i += gridDim.x*blockDim.x){
    if (i < 524288) Ct[i] = 0.f;
    else if (i < 524288 + 4096) scratch[i - 524288] = 0.f;
    else acc[i - 524288 - 4096] = 0.f;
  }
}
// ---------------- edge multiplicity counts: Ct[mach_global][op_local] ----------------
__global__ void cnt_k(const int* __restrict__ s1, float* Ct){
  int e = blockIdx.x*blockDim.x + threadIdx.x;
  if (e < NE2) atomicAdd(&Ct[(size_t)s1[e]*1024 + ((e>>3) & 1023)], 1.f);
}

// ---------------- W_out: f32 [6][K][N] -> bf16 transposed [6][N][K] (LDS tiled) ----------------
__global__ __launch_bounds__(256) void twout_k(const float* __restrict__ src, u16* __restrict__ dst){
  __shared__ u16 t[64][65];
  int l = blockIdx.x, kb = blockIdx.y*64, nb = blockIdx.z*64;
  const float* s = src + (size_t)l*262144;
  u16* d = dst + (size_t)l*262144;
  int tx = threadIdx.x & 63, ty4 = threadIdx.x >> 6;
  #pragma unroll 4
  for (int p=0;p<16;++p){
    int k = ty4 + p*4;
    t[k][tx] = f2bf(s[(size_t)(kb+k)*512 + nb + tx]);
  }
  __syncthreads();
  #pragma unroll 4
  for (int p=0;p<16;++p){
    int n = ty4 + p*4;
    d[(size_t)(nb+n)*512 + kb + tx] = t[tx][n];
  }
}

// ---------------- Wq transpose into Wc rows 0..511 (q block, identity relation) ----------------
__global__ __launch_bounds__(256) void tq_k(const float* __restrict__ Wq,
                                            u16* __restrict__ Wc_op_t, u16* __restrict__ Wc_m_t){
  __shared__ u16 tl[64][65];
  int blk = blockIdx.x;        // l*2+side
  int l = blk >> 1, side = blk & 1;
  const float* s = Wq + (size_t)blk*262144;
  u16* d = side ? (Wc_m_t + (size_t)l*CM*512) : (Wc_op_t + (size_t)l*CQ*512);
  int kb = blockIdx.y*64, nb = blockIdx.z*64;
  int tx = threadIdx.x & 63, ty4 = threadIdx.x >> 6;
  #pragma unroll 4
  for (int p=0;p<16;++p){
    int k = ty4 + p*4;
    tl[k][tx] = f2bf(s[(size_t)(kb+k)*512 + nb + tx]);
  }
  __syncthreads();
  #pragma unroll 4
  for (int p=0;p<16;++p){
    int n = ty4 + p*4;
    d[(size_t)(nb+n)*512 + kb + tx] = tl[tx][n];
  }
}

// ---------------- q biases ----------------
__global__ void qb_k(const float* __restrict__ bq, float* bias_op, float* bias_m){
  int i = blockIdx.x*blockDim.x + threadIdx.x;
  if (i >= 3072) return;
  int l = i >> 10, side = (i >> 9) & 1, f = i & 511;
  float v = bq[(l*2+side)*512 + f];
  if (side==0) bias_op[l*CQ + f] = v; else bias_m[l*CM + f] = v;
}

// ---------------- relation-combined weights: 144 small GEMMs, LDS-staged ----------------
__global__ __launch_bounds__(256) void combine2_k(const float* __restrict__ Wk, const float* __restrict__ bk,
                                                  const float* __restrict__ Wv, const float* __restrict__ bv,
                                                  const float* __restrict__ Ar, const float* __restrict__ Mr,
                                                  u16* __restrict__ Wc_op_t, float* __restrict__ bias_op,
                                                  u16* __restrict__ Wc_m_t, float* __restrict__ bias_m){
  __shared__ float RelS[4096];
  __shared__ u16 tile[64*34];
  int gx = blockIdx.x;
  int l = gx/48; int rem = gx - l*48; int s = rem >> 3; int h = rem & 7;
  int side = (s < 4) ? 0 : 1;
  int r = (s < 4) ? (s+1) : (s-3);
  int useK = side==0 ? (s==0 || s==2) : (s==4);
  int rel  = side==0 ? ((s<2)?0:2) : 1;
  size_t woff = (size_t)(l*2+side)*262144;
  size_t boff = (size_t)(l*2+side)*512;
  const float* W   = (useK ? Wk : Wv) + woff;
  const float* bb  = (useK ? bk : bv) + boff;
  const float* Rel = (useK ? Ar : Mr) + ((size_t)(l*3+rel)*8 + h)*4096;
  int h64 = h*64;
  u16* Wt; float* bias;
  if (side==0){ Wt = Wc_op_t + (size_t)l*CQ*512; bias = bias_op + l*CQ; }
  else        { Wt = Wc_m_t  + (size_t)l*CM*512; bias = bias_m  + l*CM; }
  int rbase = r*512 + h64;
  int t = threadIdx.x, lane = t & 63, wave = t >> 6;
  #pragma unroll
  for (int i=0;i<4;++i) ((floatx4*)RelS)[t + i*256] = ((const floatx4*)Rel)[t + i*256];
  __syncthreads();
  int ystart = blockIdx.y * 128;
  for (int cc0 = ystart; cc0 < ystart+128; cc0 += 32){
    #pragma unroll
    for (int p=0;p<4;++p){
      int ca = cc0 + wave*8 + p*2;
      const float* wa = W + (size_t)ca*512 + h64;
      const float* wb = wa + 512;
      float acc_a = 0.f, acc_b = 0.f;
      #pragma unroll
      for (int dd=0; dd<64; dd+=4){
        floatx4 va = *(const floatx4*)(wa+dd);
        floatx4 vb = *(const floatx4*)(wb+dd);
        #pragma unroll
        for (int e=0;e<4;++e){
          float rv = RelS[(dd+e)*64 + lane];
          acc_a += va[e]*rv;
          acc_b += vb[e]*rv;
        }
      }
      tile[lane*34 + wave*8 + p*2]     = f2bf(acc_a);
      tile[lane*34 + wave*8 + p*2 + 1] = f2bf(acc_b);
    }
    __syncthreads();
    #pragma unroll
    for (int j=0;j<8;++j){
      int e2 = (t>>5) + j*8;
      Wt[(size_t)(rbase+e2)*512 + cc0 + (t&31)] = tile[e2*34 + (t&31)];
    }
    __syncthreads();
  }
  if (blockIdx.y == 0 && wave == 0){
    float acc = 0.f;
    #pragma unroll
    for (int dd=0; dd<64; dd+=4){
      floatx4 vb = *(const floatx4*)(bb + h64 + dd);
      #pragma unroll
      for (int e=0;e<4;++e) acc += vb[e]*RelS[(dd+e)*64 + lane];
    }
    bias[rbase + lane] = acc;
  }
}

// ---------------- embedding GEMM (tiny K, f32 in) + per-block LN partials ----------------
__global__ __launch_bounds__(256) void embed_k(const float* __restrict__ X, const float* __restrict__ W,
                                               const float* __restrict__ bias, float* __restrict__ Y,
                                               int total, int K, float* pstat){
  float s = 0.f, s2 = 0.f;
  for (int idx = blockIdx.x*blockDim.x + threadIdx.x; idx < total; idx += gridDim.x*blockDim.x){
    int n = idx >> 9, f = idx & 511;
    float v = bias[f];
    for (int c=0;c<K;++c) v += X[n*K+c] * W[c*512+f];
    Y[idx] = v;
    s += v; s2 += v*v;
  }
  block_stat_out(s, s2, pstat);
}

// ---------------- stats finalize ----------------
__global__ __launch_bounds__(256) void reduce_stats_k(const float* __restrict__ pstat, int nblk,
                                                      float inv_n, float* acc){
  float s = 0.f, s2 = 0.f;
  for (int i = threadIdx.x; i < nblk; i += 256){ s += pstat[2*i]; s2 += pstat[2*i+1]; }
  __shared__ float sb[8];
  s = wred(s); s2 = wred(s2);
  int wv = threadIdx.x >> 6;
  if ((threadIdx.x & 63) == 0){ sb[wv*2] = s; sb[wv*2+1] = s2; }
  __syncthreads();
  if (threadIdx.x == 0){
    float a = 0.f, b = 0.f;
    for (int i=0;i<4;++i){ a += sb[i*2]; b += sb[i*2+1]; }
    float mean = a * inv_n;
    float var  = fmaxf(b * inv_n - mean*mean, 0.f);
    acc[0] = mean;
    acc[1] = 1.f/(sqrtf(var) + 1e-5f);
  }
}

// ---------------- graph-LN apply: dual write f32 + bf16 ----------------
__global__ __launch_bounds__(256) void ln_apply_k(const float* __restrict__ src, float* __restrict__ dst,
                                                  u16* __restrict__ dst_bf,
                                                  const float* __restrict__ w, const float* __restrict__ b,
                                                  const float* acc, int total4){
  float mean = acc[0], rinv = acc[1];
  const floatx4* s4 = (const floatx4*)src;
  floatx4* d4 = (floatx4*)dst;
  shortx4* db4 = (shortx4*)dst_bf;
  const floatx4* w4 = (const floatx4*)w;
  const floatx4* b4 = (const floatx4*)b;
  for (int i = blockIdx.x*blockDim.x + threadIdx.x; i < total4; i += gridDim.x*blockDim.x){
    int f = i & 127;
    floatx4 v = s4[i], wv = w4[f], bv = b4[f];
    shortx4 sv;
    #pragma unroll
    for (int e=0;e<4;++e){ v[e] = (v[e]-mean)*rinv*wv[e] + bv[e]; sv[e] = (short)f2bf(v[e]); }
    d4[i] = v;
    db4[i] = sv;
  }
}

// ---------------- gated residual + per-block LN partials ----------------
__global__ __launch_bounds__(256) void gate_res_k(float* __restrict__ y, const float* __restrict__ x,
                                                  const float* __restrict__ bout, const float* __restrict__ skipel,
                                                  float* pstat, int total4){
  float g = 1.f/(1.f+expf(-(*skipel)));
  floatx4* y4 = (floatx4*)y;
  const floatx4* x4 = (const floatx4*)x;
  const floatx4* b4 = (const floatx4*)bout;
  float s = 0.f, s2 = 0.f;
  for (int i = blockIdx.x*blockDim.x + threadIdx.x; i < total4; i += gridDim.x*blockDim.x){
    floatx4 yv = y4[i], xv = x4[i], bv = b4[i & 127];
    #pragma unroll
    for (int e=0;e<4;++e){
      float o = g*(yv[e]+bv[e]) + (2.f-g)*xv[e];
      yv[e] = o;
      s += o; s2 += o*o;
    }
    y4[i] = yv;
  }
  block_stat_out(s, s2, pstat);
}

// ---------------- m97-style bf16 MFMA GEMM: C[MxN] = A[MxK] @ Bt[NxK]^T (+bias) ----------------
__global__ __launch_bounds__(256) void gemm_bt(const u16* __restrict__ A, const u16* __restrict__ Bt,
                                               const float* __restrict__ bias, void* __restrict__ Cp,
                                               int M, int N, int K, int out_bf16){
  __shared__ u16 As[128*32];
  __shared__ u16 Bs[128*32];
  const int tid = threadIdx.x;
  const int lane = tid & 63, wave = tid >> 6;
  const int bm = blockIdx.y * 128, bn = blockIdx.x * 128;
  const int wm = wave & 1, wn = wave >> 1;
  const int mrow = lane & 15, quad = lane >> 4;
  const u16* Ab = A + (size_t)bm*K;
  const u16* Bb = Bt + (size_t)bn*K;
  floatx4 acc[4][4];
  #pragma unroll
  for (int a=0;a<4;++a)
    #pragma unroll
    for (int b=0;b<4;++b) acc[a][b] = (floatx4){0.f,0.f,0.f,0.f};
  const int r0 = tid >> 2, c0 = (tid & 3) * 8;
  const int r1 = (tid+256) >> 2, c1 = ((tid+256) & 3) * 8;
  const int lds0 = wave*512;
  const int lds1 = wave*512 + 2048;
  for (int k0 = 0; k0 < K; k0 += 32){
    __builtin_amdgcn_global_load_lds((const __attribute__((address_space(1))) void*)(Ab + (size_t)r0*K + k0 + c0),
                                     (__attribute__((address_space(3))) void*)(As + lds0), 16, 0, 0);
    __builtin_amdgcn_global_load_lds((const __attribute__((address_space(1))) void*)(Ab + (size_t)r1*K + k0 + c1),
                                     (__attribute__((address_space(3))) void*)(As + lds1), 16, 0, 0);
    __builtin_amdgcn_global_load_lds((const __attribute__((address_space(1))) void*)(Bb + (size_t)r0*K + k0 + c0),
                                     (__attribute__((address_space(3))) void*)(Bs + lds0), 16, 0, 0);
    __builtin_amdgcn_global_load_lds((const __attribute__((address_space(1))) void*)(Bb + (size_t)r1*K + k0 + c1),
                                     (__attribute__((address_space(3))) void*)(Bs + lds1), 16, 0, 0);
    __syncthreads();
    shortx8 af[4], bf[4];
    #pragma unroll
    for (int mt=0;mt<4;++mt) af[mt] = *(const shortx8*)(As + (wm*64 + mt*16 + mrow)*32 + quad*8);
    #pragma unroll
    for (int nt=0;nt<4;++nt) bf[nt] = *(const shortx8*)(Bs + (wn*64 + nt*16 + mrow)*32 + quad*8);
    #pragma unroll
    for (int mt=0;mt<4;++mt)
      #pragma unroll
      for (int nt=0;nt<4;++nt)
        acc[mt][nt] = __builtin_amdgcn_mfma_f32_16x16x32_bf16(af[mt], bf[nt], acc[mt][nt], 0, 0, 0);
    __syncthreads();
  }
  #pragma unroll
  for (int mt=0;mt<4;++mt){
    #pragma unroll
    for (int nt=0;nt<4;++nt){
      int col = bn + wn*64 + nt*16 + mrow;
      float bval = bias ? bias[col] : 0.f;
      #pragma unroll
      for (int r2=0;r2<4;++r2){
        int row = bm + wm*64 + mt*16 + quad*4 + r2;
        float v = acc[mt][nt][r2] + bval;
        if (out_bf16) ((u16*)Cp)[(size_t)row*N + col] = f2bf(v);
        else          ((float*)Cp)[(size_t)row*N + col] = v;
      }
    }
  }
}

// ---------------- attention into op nodes -> gelu'd bf16 agg ----------------
__global__ __launch_bounds__(512) void attn_op_k(const u16* __restrict__ qkv_op, const u16* __restrict__ qkv_m,
                                                 const int* __restrict__ s0, const int* __restrict__ s1,
                                                 const float* __restrict__ prel, u16* __restrict__ agg){
  int n = blockIdx.x;
  int h = threadIdx.x >> 6, d = threadIdx.x & 63;
  int hd = h*64 + d;
  float q = bf2f(qkv_op[(size_t)n*CQ + hd]);
  float p0 = prel[h]     * 0.125f;
  float p1 = prel[8 + h] * 0.125f;
  float a[9]; int src[9];
  int i = n & 1023;
  #pragma unroll
  for (int j=0;j<8;++j){
    int m = s1[n*8 + j];
    src[j] = m;
    float t = q * bf2f(qkv_m[(size_t)m*CM + 512 + hd]);
    a[j] = wred(t) * p1;
  }
  bool hasp = (i > 0);
  if (hasp){
    int e0 = (n >> 10)*1023 + i - 1;
    int s = s0[e0];
    src[8] = s;
    float t = q * bf2f(qkv_op[(size_t)s*CQ + 512 + hd]);
    a[8] = wred(t) * p0;
  }
  float mx = a[0];
  #pragma unroll
  for (int j=1;j<8;++j) mx = fmaxf(mx, a[j]);
  if (hasp) mx = fmaxf(mx, a[8]);
  float ssum = 0.f;
  #pragma unroll
  for (int j=0;j<8;++j){ a[j] = expf(a[j]-mx); ssum += a[j]; }
  float e8 = 0.f;
  if (hasp){ e8 = expf(a[8]-mx); ssum += e8; }
  float inv = 1.f/(ssum + 1e-16f);
  float o = 0.f;
  #pragma unroll
  for (int j=0;j<8;++j) o += a[j] * bf2f(qkv_m[(size_t)src[j]*CM + 1024 + hd]);
  if (hasp) o += e8 * bf2f(qkv_op[(size_t)src[8]*CQ + 1024 + hd]);
  agg[(size_t)n*512 + hd] = f2bf(geluf(o * inv));
}

// ---------------- machine scores: batched MFMA GEMM S2[b,h] = q_m(64xK64) x k2^T ----------------
// grid (8 n-tiles, 64 bh), block 256 (4 waves splitting 128 n-cols)
__global__ __launch_bounds__(256) void qk2_k(const u16* __restrict__ qkv_op, const u16* __restrict__ qkv_m,
                                             const float* __restrict__ prel, float* __restrict__ S2f){
  __shared__ u16 As[64*72];   // q_m tile, stride 72 (144B rows: 16B-aligned, 2-way bank alias)
  __shared__ u16 Bs[128*72];  // k2 tile
  int bh = blockIdx.y; int b = bh >> 3, h = bh & 7;
  int n0 = blockIdx.x * 128;
  int tid = threadIdx.x, lane = tid & 63, wave = tid >> 6;
  int mrow = lane & 15, quad = lane >> 4;
  float p2 = prel[16 + h] * 0.125f;
  {
    int row = tid >> 2, col = (tid & 3) * 16;
    const u16* src = qkv_m + (size_t)(b*64+row)*CM + h*64 + col;
    *(shortx8*)(As + row*72 + col)     = *(const shortx8*)(src);
    *(shortx8*)(As + row*72 + col + 8) = *(const shortx8*)(src + 8);
  }
  {
    int row = tid >> 1, col = (tid & 1) * 32;
    const u16* src = qkv_op + (size_t)(b*1024 + n0 + row)*CQ + 1536 + h*64 + col;
    #pragma unroll
    for (int e=0;e<4;++e)
      *(shortx8*)(Bs + row*72 + col + e*8) = *(const shortx8*)(src + e*8);
  }
  __syncthreads();
  floatx4 acc[4][2];
  #pragma unroll
  for (int a=0;a<4;++a){ acc[a][0] = (floatx4){0,0,0,0}; acc[a][1] = (floatx4){0,0,0,0}; }
  #pragma unroll
  for (int ks=0; ks<2; ++ks){
    shortx8 af[4], bf[2];
    #pragma unroll
    for (int mt=0;mt<4;++mt) af[mt] = *(const shortx8*)(As + (mt*16 + mrow)*72 + ks*32 + quad*8);
    #pragma unroll
    for (int nt=0;nt<2;++nt) bf[nt] = *(const shortx8*)(Bs + (wave*32 + nt*16 + mrow)*72 + ks*32 + quad*8);
    #pragma unroll
    for (int mt=0;mt<4;++mt)
      #pragma unroll
      for (int nt=0;nt<2;++nt)
        acc[mt][nt] = __builtin_amdgcn_mfma_f32_16x16x32_bf16(af[mt], bf[nt], acc[mt][nt], 0, 0, 0);
  }
  #pragma unroll
  for (int mt=0;mt<4;++mt){
    #pragma unroll
    for (int nt=0;nt<2;++nt){
      int n = n0 + wave*32 + nt*16 + mrow;
      #pragma unroll
      for (int r2=0;r2<4;++r2){
        int m = mt*16 + quad*4 + r2;
        S2f[((size_t)(b*64 + m)*8 + h)*1024 + n] = acc[mt][nt][r2] * p2;
      }
    }
  }
}

// ---------------- masked multiplicity softmax: S2 -> W2 (bf16 weights incl. count) ----------------
__global__ __launch_bounds__(512) void msoft_k(const float* __restrict__ S2f, const float* __restrict__ Ct,
                                               u16* __restrict__ W2){
  int m = blockIdx.x;
  int h = threadIdx.x >> 6, d = threadIdx.x & 63;
  const float* srow = S2f + ((size_t)m*8 + h)*1024;
  const float* crow = Ct + (size_t)m*1024;
  float s[16], c[16];
  #pragma unroll
  for (int it=0; it<16; ++it){
    s[it] = srow[it*64 + d];
    c[it] = crow[it*64 + d];
  }
  float mx = -1e30f;
  #pragma unroll
  for (int it=0; it<16; ++it) if (c[it] > 0.f) mx = fmaxf(mx, s[it]);
  mx = wredmax(mx);
  float e[16], L = 0.f;
  #pragma unroll
  for (int it=0; it<16; ++it){
    e[it] = (c[it] > 0.f) ? c[it]*expf(s[it]-mx) : 0.f;
    L += e[it];
  }
  L = wred(L);
  float inv = 1.f/(L + 1e-16f);
  u16* wrow = W2 + ((size_t)m*8 + h)*1024;
  #pragma unroll
  for (int it=0; it<16; ++it) wrow[it*64 + d] = f2bf(e[it]*inv);
}

// ---------------- machine agg: batched MFMA GEMM agg_m[b,h] = W2(64xK1024) x v2 -> gelu bf16 ----------------
// grid 64 (bh), block 256 (waves 2x2 over 64m x 64d)
__global__ __launch_bounds__(256) void aggm_k(const u16* __restrict__ W2, const u16* __restrict__ qkv_op,
                                              u16* __restrict__ agg_m){
  __shared__ u16 As[64*40];   // W2 [64 m][32 n], stride 40
  __shared__ u16 Bs[64*40];   // v2^T [64 d][32 n]
  int bh = blockIdx.x; int b = bh >> 3, h = bh & 7;
  int tid = threadIdx.x, lane = tid & 63, wave = tid >> 6;
  int wm = wave & 1, wn = wave >> 1;
  int mrow = lane & 15, quad = lane >> 4;
  floatx4 acc[2][2];
  acc[0][0]=(floatx4){0,0,0,0}; acc[0][1]=(floatx4){0,0,0,0};
  acc[1][0]=(floatx4){0,0,0,0}; acc[1][1]=(floatx4){0,0,0,0};
  const int arow = tid >> 2, acol = (tid & 3) * 8;
  const int nrow = tid >> 3, dcol = (tid & 7) * 8;
  for (int ks = 0; ks < 32; ++ks){
    int nn0 = ks*32;
    *(shortx8*)(As + arow*40 + acol) =
        *(const shortx8*)(W2 + ((size_t)(b*64 + arow)*8 + h)*1024 + nn0 + acol);
    shortx8 vv = *(const shortx8*)(qkv_op + (size_t)(b*1024 + nn0 + nrow)*CQ + 2048 + h*64 + dcol);
    #pragma unroll
    for (int e=0;e<8;++e) Bs[(dcol+e)*40 + nrow] = (u16)vv[e];
    __syncthreads();
    shortx8 af[2], bf[2];
    #pragma unroll
    for (int mt=0;mt<2;++mt) af[mt] = *(const shortx8*)(As + (wm*32 + mt*16 + mrow)*40 + quad*8);
    #pragma unroll
    for (int nt=0;nt<2;++nt) bf[nt] = *(const shortx8*)(Bs + (wn*32 + nt*16 + mrow)*40 + quad*8);
    #pragma unroll
    for (int mt=0;mt<2;++mt)
      #pragma unroll
      for (int nt=0;nt<2;++nt)
        acc[mt][nt] = __builtin_amdgcn_mfma_f32_16x16x32_bf16(af[mt], bf[nt], acc[mt][nt], 0, 0, 0);
    __syncthreads();
  }
  #pragma unroll
  for (int mt=0;mt<2;++mt){
    #pragma unroll
    for (int nt=0;nt<2;++nt){
      int dd = wn*32 + nt*16 + mrow;
      #pragma unroll
      for (int r2=0;r2<4;++r2){
        int m = wm*32 + mt*16 + quad*4 + r2;
        agg_m[(size_t)(b*64 + m)*512 + h*64 + dd] = f2bf(geluf(acc[mt][nt][r2]));
      }
    }
  }
}

// ---------------- final emit (f32 out, vectorized) + means ----------------
__global__ __launch_bounds__(256) void emit_k(const float* __restrict__ x_op, const float* __restrict__ x_m,
                                              float* __restrict__ out){
  const int T1 = NOPS*128, T2 = T1 + NMS*128;
  const floatx4* a4 = (const floatx4*)x_op;
  const floatx4* b4 = (const floatx4*)x_m;
  floatx4* o4 = (floatx4*)out;
  for (int i = blockIdx.x*blockDim.x + threadIdx.x; i < T2; i += gridDim.x*blockDim.x){
    o4[i] = (i < T1) ? a4[i] : b4[i - T1];
  }
}
__global__ __launch_bounds__(512) void meanj_part_k(const float* __restrict__ x_op, float* scratch){
  int b = blockIdx.x, chunk = blockIdx.y, f = threadIdx.x;
  float s = 0.f;
  for (int r=0;r<128;++r){
    int row = b*1024 + chunk*128 + r;
    s += x_op[(size_t)row*512 + f];
  }
  atomicAdd(&scratch[b*512 + f], s);
}
__global__ void meanj_fin_k(const float* scratch, float* out){
  int i = blockIdx.x*blockDim.x + threadIdx.x;
  if (i < 4096) out[4456448 + i] = scratch[i] * (1.f/1024.f);
}
__global__ __launch_bounds__(512) void meanm_k(const float* __restrict__ x_m, float* out){
  int b = blockIdx.x, f = threadIdx.x;
  float s = 0.f;
  for (int r=0;r<64;++r) s += x_m[(size_t)(b*64+r)*512 + f];
  out[4460544 + b*512 + f] = s * (1.f/64.f);
}

extern "C" void kernel_launch(void* const* d_in, const int* in_sizes, int n_in,
                              void* d_out, int out_size, void* d_ws, size_t ws_size,
                              hipStream_t stream){
  const float* op_x      = (const float*)d_in[0];
  const float* machine_x = (const float*)d_in[1];
  const float* W_emb_op  = (const float*)d_in[2];
  const float* b_emb_op  = (const float*)d_in[3];
  const float* W_emb_m   = (const float*)d_in[4];
  const float* b_emb_m   = (const float*)d_in[5];
  const float* opn_w     = (const float*)d_in[6];
  const float* opn_b     = (const float*)d_in[7];
  const float* mn_w      = (const float*)d_in[8];
  const float* mn_b      = (const float*)d_in[9];
  const float* Wk        = (const float*)d_in[10];
  const float* bk        = (const float*)d_in[11];
  const float* Wq        = (const float*)d_in[12];
  const float* bq        = (const float*)d_in[13];
  const float* Wv        = (const float*)d_in[14];
  const float* bv        = (const float*)d_in[15];
  const float* A_rel     = (const float*)d_in[16];
  const float* M_rel     = (const float*)d_in[17];
  const float* p_rel     = (const float*)d_in[18];
  const float* W_out     = (const float*)d_in[19];
  const float* b_out     = (const float*)d_in[20];
  const float* skip      = (const float*)d_in[21];
  const float* ln_w      = (const float*)d_in[22];
  const float* ln_b      = (const float*)d_in[23];
  const int* s0          = (const int*)d_in[24];
  const int* s1          = (const int*)d_in[25];
  float* out = (float*)d_out;

  char* ws = (char*)d_ws;
  size_t off = 0;
  auto alloc = [&](size_t bytes)->void*{
    void* p = ws + off;
    off = (off + bytes + 255) & ~(size_t)255;
    return p;
  };
  float* accb      = (float*)alloc(64*4);
  float* scratch   = (float*)alloc(4096*4);
  float* pstat     = (float*)alloc(4096*4);
  float* Ct        = (float*)alloc((size_t)NMS*1024*4);       // 2MB edge multiplicity
  float* S2f       = (float*)alloc((size_t)NMS*8*1024*4);     // 16MB machine scores
  u16*   W2        = (u16*)  alloc((size_t)NMS*8*1024*2);     // 8MB softmax weights
  float* x_op      = (float*)alloc((size_t)NOPS*512*4);
  u16*   x_op_bf   = (u16*)  alloc((size_t)NOPS*512*2);
  float* x_m       = (float*)alloc((size_t)NMS*512*4);
  u16*   x_m_bf    = (u16*)  alloc((size_t)NMS*512*2);
  u16*   qkv_op    = (u16*)  alloc((size_t)NOPS*CQ*2);        // 40MB; o_op (16MB f32) aliases it
  u16*   qkv_m     = (u16*)  alloc((size_t)NMS*CM*2);
  u16*   agg_op    = (u16*)  alloc((size_t)NOPS*512*2);
  u16*   agg_m     = (u16*)  alloc((size_t)NMS*512*2);
  u16*   Wc_op_t   = (u16*)  alloc((size_t)3*CQ*512*2);
  float* bias_op   = (float*)alloc((size_t)3*CQ*4);
  u16*   Wc_m_t    = (u16*)  alloc((size_t)3*CM*512*2);
  float* bias_m    = (float*)alloc((size_t)3*CM*4);
  u16*   Wout_t    = (u16*)  alloc((size_t)6*262144*2);
  float* o_op      = (float*)qkv_op;
  float* o_m       = (float*)qkv_m;
  float* pstat_m   = pstat + 2048;

  const int TOP = NOPS*512;
  const int TM  = NMS*512;
  const int T4OP = TOP/4, T4M = TM/4;
  const int GB_OP = 1024, GB_M = 128;

  // setup: zero, counts, weight prep (all 3 layers)
  zero_ws_k<<<512,256,0,stream>>>(Ct, accb, scratch);
  cnt_k<<<256,256,0,stream>>>(s1, Ct);
  twout_k<<<dim3(6,8,8),256,0,stream>>>(W_out, Wout_t);
  tq_k<<<dim3(6,8,8),256,0,stream>>>(Wq, Wc_op_t, Wc_m_t);
  qb_k<<<12,256,0,stream>>>(bq, bias_op, bias_m);
  combine2_k<<<dim3(144,4),256,0,stream>>>(Wk, bk, Wv, bv, A_rel, M_rel, Wc_op_t, bias_op, Wc_m_t, bias_m);

  // embeddings + graph LN
  embed_k<<<GB_OP,256,0,stream>>>(op_x, W_emb_op, b_emb_op, x_op, TOP, 16, pstat);
  embed_k<<<GB_M,256,0,stream>>>(machine_x, W_emb_m, b_emb_m, x_m, TM, 8, pstat_m);
  reduce_stats_k<<<1,256,0,stream>>>(pstat,   GB_OP, 1.f/TOP, accb + 0);
  reduce_stats_k<<<1,256,0,stream>>>(pstat_m, GB_M,  1.f/TM,  accb + 2);
  ln_apply_k<<<1024,256,0,stream>>>(x_op, x_op, x_op_bf, opn_w, opn_b, accb + 0, T4OP);
  ln_apply_k<<<128,256,0,stream>>>(x_m, x_m, x_m_bf, mn_w, mn_b, accb + 2, T4M);

  for (int l=0; l<3; ++l){
    gemm_bt<<<dim3(CQ/128, NOPS/128),256,0,stream>>>(x_op_bf, Wc_op_t + (size_t)l*CQ*512, bias_op + l*CQ, qkv_op, NOPS, CQ, 512, 1);
    gemm_bt<<<dim3(CM/128, NMS/128),256,0,stream>>>(x_m_bf, Wc_m_t + (size_t)l*CM*512, bias_m + l*CM, qkv_m, NMS, CM, 512, 1);
    attn_op_k<<<NOPS,512,0,stream>>>(qkv_op, qkv_m, s0, s1, p_rel + l*24, agg_op);
    qk2_k<<<dim3(8,64),256,0,stream>>>(qkv_op, qkv_m, p_rel + l*24, S2f);
    msoft_k<<<NMS,512,0,stream>>>(S2f, Ct, W2);
    aggm_k<<<64,256,0,stream>>>(W2, qkv_op, agg_m);
    gemm_bt<<<dim3(512/128, NOPS/128),256,0,stream>>>(agg_op, Wout_t + (size_t)(l*2+0)*262144, nullptr, o_op, NOPS, 512, 512, 0);
    gate_res_k<<<GB_OP,256,0,stream>>>(o_op, x_op, b_out + (size_t)(l*2+0)*512, skip + l*2+0, pstat, T4OP);
    gemm_bt<<<dim3(512/128, NMS/128),256,0,stream>>>(agg_m, Wout_t + (size_t)(l*2+1)*262144, nullptr, o_m, NMS, 512, 512, 0);
    gate_res_k<<<GB_M,256,0,stream>>>(o_m, x_m, b_out + (size_t)(l*2+1)*512, skip + l*2+1, pstat_m, T4M);
    reduce_stats_k<<<1,256,0,stream>>>(pstat,   GB_OP, 1.f/TOP, accb + 2*(2+2*l));
    reduce_stats_k<<<1,256,0,stream>>>(pstat_m, GB_M,  1.f/TM,  accb + 2*(3+2*l));
    ln_apply_k<<<1024,256,0,stream>>>(o_op, x_op, x_op_bf, ln_w + l*512, ln_b + l*512, accb + 2*(2+2*l), T4OP);
    ln_apply_k<<<128,256,0,stream>>>(o_m, x_m, x_m_bf, ln_w + l*512, ln_b + l*512, accb + 2*(3+2*l), T4M);
  }

  emit_k<<<2048,256,0,stream>>>(x_op, x_m, out);
  meanj_part_k<<<dim3(8,8),512,0,stream>>>(x_op, scratch);
  meanj_fin_k<<<16,256,0,stream>>>(scratch, out);
  meanm_k<<<8,512,0,stream>>>(x_m, out);
}

// Round 9
// 837.268 us; speedup vs baseline: 2.8647x; 1.0221x over previous
//
#include <hip/hip_runtime.h>

typedef unsigned short u16;
typedef __attribute__((ext_vector_type(4))) float floatx4;
typedef __attribute__((ext_vector_type(8))) short shortx8;
typedef __attribute__((ext_vector_type(4))) short shortx4;

#define NOPS 8192
#define NMS  512
#define CQ   2560   // op qkv cols: q | k0 | v0 | k2 | v2
#define CM   1536   // machine qkv cols: q | k1 | v1
#define NE2  65536

__device__ __forceinline__ float bf2f(u16 u){ return __uint_as_float(((unsigned)u)<<16); }
__device__ __forceinline__ u16 f2bf(float f){
  unsigned u = __float_as_uint(f);
  u += 0x7FFFu + ((u>>16)&1u);
  return (u16)(u>>16);
}
__device__ __forceinline__ float wred(float v){
  #pragma unroll
  for (int o=32;o;o>>=1) v += __shfl_xor(v,o,64);
  return v;
}
__device__ __forceinline__ float wredmax(float v){
  #pragma unroll
  for (int o=32;o;o>>=1) v = fmaxf(v, __shfl_xor(v,o,64));
  return v;
}
__device__ __forceinline__ float geluf(float x){
  return 0.5f*x*(1.f+erff(x*0.70710678118654752f));
}
__device__ __forceinline__ void block_stat_out(float s, float s2, float* pstat){
  __shared__ float sb[8];
  s = wred(s); s2 = wred(s2);
  int wv = threadIdx.x >> 6;
  if ((threadIdx.x & 63) == 0){ sb[wv*2] = s; sb[wv*2+1] = s2; }
  __syncthreads();
  if (threadIdx.x == 0){
    float a = 0.f, b = 0.f;
    int nw = blockDim.x >> 6;
    for (int i=0;i<nw;++i){ a += sb[i*2]; b += sb[i*2+1]; }
    pstat[blockIdx.x*2]   = a;
    pstat[blockIdx.x*2+1] = b;
  }
}

// ---------------- zero ws: Ct (512x1024) + Cn (8192x64) + scratch + accb ----------------
__global__ __launch_bounds__(256) void zero_ws_k(float* Ct, float* Cn, float* acc, float* scratch){
  const int T1 = 524288, T2 = 1048576, T3 = 1052672, T4 = 1052736;
  for (int i = blockIdx.x*blockDim.x + threadIdx.x; i < T4; i += gridDim.x*blockDim.x){
    if (i < T1) Ct[i] = 0.f;
    else if (i < T2) Cn[i - T1] = 0.f;
    else if (i < T3) scratch[i - T2] = 0.f;
    else acc[i - T3] = 0.f;
  }
}
// ---------------- edge multiplicity: Ct[mach][op_local], Cn[op][mach_local] ----------------
__global__ void cnt_k(const int* __restrict__ s1, float* Ct, float* Cn){
  int e = blockIdx.x*blockDim.x + threadIdx.x;
  if (e < NE2){
    int m = s1[e], n = e >> 3;
    atomicAdd(&Ct[(size_t)m*1024 + (n & 1023)], 1.f);
    atomicAdd(&Cn[(size_t)n*64 + (m & 63)], 1.f);
  }
}

// ---------------- W_out: f32 [6][K][N] -> bf16 transposed [6][N][K] ----------------
__global__ __launch_bounds__(256) void twout_k(const float* __restrict__ src, u16* __restrict__ dst){
  __shared__ u16 t[64][65];
  int l = blockIdx.x, kb = blockIdx.y*64, nb = blockIdx.z*64;
  const float* s = src + (size_t)l*262144;
  u16* d = dst + (size_t)l*262144;
  int tx = threadIdx.x & 63, ty4 = threadIdx.x >> 6;
  #pragma unroll 4
  for (int p=0;p<16;++p){
    int k = ty4 + p*4;
    t[k][tx] = f2bf(s[(size_t)(kb+k)*512 + nb + tx]);
  }
  __syncthreads();
  #pragma unroll 4
  for (int p=0;p<16;++p){
    int n = ty4 + p*4;
    d[(size_t)(nb+n)*512 + kb + tx] = t[tx][n];
  }
}

// ---------------- Wq transpose into Wc rows 0..511 ----------------
__global__ __launch_bounds__(256) void tq_k(const float* __restrict__ Wq,
                                            u16* __restrict__ Wc_op_t, u16* __restrict__ Wc_m_t){
  __shared__ u16 tl[64][65];
  int blk = blockIdx.x;
  int l = blk >> 1, side = blk & 1;
  const float* s = Wq + (size_t)blk*262144;
  u16* d = side ? (Wc_m_t + (size_t)l*CM*512) : (Wc_op_t + (size_t)l*CQ*512);
  int kb = blockIdx.y*64, nb = blockIdx.z*64;
  int tx = threadIdx.x & 63, ty4 = threadIdx.x >> 6;
  #pragma unroll 4
  for (int p=0;p<16;++p){
    int k = ty4 + p*4;
    tl[k][tx] = f2bf(s[(size_t)(kb+k)*512 + nb + tx]);
  }
  __syncthreads();
  #pragma unroll 4
  for (int p=0;p<16;++p){
    int n = ty4 + p*4;
    d[(size_t)(nb+n)*512 + kb + tx] = tl[tx][n];
  }
}

// ---------------- q biases ----------------
__global__ void qb_k(const float* __restrict__ bq, float* bias_op, float* bias_m){
  int i = blockIdx.x*blockDim.x + threadIdx.x;
  if (i >= 3072) return;
  int l = i >> 10, side = (i >> 9) & 1, f = i & 511;
  float v = bq[(l*2+side)*512 + f];
  if (side==0) bias_op[l*CQ + f] = v; else bias_m[l*CM + f] = v;
}

// ---------------- relation-combined weights: grid (144, 16), 32 cc per block ----------------
__global__ __launch_bounds__(256) void combine2_k(const float* __restrict__ Wk, const float* __restrict__ bk,
                                                  const float* __restrict__ Wv, const float* __restrict__ bv,
                                                  const float* __restrict__ Ar, const float* __restrict__ Mr,
                                                  u16* __restrict__ Wc_op_t, float* __restrict__ bias_op,
                                                  u16* __restrict__ Wc_m_t, float* __restrict__ bias_m){
  __shared__ float RelS[4096];
  __shared__ u16 tile[64*34];
  int gx = blockIdx.x;
  int l = gx/48; int rem = gx - l*48; int s = rem >> 3; int h = rem & 7;
  int side = (s < 4) ? 0 : 1;
  int r = (s < 4) ? (s+1) : (s-3);
  int useK = side==0 ? (s==0 || s==2) : (s==4);
  int rel  = side==0 ? ((s<2)?0:2) : 1;
  size_t woff = (size_t)(l*2+side)*262144;
  size_t boff = (size_t)(l*2+side)*512;
  const float* W   = (useK ? Wk : Wv) + woff;
  const float* bb  = (useK ? bk : bv) + boff;
  const float* Rel = (useK ? Ar : Mr) + ((size_t)(l*3+rel)*8 + h)*4096;
  int h64 = h*64;
  u16* Wt; float* bias;
  if (side==0){ Wt = Wc_op_t + (size_t)l*CQ*512; bias = bias_op + l*CQ; }
  else        { Wt = Wc_m_t  + (size_t)l*CM*512; bias = bias_m  + l*CM; }
  int rbase = r*512 + h64;
  int t = threadIdx.x, lane = t & 63, wave = t >> 6;
  #pragma unroll
  for (int i=0;i<4;++i) ((floatx4*)RelS)[t + i*256] = ((const floatx4*)Rel)[t + i*256];
  __syncthreads();
  int cc0 = blockIdx.y * 32;
  #pragma unroll
  for (int p=0;p<4;++p){
    int ca = cc0 + wave*8 + p*2;
    const float* wa = W + (size_t)ca*512 + h64;
    const float* wb = wa + 512;
    float acc_a = 0.f, acc_b = 0.f;
    #pragma unroll
    for (int dd=0; dd<64; dd+=4){
      floatx4 va = *(const floatx4*)(wa+dd);
      floatx4 vb = *(const floatx4*)(wb+dd);
      #pragma unroll
      for (int e=0;e<4;++e){
        float rv = RelS[(dd+e)*64 + lane];
        acc_a += va[e]*rv;
        acc_b += vb[e]*rv;
      }
    }
    tile[lane*34 + wave*8 + p*2]     = f2bf(acc_a);
    tile[lane*34 + wave*8 + p*2 + 1] = f2bf(acc_b);
  }
  __syncthreads();
  #pragma unroll
  for (int j=0;j<8;++j){
    int e2 = (t>>5) + j*8;
    Wt[(size_t)(rbase+e2)*512 + cc0 + (t&31)] = tile[e2*34 + (t&31)];
  }
  if (blockIdx.y == 0 && wave == 0){
    float acc = 0.f;
    #pragma unroll
    for (int dd=0; dd<64; dd+=4){
      floatx4 vb = *(const floatx4*)(bb + h64 + dd);
      #pragma unroll
      for (int e=0;e<4;++e) acc += vb[e]*RelS[(dd+e)*64 + lane];
    }
    bias[rbase + lane] = acc;
  }
}

// ---------------- embedding GEMM (tiny K) + per-block LN partials ----------------
__global__ __launch_bounds__(256) void embed_k(const float* __restrict__ X, const float* __restrict__ W,
                                               const float* __restrict__ bias, float* __restrict__ Y,
                                               int total, int K, float* pstat){
  float s = 0.f, s2 = 0.f;
  for (int idx = blockIdx.x*blockDim.x + threadIdx.x; idx < total; idx += gridDim.x*blockDim.x){
    int n = idx >> 9, f = idx & 511;
    float v = bias[f];
    for (int c=0;c<K;++c) v += X[n*K+c] * W[c*512+f];
    Y[idx] = v;
    s += v; s2 += v*v;
  }
  block_stat_out(s, s2, pstat);
}

// ---------------- stats finalize ----------------
__global__ __launch_bounds__(256) void reduce_stats_k(const float* __restrict__ pstat, int nblk,
                                                      float inv_n, float* acc){
  float s = 0.f, s2 = 0.f;
  for (int i = threadIdx.x; i < nblk; i += 256){ s += pstat[2*i]; s2 += pstat[2*i+1]; }
  __shared__ float sb[8];
  s = wred(s); s2 = wred(s2);
  int wv = threadIdx.x >> 6;
  if ((threadIdx.x & 63) == 0){ sb[wv*2] = s; sb[wv*2+1] = s2; }
  __syncthreads();
  if (threadIdx.x == 0){
    float a = 0.f, b = 0.f;
    for (int i=0;i<4;++i){ a += sb[i*2]; b += sb[i*2+1]; }
    float mean = a * inv_n;
    float var  = fmaxf(b * inv_n - mean*mean, 0.f);
    acc[0] = mean;
    acc[1] = 1.f/(sqrtf(var) + 1e-5f);
  }
}

// ---------------- graph-LN apply: dual write f32 + bf16 ----------------
__global__ __launch_bounds__(256) void ln_apply_k(const float* __restrict__ src, float* __restrict__ dst,
                                                  u16* __restrict__ dst_bf,
                                                  const float* __restrict__ w, const float* __restrict__ b,
                                                  const float* acc, int total4){
  float mean = acc[0], rinv = acc[1];
  const floatx4* s4 = (const floatx4*)src;
  floatx4* d4 = (floatx4*)dst;
  shortx4* db4 = (shortx4*)dst_bf;
  const floatx4* w4 = (const floatx4*)w;
  const floatx4* b4 = (const floatx4*)b;
  for (int i = blockIdx.x*blockDim.x + threadIdx.x; i < total4; i += gridDim.x*blockDim.x){
    int f = i & 127;
    floatx4 v = s4[i], wv = w4[f], bv = b4[f];
    shortx4 sv;
    #pragma unroll
    for (int e=0;e<4;++e){ v[e] = (v[e]-mean)*rinv*wv[e] + bv[e]; sv[e] = (short)f2bf(v[e]); }
    d4[i] = v;
    db4[i] = sv;
  }
}

// ---------------- gated residual + per-block LN partials ----------------
__global__ __launch_bounds__(256) void gate_res_k(float* __restrict__ y, const float* __restrict__ x,
                                                  const float* __restrict__ bout, const float* __restrict__ skipel,
                                                  float* pstat, int total4){
  float g = 1.f/(1.f+expf(-(*skipel)));
  floatx4* y4 = (floatx4*)y;
  const floatx4* x4 = (const floatx4*)x;
  const floatx4* b4 = (const floatx4*)bout;
  float s = 0.f, s2 = 0.f;
  for (int i = blockIdx.x*blockDim.x + threadIdx.x; i < total4; i += gridDim.x*blockDim.x){
    floatx4 yv = y4[i], xv = x4[i], bv = b4[i & 127];
    #pragma unroll
    for (int e=0;e<4;++e){
      float o = g*(yv[e]+bv[e]) + (2.f-g)*xv[e];
      yv[e] = o;
      s += o; s2 += o*o;
    }
    y4[i] = yv;
  }
  block_stat_out(s, s2, pstat);
}

// ---------------- m97-style bf16 MFMA GEMM ----------------
__global__ __launch_bounds__(256) void gemm_bt(const u16* __restrict__ A, const u16* __restrict__ Bt,
                                               const float* __restrict__ bias, void* __restrict__ Cp,
                                               int M, int N, int K, int out_bf16){
  __shared__ u16 As[128*32];
  __shared__ u16 Bs[128*32];
  const int tid = threadIdx.x;
  const int lane = tid & 63, wave = tid >> 6;
  const int bm = blockIdx.y * 128, bn = blockIdx.x * 128;
  const int wm = wave & 1, wn = wave >> 1;
  const int mrow = lane & 15, quad = lane >> 4;
  const u16* Ab = A + (size_t)bm*K;
  const u16* Bb = Bt + (size_t)bn*K;
  floatx4 acc[4][4];
  #pragma unroll
  for (int a=0;a<4;++a)
    #pragma unroll
    for (int b=0;b<4;++b) acc[a][b] = (floatx4){0.f,0.f,0.f,0.f};
  const int r0 = tid >> 2, c0 = (tid & 3) * 8;
  const int r1 = (tid+256) >> 2, c1 = ((tid+256) & 3) * 8;
  const int lds0 = wave*512;
  const int lds1 = wave*512 + 2048;
  for (int k0 = 0; k0 < K; k0 += 32){
    __builtin_amdgcn_global_load_lds((const __attribute__((address_space(1))) void*)(Ab + (size_t)r0*K + k0 + c0),
                                     (__attribute__((address_space(3))) void*)(As + lds0), 16, 0, 0);
    __builtin_amdgcn_global_load_lds((const __attribute__((address_space(1))) void*)(Ab + (size_t)r1*K + k0 + c1),
                                     (__attribute__((address_space(3))) void*)(As + lds1), 16, 0, 0);
    __builtin_amdgcn_global_load_lds((const __attribute__((address_space(1))) void*)(Bb + (size_t)r0*K + k0 + c0),
                                     (__attribute__((address_space(3))) void*)(Bs + lds0), 16, 0, 0);
    __builtin_amdgcn_global_load_lds((const __attribute__((address_space(1))) void*)(Bb + (size_t)r1*K + k0 + c1),
                                     (__attribute__((address_space(3))) void*)(Bs + lds1), 16, 0, 0);
    __syncthreads();
    shortx8 af[4], bf[4];
    #pragma unroll
    for (int mt=0;mt<4;++mt) af[mt] = *(const shortx8*)(As + (wm*64 + mt*16 + mrow)*32 + quad*8);
    #pragma unroll
    for (int nt=0;nt<4;++nt) bf[nt] = *(const shortx8*)(Bs + (wn*64 + nt*16 + mrow)*32 + quad*8);
    #pragma unroll
    for (int mt=0;mt<4;++mt)
      #pragma unroll
      for (int nt=0;nt<4;++nt)
        acc[mt][nt] = __builtin_amdgcn_mfma_f32_16x16x32_bf16(af[mt], bf[nt], acc[mt][nt], 0, 0, 0);
    __syncthreads();
  }
  #pragma unroll
  for (int mt=0;mt<4;++mt){
    #pragma unroll
    for (int nt=0;nt<4;++nt){
      int col = bn + wn*64 + nt*16 + mrow;
      float bval = bias ? bias[col] : 0.f;
      #pragma unroll
      for (int r2=0;r2<4;++r2){
        int row = bm + wm*64 + mt*16 + quad*4 + r2;
        float v = acc[mt][nt][r2] + bval;
        if (out_bf16) ((u16*)Cp)[(size_t)row*N + col] = f2bf(v);
        else          ((float*)Cp)[(size_t)row*N + col] = v;
      }
    }
  }
}

// ---------------- op scores: S1[n,m] = q_op(128n x K64) x k1^T, per (b,h) ----------------
// grid (8 n-tiles, 64 bh), block 256, waves 2x2 over 128n x 64m
__global__ __launch_bounds__(256) void qk1_k(const u16* __restrict__ qkv_op, const u16* __restrict__ qkv_m,
                                             const float* __restrict__ prel, float* __restrict__ S1f){
  __shared__ u16 As[128*72];  // q tile
  __shared__ u16 Bs[64*72];   // k1 tile
  int bh = blockIdx.y; int b = bh >> 3, h = bh & 7;
  int n0 = blockIdx.x * 128;
  int tid = threadIdx.x, lane = tid & 63, wave = tid >> 6;
  int wm = wave & 1, wn = wave >> 1;
  int mrow = lane & 15, quad = lane >> 4;
  float p1 = prel[8 + h] * 0.125f;
  {
    int row = tid >> 1, col = (tid & 1) * 32;
    const u16* src = qkv_op + (size_t)(b*1024 + n0 + row)*CQ + h*64 + col;
    #pragma unroll
    for (int e=0;e<4;++e) *(shortx8*)(As + row*72 + col + e*8) = *(const shortx8*)(src + e*8);
  }
  {
    int row = tid >> 2, col = (tid & 3) * 16;
    const u16* src = qkv_m + (size_t)(b*64 + row)*CM + 512 + h*64 + col;
    *(shortx8*)(Bs + row*72 + col)     = *(const shortx8*)(src);
    *(shortx8*)(Bs + row*72 + col + 8) = *(const shortx8*)(src + 8);
  }
  __syncthreads();
  floatx4 acc[4][2];
  #pragma unroll
  for (int a=0;a<4;++a){ acc[a][0] = (floatx4){0,0,0,0}; acc[a][1] = (floatx4){0,0,0,0}; }
  #pragma unroll
  for (int ks=0; ks<2; ++ks){
    shortx8 af[4], bf[2];
    #pragma unroll
    for (int mt=0;mt<4;++mt) af[mt] = *(const shortx8*)(As + (wm*64 + mt*16 + mrow)*72 + ks*32 + quad*8);
    #pragma unroll
    for (int nt=0;nt<2;++nt) bf[nt] = *(const shortx8*)(Bs + (wn*32 + nt*16 + mrow)*72 + ks*32 + quad*8);
    #pragma unroll
    for (int mt=0;mt<4;++mt)
      #pragma unroll
      for (int nt=0;nt<2;++nt)
        acc[mt][nt] = __builtin_amdgcn_mfma_f32_16x16x32_bf16(af[mt], bf[nt], acc[mt][nt], 0, 0, 0);
  }
  #pragma unroll
  for (int mt=0;mt<4;++mt){
    #pragma unroll
    for (int nt=0;nt<2;++nt){
      int m = wn*32 + nt*16 + mrow;
      #pragma unroll
      for (int r2=0;r2<4;++r2){
        int n = n0 + wm*64 + mt*16 + quad*4 + r2;
        S1f[((size_t)(b*1024 + n)*8 + h)*64 + m] = acc[mt][nt][r2] * p1;
      }
    }
  }
}

// ---------------- op softmax: per (n,h) over 64 machines (count-weighted) + precedes edge ----------------
// thread per (n,h); W1 holds UNNORMALIZED c*exp(s-mx); wpre/linv for epilogue fold.
__global__ __launch_bounds__(256) void msoft1_k(const float* __restrict__ S1f, const float* __restrict__ Cn,
                                                const u16* __restrict__ qkv_op, const float* __restrict__ prel,
                                                u16* __restrict__ W1, float* __restrict__ wpre,
                                                float* __restrict__ linv){
  int i = blockIdx.x*256 + threadIdx.x;   // 65536
  int n = i >> 3, h = i & 7;
  int nl = n & 1023;
  float sp = -1e30f;
  if (nl > 0){
    float p0 = prel[h] * 0.125f;
    const u16* qp = qkv_op + (size_t)n*CQ + h*64;
    const u16* kp = qkv_op + (size_t)(n-1)*CQ + 512 + h*64;
    float acc = 0.f;
    #pragma unroll
    for (int j=0;j<8;++j){
      shortx8 qa = *(const shortx8*)(qp + j*8);
      shortx8 ka = *(const shortx8*)(kp + j*8);
      #pragma unroll
      for (int e=0;e<8;++e) acc += bf2f((u16)qa[e])*bf2f((u16)ka[e]);
    }
    sp = acc * p0;
  }
  const floatx4* s4 = (const floatx4*)(S1f + (size_t)i*64);
  const floatx4* c4 = (const floatx4*)(Cn + (size_t)n*64);
  float mx = sp;
  #pragma unroll
  for (int it=0; it<16; ++it){
    floatx4 sv = s4[it], cv = c4[it];
    #pragma unroll
    for (int e=0;e<4;++e) if (cv[e] > 0.f) mx = fmaxf(mx, sv[e]);
  }
  float L = 0.f;
  shortx4* w4 = (shortx4*)(W1 + (size_t)i*64);
  #pragma unroll
  for (int it=0; it<16; ++it){
    floatx4 sv = s4[it], cv = c4[it];
    shortx4 pv;
    #pragma unroll
    for (int e=0;e<4;++e){
      float w = (cv[e] > 0.f) ? cv[e]*expf(sv[e]-mx) : 0.f;
      L += w;
      pv[e] = (short)f2bf(w);
    }
    w4[it] = pv;
  }
  float ep = (nl > 0) ? expf(sp - mx) : 0.f;
  L += ep;
  wpre[i] = ep;
  linv[i] = 1.f/(L + 1e-16f);
}

// ---------------- op agg: (W1[128n x 64m] x v1[64m x 64d] + wpre*v0[n-1]) * linv -> gelu bf16 ----------------
// grid (8 n-tiles, 64 bh), block 256, waves 2x2 over 128n x 64d
__global__ __launch_bounds__(256) void aggop_k(const u16* __restrict__ W1, const u16* __restrict__ qkv_op,
                                               const u16* __restrict__ qkv_m, const float* __restrict__ wpre,
                                               const float* __restrict__ linv, u16* __restrict__ agg_op){
  __shared__ u16 As[128*72];  // W1 tile [n][m]
  __shared__ u16 Bs[64*72];   // v1^T [d][m]
  int bh = blockIdx.y; int b = bh >> 3, h = bh & 7;
  int n0 = blockIdx.x * 128;
  int tid = threadIdx.x, lane = tid & 63, wave = tid >> 6;
  int wm = wave & 1, wn = wave >> 1;
  int mrow = lane & 15, quad = lane >> 4;
  {
    int row = tid >> 1, col = (tid & 1) * 32;
    const u16* src = W1 + ((size_t)(b*1024 + n0 + row)*8 + h)*64 + col;
    #pragma unroll
    for (int e=0;e<4;++e) *(shortx8*)(As + row*72 + col + e*8) = *(const shortx8*)(src + e*8);
  }
  {
    int m = tid >> 2, dcol = (tid & 3) * 16;
    const u16* src = qkv_m + (size_t)(b*64 + m)*CM + 1024 + h*64 + dcol;
    shortx8 v0 = *(const shortx8*)(src);
    shortx8 v1 = *(const shortx8*)(src + 8);
    #pragma unroll
    for (int e=0;e<8;++e){ Bs[(dcol+e)*72 + m] = (u16)v0[e]; Bs[(dcol+8+e)*72 + m] = (u16)v1[e]; }
  }
  __syncthreads();
  floatx4 acc[4][2];
  #pragma unroll
  for (int a=0;a<4;++a){ acc[a][0] = (floatx4){0,0,0,0}; acc[a][1] = (floatx4){0,0,0,0}; }
  #pragma unroll
  for (int ks=0; ks<2; ++ks){
    shortx8 af[4], bf[2];
    #pragma unroll
    for (int mt=0;mt<4;++mt) af[mt] = *(const shortx8*)(As + (wm*64 + mt*16 + mrow)*72 + ks*32 + quad*8);
    #pragma unroll
    for (int nt=0;nt<2;++nt) bf[nt] = *(const shortx8*)(Bs + (wn*32 + nt*16 + mrow)*72 + ks*32 + quad*8);
    #pragma unroll
    for (int mt=0;mt<4;++mt)
      #pragma unroll
      for (int nt=0;nt<2;++nt)
        acc[mt][nt] = __builtin_amdgcn_mfma_f32_16x16x32_bf16(af[mt], bf[nt], acc[mt][nt], 0, 0, 0);
  }
  #pragma unroll
  for (int mt=0;mt<4;++mt){
    #pragma unroll
    for (int nt=0;nt<2;++nt){
      int d = wn*32 + nt*16 + mrow;
      #pragma unroll
      for (int r2=0;r2<4;++r2){
        int n = n0 + wm*64 + mt*16 + quad*4 + r2;
        size_t ng = (size_t)b*1024 + n;
        size_t ih = ng*8 + h;
        float v = acc[mt][nt][r2];
        if ((n & 1023) > 0) v += wpre[ih] * bf2f(qkv_op[(ng-1)*CQ + 1024 + h*64 + d]);
        v *= linv[ih];
        agg_op[ng*512 + h*64 + d] = f2bf(geluf(v));
      }
    }
  }
}

// ---------------- machine scores: S2[m,n] per (b,h) ----------------
__global__ __launch_bounds__(256) void qk2_k(const u16* __restrict__ qkv_op, const u16* __restrict__ qkv_m,
                                             const float* __restrict__ prel, float* __restrict__ S2f){
  __shared__ u16 As[64*72];
  __shared__ u16 Bs[128*72];
  int bh = blockIdx.y; int b = bh >> 3, h = bh & 7;
  int n0 = blockIdx.x * 128;
  int tid = threadIdx.x, lane = tid & 63, wave = tid >> 6;
  int mrow = lane & 15, quad = lane >> 4;
  float p2 = prel[16 + h] * 0.125f;
  {
    int row = tid >> 2, col = (tid & 3) * 16;
    const u16* src = qkv_m + (size_t)(b*64+row)*CM + h*64 + col;
    *(shortx8*)(As + row*72 + col)     = *(const shortx8*)(src);
    *(shortx8*)(As + row*72 + col + 8) = *(const shortx8*)(src + 8);
  }
  {
    int row = tid >> 1, col = (tid & 1) * 32;
    const u16* src = qkv_op + (size_t)(b*1024 + n0 + row)*CQ + 1536 + h*64 + col;
    #pragma unroll
    for (int e=0;e<4;++e)
      *(shortx8*)(Bs + row*72 + col + e*8) = *(const shortx8*)(src + e*8);
  }
  __syncthreads();
  floatx4 acc[4][2];
  #pragma unroll
  for (int a=0;a<4;++a){ acc[a][0] = (floatx4){0,0,0,0}; acc[a][1] = (floatx4){0,0,0,0}; }
  #pragma unroll
  for (int ks=0; ks<2; ++ks){
    shortx8 af[4], bf[2];
    #pragma unroll
    for (int mt=0;mt<4;++mt) af[mt] = *(const shortx8*)(As + (mt*16 + mrow)*72 + ks*32 + quad*8);
    #pragma unroll
    for (int nt=0;nt<2;++nt) bf[nt] = *(const shortx8*)(Bs + (wave*32 + nt*16 + mrow)*72 + ks*32 + quad*8);
    #pragma unroll
    for (int mt=0;mt<4;++mt)
      #pragma unroll
      for (int nt=0;nt<2;++nt)
        acc[mt][nt] = __builtin_amdgcn_mfma_f32_16x16x32_bf16(af[mt], bf[nt], acc[mt][nt], 0, 0, 0);
  }
  #pragma unroll
  for (int mt=0;mt<4;++mt){
    #pragma unroll
    for (int nt=0;nt<2;++nt){
      int n = n0 + wave*32 + nt*16 + mrow;
      #pragma unroll
      for (int r2=0;r2<4;++r2){
        int m = mt*16 + quad*4 + r2;
        S2f[((size_t)(b*64 + m)*8 + h)*1024 + n] = acc[mt][nt][r2] * p2;
      }
    }
  }
}

// ---------------- machine softmax (count-weighted) ----------------
__global__ __launch_bounds__(512) void msoft_k(const float* __restrict__ S2f, const float* __restrict__ Ct,
                                               u16* __restrict__ W2){
  int m = blockIdx.x;
  int h = threadIdx.x >> 6, d = threadIdx.x & 63;
  const float* srow = S2f + ((size_t)m*8 + h)*1024;
  const float* crow = Ct + (size_t)m*1024;
  float s[16], c[16];
  #pragma unroll
  for (int it=0; it<16; ++it){
    s[it] = srow[it*64 + d];
    c[it] = crow[it*64 + d];
  }
  float mx = -1e30f;
  #pragma unroll
  for (int it=0; it<16; ++it) if (c[it] > 0.f) mx = fmaxf(mx, s[it]);
  mx = wredmax(mx);
  float e[16], L = 0.f;
  #pragma unroll
  for (int it=0; it<16; ++it){
    e[it] = (c[it] > 0.f) ? c[it]*expf(s[it]-mx) : 0.f;
    L += e[it];
  }
  L = wred(L);
  float inv = 1.f/(L + 1e-16f);
  u16* wrow = W2 + ((size_t)m*8 + h)*1024;
  #pragma unroll
  for (int it=0; it<16; ++it) wrow[it*64 + d] = f2bf(e[it]*inv);
}

// ---------------- machine agg GEMM -> gelu bf16 ----------------
__global__ __launch_bounds__(256) void aggm_k(const u16* __restrict__ W2, const u16* __restrict__ qkv_op,
                                              u16* __restrict__ agg_m){
  __shared__ u16 As[64*40];
  __shared__ u16 Bs[64*40];
  int bh = blockIdx.x; int b = bh >> 3, h = bh & 7;
  int tid = threadIdx.x, lane = tid & 63, wave = tid >> 6;
  int wm = wave & 1, wn = wave >> 1;
  int mrow = lane & 15, quad = lane >> 4;
  floatx4 acc[2][2];
  acc[0][0]=(floatx4){0,0,0,0}; acc[0][1]=(floatx4){0,0,0,0};
  acc[1][0]=(floatx4){0,0,0,0}; acc[1][1]=(floatx4){0,0,0,0};
  const int arow = tid >> 2, acol = (tid & 3) * 8;
  const int nrow = tid >> 3, dcol = (tid & 7) * 8;
  for (int ks = 0; ks < 32; ++ks){
    int nn0 = ks*32;
    *(shortx8*)(As + arow*40 + acol) =
        *(const shortx8*)(W2 + ((size_t)(b*64 + arow)*8 + h)*1024 + nn0 + acol);
    shortx8 vv = *(const shortx8*)(qkv_op + (size_t)(b*1024 + nn0 + nrow)*CQ + 2048 + h*64 + dcol);
    #pragma unroll
    for (int e=0;e<8;++e) Bs[(dcol+e)*40 + nrow] = (u16)vv[e];
    __syncthreads();
    shortx8 af[2], bf[2];
    #pragma unroll
    for (int mt=0;mt<2;++mt) af[mt] = *(const shortx8*)(As + (wm*32 + mt*16 + mrow)*40 + quad*8);
    #pragma unroll
    for (int nt=0;nt<2;++nt) bf[nt] = *(const shortx8*)(Bs + (wn*32 + nt*16 + mrow)*40 + quad*8);
    #pragma unroll
    for (int mt=0;mt<2;++mt)
      #pragma unroll
      for (int nt=0;nt<2;++nt)
        acc[mt][nt] = __builtin_amdgcn_mfma_f32_16x16x32_bf16(af[mt], bf[nt], acc[mt][nt], 0, 0, 0);
    __syncthreads();
  }
  #pragma unroll
  for (int mt=0;mt<2;++mt){
    #pragma unroll
    for (int nt=0;nt<2;++nt){
      int dd = wn*32 + nt*16 + mrow;
      #pragma unroll
      for (int r2=0;r2<4;++r2){
        int m = wm*32 + mt*16 + quad*4 + r2;
        agg_m[(size_t)(b*64 + m)*512 + h*64 + dd] = f2bf(geluf(acc[mt][nt][r2]));
      }
    }
  }
}

// ---------------- final emit + means ----------------
__global__ __launch_bounds__(256) void emit_k(const float* __restrict__ x_op, const float* __restrict__ x_m,
                                              float* __restrict__ out){
  const int T1 = NOPS*128, T2 = T1 + NMS*128;
  const floatx4* a4 = (const floatx4*)x_op;
  const floatx4* b4 = (const floatx4*)x_m;
  floatx4* o4 = (floatx4*)out;
  for (int i = blockIdx.x*blockDim.x + threadIdx.x; i < T2; i += gridDim.x*blockDim.x){
    o4[i] = (i < T1) ? a4[i] : b4[i - T1];
  }
}
__global__ __launch_bounds__(512) void meanj_part_k(const float* __restrict__ x_op, float* scratch){
  int b = blockIdx.x, chunk = blockIdx.y, f = threadIdx.x;
  float s = 0.f;
  for (int r=0;r<128;++r){
    int row = b*1024 + chunk*128 + r;
    s += x_op[(size_t)row*512 + f];
  }
  atomicAdd(&scratch[b*512 + f], s);
}
__global__ void meanj_fin_k(const float* scratch, float* out){
  int i = blockIdx.x*blockDim.x + threadIdx.x;
  if (i < 4096) out[4456448 + i] = scratch[i] * (1.f/1024.f);
}
__global__ __launch_bounds__(512) void meanm_k(const float* __restrict__ x_m, float* out){
  int b = blockIdx.x, f = threadIdx.x;
  float s = 0.f;
  for (int r=0;r<64;++r) s += x_m[(size_t)(b*64+r)*512 + f];
  out[4460544 + b*512 + f] = s * (1.f/64.f);
}

extern "C" void kernel_launch(void* const* d_in, const int* in_sizes, int n_in,
                              void* d_out, int out_size, void* d_ws, size_t ws_size,
                              hipStream_t stream){
  const float* op_x      = (const float*)d_in[0];
  const float* machine_x = (const float*)d_in[1];
  const float* W_emb_op  = (const float*)d_in[2];
  const float* b_emb_op  = (const float*)d_in[3];
  const float* W_emb_m   = (const float*)d_in[4];
  const float* b_emb_m   = (const float*)d_in[5];
  const float* opn_w     = (const float*)d_in[6];
  const float* opn_b     = (const float*)d_in[7];
  const float* mn_w      = (const float*)d_in[8];
  const float* mn_b      = (const float*)d_in[9];
  const float* Wk        = (const float*)d_in[10];
  const float* bk        = (const float*)d_in[11];
  const float* Wq        = (const float*)d_in[12];
  const float* bq        = (const float*)d_in[13];
  const float* Wv        = (const float*)d_in[14];
  const float* bv        = (const float*)d_in[15];
  const float* A_rel     = (const float*)d_in[16];
  const float* M_rel     = (const float*)d_in[17];
  const float* p_rel     = (const float*)d_in[18];
  const float* W_out     = (const float*)d_in[19];
  const float* b_out     = (const float*)d_in[20];
  const float* skip      = (const float*)d_in[21];
  const float* ln_w      = (const float*)d_in[22];
  const float* ln_b      = (const float*)d_in[23];
  const int* s0          = (const int*)d_in[24];
  const int* s1          = (const int*)d_in[25];
  float* out = (float*)d_out;

  char* ws = (char*)d_ws;
  size_t off = 0;
  auto alloc = [&](size_t bytes)->void*{
    void* p = ws + off;
    off = (off + bytes + 255) & ~(size_t)255;
    return p;
  };
  float* accb      = (float*)alloc(64*4);
  float* scratch   = (float*)alloc(4096*4);
  float* pstat     = (float*)alloc(4096*4);
  float* Ct        = (float*)alloc((size_t)NMS*1024*4);
  float* Cn        = (float*)alloc((size_t)NOPS*64*4);
  float* S2f       = (float*)alloc((size_t)NMS*8*1024*4);
  u16*   W2        = (u16*)  alloc((size_t)NMS*8*1024*2);
  float* S1f       = (float*)alloc((size_t)NOPS*8*64*4);
  u16*   W1        = (u16*)  alloc((size_t)NOPS*8*64*2);
  float* wpre      = (float*)alloc((size_t)NOPS*8*4);
  float* linv      = (float*)alloc((size_t)NOPS*8*4);
  float* x_op      = (float*)alloc((size_t)NOPS*512*4);
  u16*   x_op_bf   = (u16*)  alloc((size_t)NOPS*512*2);
  float* x_m       = (float*)alloc((size_t)NMS*512*4);
  u16*   x_m_bf    = (u16*)  alloc((size_t)NMS*512*2);
  u16*   qkv_op    = (u16*)  alloc((size_t)NOPS*CQ*2);   // 40MB; o_op (16MB f32) aliases it
  u16*   qkv_m     = (u16*)  alloc((size_t)NMS*CM*2);
  u16*   agg_op    = (u16*)  alloc((size_t)NOPS*512*2);
  u16*   agg_m     = (u16*)  alloc((size_t)NMS*512*2);
  u16*   Wc_op_t   = (u16*)  alloc((size_t)3*CQ*512*2);
  float* bias_op   = (float*)alloc((size_t)3*CQ*4);
  u16*   Wc_m_t    = (u16*)  alloc((size_t)3*CM*512*2);
  float* bias_m    = (float*)alloc((size_t)3*CM*4);
  u16*   Wout_t    = (u16*)  alloc((size_t)6*262144*2);
  float* o_op      = (float*)qkv_op;
  float* o_m       = (float*)qkv_m;
  float* pstat_m   = pstat + 2048;

  const int TOP = NOPS*512;
  const int TM  = NMS*512;
  const int T4OP = TOP/4, T4M = TM/4;
  const int GB_OP = 1024, GB_M = 128;

  // setup
  zero_ws_k<<<1024,256,0,stream>>>(Ct, Cn, accb, scratch);
  cnt_k<<<256,256,0,stream>>>(s1, Ct, Cn);
  twout_k<<<dim3(6,8,8),256,0,stream>>>(W_out, Wout_t);
  tq_k<<<dim3(6,8,8),256,0,stream>>>(Wq, Wc_op_t, Wc_m_t);
  qb_k<<<12,256,0,stream>>>(bq, bias_op, bias_m);
  combine2_k<<<dim3(144,16),256,0,stream>>>(Wk, bk, Wv, bv, A_rel, M_rel, Wc_op_t, bias_op, Wc_m_t, bias_m);

  // embeddings + graph LN
  embed_k<<<GB_OP,256,0,stream>>>(op_x, W_emb_op, b_emb_op, x_op, TOP, 16, pstat);
  embed_k<<<GB_M,256,0,stream>>>(machine_x, W_emb_m, b_emb_m, x_m, TM, 8, pstat_m);
  reduce_stats_k<<<1,256,0,stream>>>(pstat,   GB_OP, 1.f/TOP, accb + 0);
  reduce_stats_k<<<1,256,0,stream>>>(pstat_m, GB_M,  1.f/TM,  accb + 2);
  ln_apply_k<<<1024,256,0,stream>>>(x_op, x_op, x_op_bf, opn_w, opn_b, accb + 0, T4OP);
  ln_apply_k<<<128,256,0,stream>>>(x_m, x_m, x_m_bf, mn_w, mn_b, accb + 2, T4M);

  for (int l=0; l<3; ++l){
    gemm_bt<<<dim3(CQ/128, NOPS/128),256,0,stream>>>(x_op_bf, Wc_op_t + (size_t)l*CQ*512, bias_op + l*CQ, qkv_op, NOPS, CQ, 512, 1);
    gemm_bt<<<dim3(CM/128, NMS/128),256,0,stream>>>(x_m_bf, Wc_m_t + (size_t)l*CM*512, bias_m + l*CM, qkv_m, NMS, CM, 512, 1);
    // op-side dense attention
    qk1_k<<<dim3(8,64),256,0,stream>>>(qkv_op, qkv_m, p_rel + l*24, S1f);
    msoft1_k<<<256,256,0,stream>>>(S1f, Cn, qkv_op, p_rel + l*24, W1, wpre, linv);
    aggop_k<<<dim3(8,64),256,0,stream>>>(W1, qkv_op, qkv_m, wpre, linv, agg_op);
    // machine-side dense attention
    qk2_k<<<dim3(8,64),256,0,stream>>>(qkv_op, qkv_m, p_rel + l*24, S2f);
    msoft_k<<<NMS,512,0,stream>>>(S2f, Ct, W2);
    aggm_k<<<64,256,0,stream>>>(W2, qkv_op, agg_m);
    // output projections
    gemm_bt<<<dim3(512/128, NOPS/128),256,0,stream>>>(agg_op, Wout_t + (size_t)(l*2+0)*262144, nullptr, o_op, NOPS, 512, 512, 0);
    gate_res_k<<<GB_OP,256,0,stream>>>(o_op, x_op, b_out + (size_t)(l*2+0)*512, skip + l*2+0, pstat, T4OP);
    gemm_bt<<<dim3(512/128, NMS/128),256,0,stream>>>(agg_m, Wout_t + (size_t)(l*2+1)*262144, nullptr, o_m, NMS, 512, 512, 0);
    gate_res_k<<<GB_M,256,0,stream>>>(o_m, x_m, b_out + (size_t)(l*2+1)*512, skip + l*2+1, pstat_m, T4M);
    reduce_stats_k<<<1,256,0,stream>>>(pstat,   GB_OP, 1.f/TOP, accb + 2*(2+2*l));
    reduce_stats_k<<<1,256,0,stream>>>(pstat_m, GB_M,  1.f/TM,  accb + 2*(3+2*l));
    ln_apply_k<<<1024,256,0,stream>>>(o_op, x_op, x_op_bf, ln_w + l*512, ln_b + l*512, accb + 2*(2+2*l), T4OP);
    ln_apply_k<<<128,256,0,stream>>>(o_m, x_m, x_m_bf, ln_w + l*512, ln_b + l*512, accb + 2*(3+2*l), T4M);
  }

  emit_k<<<2048,256,0,stream>>>(x_op, x_m, out);
  meanj_part_k<<<dim3(8,8),512,0,stream>>>(x_op, scratch);
  meanj_fin_k<<<16,256,0,stream>>>(scratch, out);
  meanm_k<<<8,512,0,stream>>>(x_m, out);
}

// Round 10
// 634.532 us; speedup vs baseline: 3.7800x; 1.3195x over previous
//
#include <hip/hip_runtime.h>

typedef unsigned short u16;
typedef __attribute__((ext_vector_type(4))) float floatx4;
typedef __attribute__((ext_vector_type(8))) short shortx8;
typedef __attribute__((ext_vector_type(4))) short shortx4;

#define NOPS 8192
#define NMS  512
#define CQ   2560   // op qkv cols: q | k0 | v0 | k2 | v2
#define CM   1536   // machine qkv cols: q | k1 | v1
#define NE2  65536
#define TOPC (NOPS*512)
#define TMC  (NMS*512)

__device__ __forceinline__ float bf2f(u16 u){ return __uint_as_float(((unsigned)u)<<16); }
__device__ __forceinline__ u16 f2bf(float f){
  unsigned u = __float_as_uint(f);
  u += 0x7FFFu + ((u>>16)&1u);
  return (u16)(u>>16);
}
__device__ __forceinline__ float wred(float v){
  #pragma unroll
  for (int o=32;o;o>>=1) v += __shfl_xor(v,o,64);
  return v;
}
__device__ __forceinline__ float wredmax(float v){
  #pragma unroll
  for (int o=32;o;o>>=1) v = fmaxf(v, __shfl_xor(v,o,64));
  return v;
}
__device__ __forceinline__ float geluf(float x){
  return 0.5f*x*(1.f+erff(x*0.70710678118654752f));
}
// block (s,s2) reduction -> one pair at pstat[slot]
__device__ __forceinline__ void block_stat_out2(float s, float s2, float* pstat, int slot){
  __shared__ float sb[8];
  s = wred(s); s2 = wred(s2);
  int wv = threadIdx.x >> 6;
  if ((threadIdx.x & 63) == 0){ sb[wv*2] = s; sb[wv*2+1] = s2; }
  __syncthreads();
  if (threadIdx.x == 0){
    float a = 0.f, b = 0.f;
    int nw = blockDim.x >> 6;
    for (int i=0;i<nw;++i){ a += sb[i*2]; b += sb[i*2+1]; }
    pstat[slot*2]   = a;
    pstat[slot*2+1] = b;
  }
}

// ---------------- zero ws: Ct + Cn + scratch + accb ----------------
__global__ __launch_bounds__(256) void zero_ws_k(float* Ct, float* Cn, float* acc, float* scratch){
  const int T1 = 524288, T2 = 1048576, T3 = 1052672, T4 = 1052736;
  for (int i = blockIdx.x*blockDim.x + threadIdx.x; i < T4; i += gridDim.x*blockDim.x){
    if (i < T1) Ct[i] = 0.f;
    else if (i < T2) Cn[i - T1] = 0.f;
    else if (i < T3) scratch[i - T2] = 0.f;
    else acc[i - T3] = 0.f;
  }
}
// ---------------- edge multiplicity: Ct[mach][op_local], Cn[op][mach_local] ----------------
__global__ void cnt_k(const int* __restrict__ s1, float* Ct, float* Cn){
  int e = blockIdx.x*blockDim.x + threadIdx.x;
  if (e < NE2){
    int m = s1[e], n = e >> 3;
    atomicAdd(&Ct[(size_t)m*1024 + (n & 1023)], 1.f);
    atomicAdd(&Cn[(size_t)n*64 + (m & 63)], 1.f);
  }
}

// ---------------- W_out: f32 [6][K][N] -> bf16 transposed [6][N][K] ----------------
__global__ __launch_bounds__(256) void twout_k(const float* __restrict__ src, u16* __restrict__ dst){
  __shared__ u16 t[64][65];
  int l = blockIdx.x, kb = blockIdx.y*64, nb = blockIdx.z*64;
  const float* s = src + (size_t)l*262144;
  u16* d = dst + (size_t)l*262144;
  int tx = threadIdx.x & 63, ty4 = threadIdx.x >> 6;
  #pragma unroll 4
  for (int p=0;p<16;++p){
    int k = ty4 + p*4;
    t[k][tx] = f2bf(s[(size_t)(kb+k)*512 + nb + tx]);
  }
  __syncthreads();
  #pragma unroll 4
  for (int p=0;p<16;++p){
    int n = ty4 + p*4;
    d[(size_t)(nb+n)*512 + kb + tx] = t[tx][n];
  }
}

// ---------------- Wq transpose into Wc rows 0..511 ----------------
__global__ __launch_bounds__(256) void tq_k(const float* __restrict__ Wq,
                                            u16* __restrict__ Wc_op_t, u16* __restrict__ Wc_m_t){
  __shared__ u16 tl[64][65];
  int blk = blockIdx.x;
  int l = blk >> 1, side = blk & 1;
  const float* s = Wq + (size_t)blk*262144;
  u16* d = side ? (Wc_m_t + (size_t)l*CM*512) : (Wc_op_t + (size_t)l*CQ*512);
  int kb = blockIdx.y*64, nb = blockIdx.z*64;
  int tx = threadIdx.x & 63, ty4 = threadIdx.x >> 6;
  #pragma unroll 4
  for (int p=0;p<16;++p){
    int k = ty4 + p*4;
    tl[k][tx] = f2bf(s[(size_t)(kb+k)*512 + nb + tx]);
  }
  __syncthreads();
  #pragma unroll 4
  for (int p=0;p<16;++p){
    int n = ty4 + p*4;
    d[(size_t)(nb+n)*512 + kb + tx] = tl[tx][n];
  }
}

// ---------------- q biases ----------------
__global__ void qb_k(const float* __restrict__ bq, float* bias_op, float* bias_m){
  int i = blockIdx.x*blockDim.x + threadIdx.x;
  if (i >= 3072) return;
  int l = i >> 10, side = (i >> 9) & 1, f = i & 511;
  float v = bq[(l*2+side)*512 + f];
  if (side==0) bias_op[l*CQ + f] = v; else bias_m[l*CM + f] = v;
}

// ---------------- relation combine via MFMA: out[e][cc] = Rel^T x W^T, grid (144,4) ----------------
__global__ __launch_bounds__(256) void combine3_k(const float* __restrict__ Wk, const float* __restrict__ Wv,
                                                  const float* __restrict__ Ar, const float* __restrict__ Mr,
                                                  u16* __restrict__ Wc_op_t, u16* __restrict__ Wc_m_t){
  __shared__ u16 As[64*72];    // Rel^T bf16: As[e*72+d]
  __shared__ u16 Bs[128*72];   // W rows bf16: Bs[ccl*72+d]
  int gx = blockIdx.x;
  int l = gx/48; int rem = gx - l*48; int s = rem >> 3; int h = rem & 7;
  int side = (s < 4) ? 0 : 1;
  int r = (s < 4) ? (s+1) : (s-3);
  int useK = side==0 ? (s==0 || s==2) : (s==4);
  int rel  = side==0 ? ((s<2)?0:2) : 1;
  const float* W   = (useK ? Wk : Wv) + (size_t)(l*2+side)*262144;
  const float* Rel = (useK ? Ar : Mr) + ((size_t)(l*3+rel)*8 + h)*4096;
  int h64 = h*64;
  u16* Wt = side ? (Wc_m_t + (size_t)l*CM*512) : (Wc_op_t + (size_t)l*CQ*512);
  int rbase = r*512 + h64;
  int cc0 = blockIdx.y * 128;
  int tid = threadIdx.x, lane = tid & 63, wave = tid >> 6;
  {
    int d = tid >> 2, e0 = (tid & 3) * 16;
    #pragma unroll
    for (int j=0;j<16;++j) As[(e0+j)*72 + d] = f2bf(Rel[d*64 + e0 + j]);
  }
  {
    int ccl = tid >> 1, d0 = (tid & 1) * 32;
    const float* src = W + (size_t)(cc0+ccl)*512 + h64 + d0;
    #pragma unroll
    for (int j=0;j<32;j+=4){
      floatx4 v = *(const floatx4*)(src + j);
      shortx4 sv;
      #pragma unroll
      for (int e=0;e<4;++e) sv[e] = (short)f2bf(v[e]);
      *(shortx4*)(Bs + ccl*72 + d0 + j) = sv;
    }
  }
  __syncthreads();
  int wm = wave & 1, wn = wave >> 1;
  int mrow = lane & 15, quad = lane >> 4;
  floatx4 acc[2][4];
  #pragma unroll
  for (int a=0;a<2;++a)
    #pragma unroll
    for (int b=0;b<4;++b) acc[a][b] = (floatx4){0.f,0.f,0.f,0.f};
  #pragma unroll
  for (int ks=0; ks<2; ++ks){
    shortx8 af[2], bf[4];
    #pragma unroll
    for (int mt=0;mt<2;++mt) af[mt] = *(const shortx8*)(As + (wm*32 + mt*16 + mrow)*72 + ks*32 + quad*8);
    #pragma unroll
    for (int nt=0;nt<4;++nt) bf[nt] = *(const shortx8*)(Bs + (wn*64 + nt*16 + mrow)*72 + ks*32 + quad*8);
    #pragma unroll
    for (int mt=0;mt<2;++mt)
      #pragma unroll
      for (int nt=0;nt<4;++nt)
        acc[mt][nt] = __builtin_amdgcn_mfma_f32_16x16x32_bf16(af[mt], bf[nt], acc[mt][nt], 0, 0, 0);
  }
  #pragma unroll
  for (int mt=0;mt<2;++mt){
    #pragma unroll
    for (int nt=0;nt<4;++nt){
      int ccl = wn*64 + nt*16 + mrow;
      #pragma unroll
      for (int r2=0;r2<4;++r2){
        int e = wm*32 + mt*16 + quad*4 + r2;
        Wt[(size_t)(rbase + e)*512 + cc0 + ccl] = f2bf(acc[mt][nt][r2]);
      }
    }
  }
}
// bias row of the combine (cc==512): grid 144, 64 threads
__global__ void cbias_k(const float* __restrict__ bk, const float* __restrict__ bv,
                        const float* __restrict__ Ar, const float* __restrict__ Mr,
                        float* bias_op, float* bias_m){
  int gx = blockIdx.x; int e = threadIdx.x;
  int l = gx/48; int rem = gx - l*48; int s = rem >> 3; int h = rem & 7;
  int side = (s < 4) ? 0 : 1;
  int r = (s < 4) ? (s+1) : (s-3);
  int useK = side==0 ? (s==0 || s==2) : (s==4);
  int rel  = side==0 ? ((s<2)?0:2) : 1;
  const float* bb  = (useK ? bk : bv) + (size_t)(l*2+side)*512 + h*64;
  const float* Rel = (useK ? Ar : Mr) + ((size_t)(l*3+rel)*8 + h)*4096;
  float acc = 0.f;
  for (int d=0; d<64; ++d) acc += bb[d]*Rel[d*64 + e];
  float* bias = side ? (bias_m + l*CM) : (bias_op + l*CQ);
  bias[r*512 + h*64 + e] = acc;
}

// ---------------- merged embedding (op+m) + per-block LN partials ----------------
__global__ __launch_bounds__(256) void embed2_k(const float* __restrict__ Xop, const float* __restrict__ Wop,
                                                const float* __restrict__ bop, float* __restrict__ Yop,
                                                const float* __restrict__ Xm, const float* __restrict__ Wm,
                                                const float* __restrict__ bm_, float* __restrict__ Ym,
                                                float* pstat, float* pstat_m){
  int bid = blockIdx.x;
  const float *X, *W, *bias; float *Y, *ps; int K, total, nb, lb;
  if (bid < 1024){ X=Xop; W=Wop; bias=bop; Y=Yop; ps=pstat;   K=16; total=TOPC; nb=1024; lb=bid; }
  else           { X=Xm;  W=Wm;  bias=bm_; Y=Ym;  ps=pstat_m; K=8;  total=TMC;  nb=128;  lb=bid-1024; }
  float s = 0.f, s2 = 0.f;
  for (int idx = lb*256 + threadIdx.x; idx < total; idx += nb*256){
    int n = idx >> 9, f = idx & 511;
    float v = bias[f];
    for (int c=0;c<K;++c) v += X[n*K+c] * W[c*512+f];
    Y[idx] = v;
    s += v; s2 += v*v;
  }
  block_stat_out2(s, s2, ps, lb);
}

// ---------------- merged stats finalize: block 0 = op, block 1 = m ----------------
__global__ __launch_bounds__(256) void reduce2_k(const float* __restrict__ pstat, const float* __restrict__ pstat_m,
                                                 float* acc_op, float* acc_m){
  const float* ps; int nblk; float inv_n; float* acc;
  if (blockIdx.x == 0){ ps = pstat;   nblk = 1024; inv_n = 1.f/TOPC; acc = acc_op; }
  else                { ps = pstat_m; nblk = 128;  inv_n = 1.f/TMC;  acc = acc_m; }
  float s = 0.f, s2 = 0.f;
  for (int i = threadIdx.x; i < nblk; i += 256){ s += ps[2*i]; s2 += ps[2*i+1]; }
  __shared__ float sb[8];
  s = wred(s); s2 = wred(s2);
  int wv = threadIdx.x >> 6;
  if ((threadIdx.x & 63) == 0){ sb[wv*2] = s; sb[wv*2+1] = s2; }
  __syncthreads();
  if (threadIdx.x == 0){
    float a = 0.f, b = 0.f;
    for (int i=0;i<4;++i){ a += sb[i*2]; b += sb[i*2+1]; }
    float mean = a * inv_n;
    float var  = fmaxf(b * inv_n - mean*mean, 0.f);
    acc[0] = mean;
    acc[1] = 1.f/(sqrtf(var) + 1e-5f);
  }
}

// ---------------- merged graph-LN apply (op+m): dual write f32 + bf16 ----------------
__global__ __launch_bounds__(256) void ln2_k(const float* __restrict__ src_op, float* __restrict__ dst_op,
                                             u16* __restrict__ dbf_op, const float* __restrict__ w_op,
                                             const float* __restrict__ b_op, const float* __restrict__ acc_op,
                                             const float* __restrict__ src_m, float* __restrict__ dst_m,
                                             u16* __restrict__ dbf_m, const float* __restrict__ w_m,
                                             const float* __restrict__ b_m, const float* __restrict__ acc_m){
  int bid = blockIdx.x;
  const float *src, *w, *b, *acc; float* dst; u16* dbf; int total4, nb, lb;
  if (bid < 1024){ src=src_op; dst=dst_op; dbf=dbf_op; w=w_op; b=b_op; acc=acc_op; total4=TOPC/4; nb=1024; lb=bid; }
  else           { src=src_m;  dst=dst_m;  dbf=dbf_m;  w=w_m;  b=b_m;  acc=acc_m;  total4=TMC/4;  nb=128;  lb=bid-1024; }
  float mean = acc[0], rinv = acc[1];
  const floatx4* s4 = (const floatx4*)src;
  floatx4* d4 = (floatx4*)dst;
  shortx4* db4 = (shortx4*)dbf;
  const floatx4* w4 = (const floatx4*)w;
  const floatx4* b4 = (const floatx4*)b;
  for (int i = lb*256 + threadIdx.x; i < total4; i += nb*256){
    int f = i & 127;
    floatx4 v = s4[i], wv = w4[f], bv = b4[f];
    shortx4 sv;
    #pragma unroll
    for (int e=0;e<4;++e){ v[e] = (v[e]-mean)*rinv*wv[e] + bv[e]; sv[e] = (short)f2bf(v[e]); }
    d4[i] = v;
    db4[i] = sv;
  }
}

// ---------------- merged gated residual (op+m) + per-block LN partials ----------------
__global__ __launch_bounds__(256) void gate2_k(float* __restrict__ y_op, const float* __restrict__ x_op,
                                               const float* __restrict__ bo_op, const float* __restrict__ sk_op,
                                               float* __restrict__ y_m, const float* __restrict__ x_m,
                                               const float* __restrict__ bo_m, const float* __restrict__ sk_m,
                                               float* pstat, float* pstat_m){
  int bid = blockIdx.x;
  float *y, *ps; const float *x, *bo, *sk; int total4, nb, lb;
  if (bid < 1024){ y=y_op; x=x_op; bo=bo_op; sk=sk_op; ps=pstat;   total4=TOPC/4; nb=1024; lb=bid; }
  else           { y=y_m;  x=x_m;  bo=bo_m;  sk=sk_m;  ps=pstat_m; total4=TMC/4;  nb=128;  lb=bid-1024; }
  float g = 1.f/(1.f+expf(-(*sk)));
  floatx4* y4 = (floatx4*)y;
  const floatx4* x4 = (const floatx4*)x;
  const floatx4* b4 = (const floatx4*)bo;
  float s = 0.f, s2 = 0.f;
  for (int i = lb*256 + threadIdx.x; i < total4; i += nb*256){
    floatx4 yv = y4[i], xv = x4[i], bv = b4[i & 127];
    #pragma unroll
    for (int e=0;e<4;++e){
      float o = g*(yv[e]+bv[e]) + (2.f-g)*xv[e];
      yv[e] = o;
      s += o; s2 += o*o;
    }
    y4[i] = yv;
  }
  block_stat_out2(s, s2, ps, lb);
}

// ---------------- m97-style GEMM core + merged dual-GEMM kernel ----------------
__device__ __forceinline__ void gemm_core(u16* As, u16* Bs, const u16* __restrict__ A,
                                          const u16* __restrict__ Bt, const float* __restrict__ bias,
                                          void* __restrict__ Cp, int N, int K, int out_bf16,
                                          int bx, int by){
  const int tid = threadIdx.x;
  const int lane = tid & 63, wave = tid >> 6;
  const int bm = by * 128, bn = bx * 128;
  const int wm = wave & 1, wn = wave >> 1;
  const int mrow = lane & 15, quad = lane >> 4;
  const u16* Ab = A + (size_t)bm*K;
  const u16* Bb = Bt + (size_t)bn*K;
  floatx4 acc[4][4];
  #pragma unroll
  for (int a=0;a<4;++a)
    #pragma unroll
    for (int b=0;b<4;++b) acc[a][b] = (floatx4){0.f,0.f,0.f,0.f};
  const int r0 = tid >> 2, c0 = (tid & 3) * 8;
  const int r1 = (tid+256) >> 2, c1 = ((tid+256) & 3) * 8;
  const int lds0 = wave*512;
  const int lds1 = wave*512 + 2048;
  for (int k0 = 0; k0 < K; k0 += 32){
    __builtin_amdgcn_global_load_lds((const __attribute__((address_space(1))) void*)(Ab + (size_t)r0*K + k0 + c0),
                                     (__attribute__((address_space(3))) void*)(As + lds0), 16, 0, 0);
    __builtin_amdgcn_global_load_lds((const __attribute__((address_space(1))) void*)(Ab + (size_t)r1*K + k0 + c1),
                                     (__attribute__((address_space(3))) void*)(As + lds1), 16, 0, 0);
    __builtin_amdgcn_global_load_lds((const __attribute__((address_space(1))) void*)(Bb + (size_t)r0*K + k0 + c0),
                                     (__attribute__((address_space(3))) void*)(Bs + lds0), 16, 0, 0);
    __builtin_amdgcn_global_load_lds((const __attribute__((address_space(1))) void*)(Bb + (size_t)r1*K + k0 + c1),
                                     (__attribute__((address_space(3))) void*)(Bs + lds1), 16, 0, 0);
    __syncthreads();
    shortx8 af[4], bf[4];
    #pragma unroll
    for (int mt=0;mt<4;++mt) af[mt] = *(const shortx8*)(As + (wm*64 + mt*16 + mrow)*32 + quad*8);
    #pragma unroll
    for (int nt=0;nt<4;++nt) bf[nt] = *(const shortx8*)(Bs + (wn*64 + nt*16 + mrow)*32 + quad*8);
    #pragma unroll
    for (int mt=0;mt<4;++mt)
      #pragma unroll
      for (int nt=0;nt<4;++nt)
        acc[mt][nt] = __builtin_amdgcn_mfma_f32_16x16x32_bf16(af[mt], bf[nt], acc[mt][nt], 0, 0, 0);
    __syncthreads();
  }
  #pragma unroll
  for (int mt=0;mt<4;++mt){
    #pragma unroll
    for (int nt=0;nt<4;++nt){
      int col = bn + wn*64 + nt*16 + mrow;
      float bval = bias ? bias[col] : 0.f;
      #pragma unroll
      for (int r2=0;r2<4;++r2){
        int row = bm + wm*64 + mt*16 + quad*4 + r2;
        float v = acc[mt][nt][r2] + bval;
        if (out_bf16) ((u16*)Cp)[(size_t)row*N + col] = f2bf(v);
        else          ((float*)Cp)[(size_t)row*N + col] = v;
      }
    }
  }
}
__global__ __launch_bounds__(256) void gemm2_k(const u16* A1, const u16* B1, const float* bias1, void* C1,
                                               int N1, int ob1, int ntx1, int nblk1,
                                               const u16* A2, const u16* B2, const float* bias2, void* C2,
                                               int N2, int ob2, int ntx2, int K){
  __shared__ u16 As[128*32];
  __shared__ u16 Bs[128*32];
  int id = blockIdx.x;
  if (id < nblk1) gemm_core(As, Bs, A1, B1, bias1, C1, N1, K, ob1, id % ntx1, id / ntx1);
  else { int j = id - nblk1; gemm_core(As, Bs, A2, B2, bias2, C2, N2, K, ob2, j % ntx2, j / ntx2); }
}

// ---------------- merged score GEMMs: z=0 -> S1[n,m], z=1 -> S2[m,n] ----------------
__global__ __launch_bounds__(256) void qk12_k(const u16* __restrict__ qkv_op, const u16* __restrict__ qkv_m,
                                              const float* __restrict__ prel, float* __restrict__ S1f,
                                              float* __restrict__ S2f){
  __shared__ u16 As[128*72];
  __shared__ u16 Bs[128*72];
  int bh = blockIdx.y; int b = bh >> 3, h = bh & 7;
  int n0 = blockIdx.x * 128;
  int tid = threadIdx.x, lane = tid & 63, wave = tid >> 6;
  int mrow = lane & 15, quad = lane >> 4;
  if (blockIdx.z == 0){
    int wm = wave & 1, wn = wave >> 1;
    float p1 = prel[8 + h] * 0.125f;
    {
      int row = tid >> 1, col = (tid & 1) * 32;
      const u16* src = qkv_op + (size_t)(b*1024 + n0 + row)*CQ + h*64 + col;
      #pragma unroll
      for (int e=0;e<4;++e) *(shortx8*)(As + row*72 + col + e*8) = *(const shortx8*)(src + e*8);
    }
    {
      int row = tid >> 2, col = (tid & 3) * 16;
      const u16* src = qkv_m + (size_t)(b*64 + row)*CM + 512 + h*64 + col;
      *(shortx8*)(Bs + row*72 + col)     = *(const shortx8*)(src);
      *(shortx8*)(Bs + row*72 + col + 8) = *(const shortx8*)(src + 8);
    }
    __syncthreads();
    floatx4 acc[4][2];
    #pragma unroll
    for (int a=0;a<4;++a){ acc[a][0] = (floatx4){0,0,0,0}; acc[a][1] = (floatx4){0,0,0,0}; }
    #pragma unroll
    for (int ks=0; ks<2; ++ks){
      shortx8 af[4], bf[2];
      #pragma unroll
      for (int mt=0;mt<4;++mt) af[mt] = *(const shortx8*)(As + (wm*64 + mt*16 + mrow)*72 + ks*32 + quad*8);
      #pragma unroll
      for (int nt=0;nt<2;++nt) bf[nt] = *(const shortx8*)(Bs + (wn*32 + nt*16 + mrow)*72 + ks*32 + quad*8);
      #pragma unroll
      for (int mt=0;mt<4;++mt)
        #pragma unroll
        for (int nt=0;nt<2;++nt)
          acc[mt][nt] = __builtin_amdgcn_mfma_f32_16x16x32_bf16(af[mt], bf[nt], acc[mt][nt], 0, 0, 0);
    }
    #pragma unroll
    for (int mt=0;mt<4;++mt){
      #pragma unroll
      for (int nt=0;nt<2;++nt){
        int m = wn*32 + nt*16 + mrow;
        #pragma unroll
        for (int r2=0;r2<4;++r2){
          int n = n0 + wm*64 + mt*16 + quad*4 + r2;
          S1f[((size_t)(b*1024 + n)*8 + h)*64 + m] = acc[mt][nt][r2] * p1;
        }
      }
    }
  } else {
    float p2 = prel[16 + h] * 0.125f;
    {
      int row = tid >> 2, col = (tid & 3) * 16;
      const u16* src = qkv_m + (size_t)(b*64+row)*CM + h*64 + col;
      *(shortx8*)(As + row*72 + col)     = *(const shortx8*)(src);
      *(shortx8*)(As + row*72 + col + 8) = *(const shortx8*)(src + 8);
    }
    {
      int row = tid >> 1, col = (tid & 1) * 32;
      const u16* src = qkv_op + (size_t)(b*1024 + n0 + row)*CQ + 1536 + h*64 + col;
      #pragma unroll
      for (int e=0;e<4;++e) *(shortx8*)(Bs + row*72 + col + e*8) = *(const shortx8*)(src + e*8);
    }
    __syncthreads();
    floatx4 acc[4][2];
    #pragma unroll
    for (int a=0;a<4;++a){ acc[a][0] = (floatx4){0,0,0,0}; acc[a][1] = (floatx4){0,0,0,0}; }
    #pragma unroll
    for (int ks=0; ks<2; ++ks){
      shortx8 af[4], bf[2];
      #pragma unroll
      for (int mt=0;mt<4;++mt) af[mt] = *(const shortx8*)(As + (mt*16 + mrow)*72 + ks*32 + quad*8);
      #pragma unroll
      for (int nt=0;nt<2;++nt) bf[nt] = *(const shortx8*)(Bs + (wave*32 + nt*16 + mrow)*72 + ks*32 + quad*8);
      #pragma unroll
      for (int mt=0;mt<4;++mt)
        #pragma unroll
        for (int nt=0;nt<2;++nt)
          acc[mt][nt] = __builtin_amdgcn_mfma_f32_16x16x32_bf16(af[mt], bf[nt], acc[mt][nt], 0, 0, 0);
    }
    #pragma unroll
    for (int mt=0;mt<4;++mt){
      #pragma unroll
      for (int nt=0;nt<2;++nt){
        int n = n0 + wave*32 + nt*16 + mrow;
        #pragma unroll
        for (int r2=0;r2<4;++r2){
          int m = mt*16 + quad*4 + r2;
          S2f[((size_t)(b*64 + m)*8 + h)*1024 + n] = acc[mt][nt][r2] * p2;
        }
      }
    }
  }
}

// ---------------- merged softmaxes: blocks [0,128) op-side, [128,640) machine-side ----------------
__global__ __launch_bounds__(512) void msoft12_k(const float* __restrict__ S1f, const float* __restrict__ Cn,
                                                 const u16* __restrict__ qkv_op, const float* __restrict__ prel,
                                                 u16* __restrict__ W1, float* __restrict__ wpre,
                                                 float* __restrict__ linv,
                                                 const float* __restrict__ S2f, const float* __restrict__ Ct,
                                                 u16* __restrict__ W2){
  int bid = blockIdx.x;
  if (bid < 128){
    int i = bid*512 + threadIdx.x;   // (n,h)
    int n = i >> 3, h = i & 7;
    int nl = n & 1023;
    float sp = -1e30f;
    if (nl > 0){
      float p0 = prel[h] * 0.125f;
      const u16* qp = qkv_op + (size_t)n*CQ + h*64;
      const u16* kp = qkv_op + (size_t)(n-1)*CQ + 512 + h*64;
      float acc = 0.f;
      #pragma unroll
      for (int j=0;j<8;++j){
        shortx8 qa = *(const shortx8*)(qp + j*8);
        shortx8 ka = *(const shortx8*)(kp + j*8);
        #pragma unroll
        for (int e=0;e<8;++e) acc += bf2f((u16)qa[e])*bf2f((u16)ka[e]);
      }
      sp = acc * p0;
    }
    const floatx4* s4 = (const floatx4*)(S1f + (size_t)i*64);
    const floatx4* c4 = (const floatx4*)(Cn + (size_t)n*64);
    float mx = sp;
    #pragma unroll
    for (int it=0; it<16; ++it){
      floatx4 sv = s4[it], cv = c4[it];
      #pragma unroll
      for (int e=0;e<4;++e) if (cv[e] > 0.f) mx = fmaxf(mx, sv[e]);
    }
    float L = 0.f;
    shortx4* w4 = (shortx4*)(W1 + (size_t)i*64);
    #pragma unroll
    for (int it=0; it<16; ++it){
      floatx4 sv = s4[it], cv = c4[it];
      shortx4 pv;
      #pragma unroll
      for (int e=0;e<4;++e){
        float w = (cv[e] > 0.f) ? cv[e]*expf(sv[e]-mx) : 0.f;
        L += w;
        pv[e] = (short)f2bf(w);
      }
      w4[it] = pv;
    }
    float ep = (nl > 0) ? expf(sp - mx) : 0.f;
    L += ep;
    wpre[i] = ep;
    linv[i] = 1.f/(L + 1e-16f);
  } else {
    int m = bid - 128;
    int h = threadIdx.x >> 6, d = threadIdx.x & 63;
    const float* srow = S2f + ((size_t)m*8 + h)*1024;
    const float* crow = Ct + (size_t)m*1024;
    float s[16], c[16];
    #pragma unroll
    for (int it=0; it<16; ++it){ s[it] = srow[it*64 + d]; c[it] = crow[it*64 + d]; }
    float mx = -1e30f;
    #pragma unroll
    for (int it=0; it<16; ++it) if (c[it] > 0.f) mx = fmaxf(mx, s[it]);
    mx = wredmax(mx);
    float e[16], L = 0.f;
    #pragma unroll
    for (int it=0; it<16; ++it){
      e[it] = (c[it] > 0.f) ? c[it]*expf(s[it]-mx) : 0.f;
      L += e[it];
    }
    L = wred(L);
    float inv = 1.f/(L + 1e-16f);
    u16* wrow = W2 + ((size_t)m*8 + h)*1024;
    #pragma unroll
    for (int it=0; it<16; ++it) wrow[it*64 + d] = f2bf(e[it]*inv);
  }
}

// ---------------- merged agg GEMMs: blocks [0,512) op-side, [512,576) machine-side ----------------
__global__ __launch_bounds__(256) void agg12_k(const u16* __restrict__ W1, const u16* __restrict__ qkv_op,
                                               const u16* __restrict__ qkv_m, const float* __restrict__ wpre,
                                               const float* __restrict__ linv, u16* __restrict__ agg_op,
                                               const u16* __restrict__ W2, u16* __restrict__ agg_m){
  __shared__ u16 As[128*72];
  __shared__ u16 Bs[64*72];
  int bid = blockIdx.x;
  int tid = threadIdx.x, lane = tid & 63, wave = tid >> 6;
  int wm = wave & 1, wn = wave >> 1;
  int mrow = lane & 15, quad = lane >> 4;
  if (bid < 512){
    int bh = bid >> 3; int b = bh >> 3, h = bh & 7;
    int n0 = (bid & 7) * 128;
    {
      int row = tid >> 1, col = (tid & 1) * 32;
      const u16* src = W1 + ((size_t)(b*1024 + n0 + row)*8 + h)*64 + col;
      #pragma unroll
      for (int e=0;e<4;++e) *(shortx8*)(As + row*72 + col + e*8) = *(const shortx8*)(src + e*8);
    }
    {
      int m = tid >> 2, dcol = (tid & 3) * 16;
      const u16* src = qkv_m + (size_t)(b*64 + m)*CM + 1024 + h*64 + dcol;
      shortx8 v0 = *(const shortx8*)(src);
      shortx8 v1 = *(const shortx8*)(src + 8);
      #pragma unroll
      for (int e=0;e<8;++e){ Bs[(dcol+e)*72 + m] = (u16)v0[e]; Bs[(dcol+8+e)*72 + m] = (u16)v1[e]; }
    }
    __syncthreads();
    floatx4 acc[4][2];
    #pragma unroll
    for (int a=0;a<4;++a){ acc[a][0] = (floatx4){0,0,0,0}; acc[a][1] = (floatx4){0,0,0,0}; }
    #pragma unroll
    for (int ks=0; ks<2; ++ks){
      shortx8 af[4], bf[2];
      #pragma unroll
      for (int mt=0;mt<4;++mt) af[mt] = *(const shortx8*)(As + (wm*64 + mt*16 + mrow)*72 + ks*32 + quad*8);
      #pragma unroll
      for (int nt=0;nt<2;++nt) bf[nt] = *(const shortx8*)(Bs + (wn*32 + nt*16 + mrow)*72 + ks*32 + quad*8);
      #pragma unroll
      for (int mt=0;mt<4;++mt)
        #pragma unroll
        for (int nt=0;nt<2;++nt)
          acc[mt][nt] = __builtin_amdgcn_mfma_f32_16x16x32_bf16(af[mt], bf[nt], acc[mt][nt], 0, 0, 0);
    }
    #pragma unroll
    for (int mt=0;mt<4;++mt){
      #pragma unroll
      for (int nt=0;nt<2;++nt){
        int d = wn*32 + nt*16 + mrow;
        #pragma unroll
        for (int r2=0;r2<4;++r2){
          int n = n0 + wm*64 + mt*16 + quad*4 + r2;
          size_t ng = (size_t)b*1024 + n;
          size_t ih = ng*8 + h;
          float v = acc[mt][nt][r2];
          if ((n & 1023) > 0) v += wpre[ih] * bf2f(qkv_op[(ng-1)*CQ + 1024 + h*64 + d]);
          v *= linv[ih];
          agg_op[ng*512 + h*64 + d] = f2bf(geluf(v));
        }
      }
    }
  } else {
    int bh = bid - 512; int b = bh >> 3, h = bh & 7;
    floatx4 acc[2][2];
    acc[0][0]=(floatx4){0,0,0,0}; acc[0][1]=(floatx4){0,0,0,0};
    acc[1][0]=(floatx4){0,0,0,0}; acc[1][1]=(floatx4){0,0,0,0};
    const int arow = tid >> 2, acol = (tid & 3) * 8;
    const int nrow = tid >> 3, dcol = (tid & 7) * 8;
    for (int ks = 0; ks < 32; ++ks){
      int nn0 = ks*32;
      *(shortx8*)(As + arow*40 + acol) =
          *(const shortx8*)(W2 + ((size_t)(b*64 + arow)*8 + h)*1024 + nn0 + acol);
      shortx8 vv = *(const shortx8*)(qkv_op + (size_t)(b*1024 + nn0 + nrow)*CQ + 2048 + h*64 + dcol);
      #pragma unroll
      for (int e=0;e<8;++e) Bs[(dcol+e)*40 + nrow] = (u16)vv[e];
      __syncthreads();
      shortx8 af[2], bf[2];
      #pragma unroll
      for (int mt=0;mt<2;++mt) af[mt] = *(const shortx8*)(As + (wm*32 + mt*16 + mrow)*40 + quad*8);
      #pragma unroll
      for (int nt=0;nt<2;++nt) bf[nt] = *(const shortx8*)(Bs + (wn*32 + nt*16 + mrow)*40 + quad*8);
      #pragma unroll
      for (int mt=0;mt<2;++mt)
        #pragma unroll
        for (int nt=0;nt<2;++nt)
          acc[mt][nt] = __builtin_amdgcn_mfma_f32_16x16x32_bf16(af[mt], bf[nt], acc[mt][nt], 0, 0, 0);
      __syncthreads();
    }
    #pragma unroll
    for (int mt=0;mt<2;++mt){
      #pragma unroll
      for (int nt=0;nt<2;++nt){
        int dd = wn*32 + nt*16 + mrow;
        #pragma unroll
        for (int r2=0;r2<4;++r2){
          int m = wm*32 + mt*16 + quad*4 + r2;
          agg_m[(size_t)(b*64 + m)*512 + h*64 + dd] = f2bf(geluf(acc[mt][nt][r2]));
        }
      }
    }
  }
}

// ---------------- final emit + means ----------------
__global__ __launch_bounds__(256) void emit_k(const float* __restrict__ x_op, const float* __restrict__ x_m,
                                              float* __restrict__ out){
  const int T1 = NOPS*128, T2 = T1 + NMS*128;
  const floatx4* a4 = (const floatx4*)x_op;
  const floatx4* b4 = (const floatx4*)x_m;
  floatx4* o4 = (floatx4*)out;
  for (int i = blockIdx.x*blockDim.x + threadIdx.x; i < T2; i += gridDim.x*blockDim.x){
    o4[i] = (i < T1) ? a4[i] : b4[i - T1];
  }
}
__global__ __launch_bounds__(512) void meanj_part_k(const float* __restrict__ x_op, float* scratch){
  int b = blockIdx.x, chunk = blockIdx.y, f = threadIdx.x;
  float s = 0.f;
  for (int r=0;r<128;++r){
    int row = b*1024 + chunk*128 + r;
    s += x_op[(size_t)row*512 + f];
  }
  atomicAdd(&scratch[b*512 + f], s);
}
__global__ void meanj_fin_k(const float* scratch, float* out){
  int i = blockIdx.x*blockDim.x + threadIdx.x;
  if (i < 4096) out[4456448 + i] = scratch[i] * (1.f/1024.f);
}
__global__ __launch_bounds__(512) void meanm_k(const float* __restrict__ x_m, float* out){
  int b = blockIdx.x, f = threadIdx.x;
  float s = 0.f;
  for (int r=0;r<64;++r) s += x_m[(size_t)(b*64+r)*512 + f];
  out[4460544 + b*512 + f] = s * (1.f/64.f);
}

extern "C" void kernel_launch(void* const* d_in, const int* in_sizes, int n_in,
                              void* d_out, int out_size, void* d_ws, size_t ws_size,
                              hipStream_t stream){
  const float* op_x      = (const float*)d_in[0];
  const float* machine_x = (const float*)d_in[1];
  const float* W_emb_op  = (const float*)d_in[2];
  const float* b_emb_op  = (const float*)d_in[3];
  const float* W_emb_m   = (const float*)d_in[4];
  const float* b_emb_m   = (const float*)d_in[5];
  const float* opn_w     = (const float*)d_in[6];
  const float* opn_b     = (const float*)d_in[7];
  const float* mn_w      = (const float*)d_in[8];
  const float* mn_b      = (const float*)d_in[9];
  const float* Wk        = (const float*)d_in[10];
  const float* bk        = (const float*)d_in[11];
  const float* Wq        = (const float*)d_in[12];
  const float* bq        = (const float*)d_in[13];
  const float* Wv        = (const float*)d_in[14];
  const float* bv        = (const float*)d_in[15];
  const float* A_rel     = (const float*)d_in[16];
  const float* M_rel     = (const float*)d_in[17];
  const float* p_rel     = (const float*)d_in[18];
  const float* W_out     = (const float*)d_in[19];
  const float* b_out     = (const float*)d_in[20];
  const float* skip      = (const float*)d_in[21];
  const float* ln_w      = (const float*)d_in[22];
  const float* ln_b      = (const float*)d_in[23];
  const int* s1          = (const int*)d_in[25];
  float* out = (float*)d_out;

  char* ws = (char*)d_ws;
  size_t off = 0;
  auto alloc = [&](size_t bytes)->void*{
    void* p = ws + off;
    off = (off + bytes + 255) & ~(size_t)255;
    return p;
  };
  float* accb      = (float*)alloc(64*4);
  float* scratch   = (float*)alloc(4096*4);
  float* pstat     = (float*)alloc(4096*4);
  float* Ct        = (float*)alloc((size_t)NMS*1024*4);
  float* Cn        = (float*)alloc((size_t)NOPS*64*4);
  float* S2f       = (float*)alloc((size_t)NMS*8*1024*4);
  u16*   W2        = (u16*)  alloc((size_t)NMS*8*1024*2);
  float* S1f       = (float*)alloc((size_t)NOPS*8*64*4);
  u16*   W1        = (u16*)  alloc((size_t)NOPS*8*64*2);
  float* wpre      = (float*)alloc((size_t)NOPS*8*4);
  float* linv      = (float*)alloc((size_t)NOPS*8*4);
  float* x_op      = (float*)alloc((size_t)NOPS*512*4);
  u16*   x_op_bf   = (u16*)  alloc((size_t)NOPS*512*2);
  float* x_m       = (float*)alloc((size_t)NMS*512*4);
  u16*   x_m_bf    = (u16*)  alloc((size_t)NMS*512*2);
  u16*   qkv_op    = (u16*)  alloc((size_t)NOPS*CQ*2);   // 40MB; o_op (16MB f32) aliases it
  u16*   qkv_m     = (u16*)  alloc((size_t)NMS*CM*2);
  u16*   agg_op    = (u16*)  alloc((size_t)NOPS*512*2);
  u16*   agg_m     = (u16*)  alloc((size_t)NMS*512*2);
  u16*   Wc_op_t   = (u16*)  alloc((size_t)3*CQ*512*2);
  float* bias_op   = (float*)alloc((size_t)3*CQ*4);
  u16*   Wc_m_t    = (u16*)  alloc((size_t)3*CM*512*2);
  float* bias_m    = (float*)alloc((size_t)3*CM*4);
  u16*   Wout_t    = (u16*)  alloc((size_t)6*262144*2);
  float* o_op      = (float*)qkv_op;
  float* o_m       = (float*)qkv_m;
  float* pstat_m   = pstat + 2048;

  // setup
  zero_ws_k<<<1024,256,0,stream>>>(Ct, Cn, accb, scratch);
  cnt_k<<<256,256,0,stream>>>(s1, Ct, Cn);
  twout_k<<<dim3(6,8,8),256,0,stream>>>(W_out, Wout_t);
  tq_k<<<dim3(6,8,8),256,0,stream>>>(Wq, Wc_op_t, Wc_m_t);
  qb_k<<<12,256,0,stream>>>(bq, bias_op, bias_m);
  combine3_k<<<dim3(144,4),256,0,stream>>>(Wk, Wv, A_rel, M_rel, Wc_op_t, Wc_m_t);
  cbias_k<<<144,64,0,stream>>>(bk, bv, A_rel, M_rel, bias_op, bias_m);

  // embeddings + graph LN
  embed2_k<<<1152,256,0,stream>>>(op_x, W_emb_op, b_emb_op, x_op,
                                  machine_x, W_emb_m, b_emb_m, x_m, pstat, pstat_m);
  reduce2_k<<<2,256,0,stream>>>(pstat, pstat_m, accb + 0, accb + 2);
  ln2_k<<<1152,256,0,stream>>>(x_op, x_op, x_op_bf, opn_w, opn_b, accb + 0,
                               x_m, x_m, x_m_bf, mn_w, mn_b, accb + 2);

  for (int l=0; l<3; ++l){
    gemm2_k<<<1328,256,0,stream>>>(x_op_bf, Wc_op_t + (size_t)l*CQ*512, bias_op + l*CQ, qkv_op, CQ, 1, 20, 1280,
                                   x_m_bf, Wc_m_t + (size_t)l*CM*512, bias_m + l*CM, qkv_m, CM, 1, 12, 512);
    qk12_k<<<dim3(8,64,2),256,0,stream>>>(qkv_op, qkv_m, p_rel + l*24, S1f, S2f);
    msoft12_k<<<640,512,0,stream>>>(S1f, Cn, qkv_op, p_rel + l*24, W1, wpre, linv, S2f, Ct, W2);
    agg12_k<<<576,256,0,stream>>>(W1, qkv_op, qkv_m, wpre, linv, agg_op, W2, agg_m);
    gemm2_k<<<272,256,0,stream>>>(agg_op, Wout_t + (size_t)(l*2+0)*262144, nullptr, o_op, 512, 0, 4, 256,
                                  agg_m, Wout_t + (size_t)(l*2+1)*262144, nullptr, o_m, 512, 0, 4, 512);
    gate2_k<<<1152,256,0,stream>>>(o_op, x_op, b_out + (size_t)(l*2+0)*512, skip + l*2+0,
                                   o_m, x_m, b_out + (size_t)(l*2+1)*512, skip + l*2+1, pstat, pstat_m);
    reduce2_k<<<2,256,0,stream>>>(pstat, pstat_m, accb + 2*(2+2*l), accb + 2*(3+2*l));
    ln2_k<<<1152,256,0,stream>>>(o_op, x_op, x_op_bf, ln_w + l*512, ln_b + l*512, accb + 2*(2+2*l),
                                 o_m, x_m, x_m_bf, ln_w + l*512, ln_b + l*512, accb + 2*(3+2*l));
  }

  emit_k<<<2048,256,0,stream>>>(x_op, x_m, out);
  meanj_part_k<<<dim3(8,8),512,0,stream>>>(x_op, scratch);
  meanj_fin_k<<<16,256,0,stream>>>(scratch, out);
  meanm_k<<<8,512,0,stream>>>(x_m, out);
}